// Round 4
// baseline (498.176 us; speedup 1.0000x reference)
//
#include <hip/hip_runtime.h>
#include <math.h>

// ---------------------------------------------------------------------------
// Round 11: tile_conv staging -> global_load_lds (width 16) + XOR swizzle.
//   R10 reg-staged dbuf gained only 25us: staging still paid the
//   global->VGPR->LDS round trip + VALU addressing (m93-class). Now:
//   direct-to-LDS DMA (m97 lever, +69% there). Linear LDS rows (64 f16 =
//   128B), both-sides XOR swizzle (slot ^= row&7) on global source + ds_read
//   (rule #21) -> 2-way bank conflicts only. SAME-pad OOB rows load from a
//   zeroed 4KB workspace page (re-zeroed each launch; harness poisons ws).
//   Double-buffer, ONE __syncthreads per K-chunk; loads issue after the
//   barrier and land during the MFMA phase (latency hidden).
//
//   conv1: conv1_mfma (R9). tps_k: LDS-parallel gauss (R8).
//   conv2/3/4: tile_conv single fp16; corr: tile_conv SPLIT (hi+lo, 3xMFMA)
//   conv_r1: tile_conv split-K 7; conv_r2: gemm_conv split-K 25.
//
// Workspace (float units), peak 124.17 MB (<127.8 MB proven round 5):
//   WT2@0(36864) WT3@36864(147456) WT4@184320(589824)
//   WTr1@774144(802816,single) WTr2@1576960(102400,single)
//   FEATs @1679360 (4194304)   single fp16, 2 img x 8192 x 512
//   S2    @5873664 (8388608)   full img 32x64x64x128 fp16
//   S1    @14262272 (16777216) full img 32x128x128x64 fp16
//   S3    overlays S1 @14262272 (4194304)
//   post-chain: FEATsp @5873664 (8388608, hi+lo; overlays S2)
//     CORRf@14262272(2097152) CORRh@16359424(1048576, single)
//     R1p@17408000(7x409600) R1h@20275200(204800, single)
//     R2p@20480000(25x73728) R2f@22323200(73728)
//     GEO@22396928 AX@22397504 AY@22405696 -> end 22413888
//   WT1@31039488 (1024)  ZP@31040512 (1024, zeroed every launch)
// ---------------------------------------------------------------------------

typedef __attribute__((ext_vector_type(8))) _Float16 f16x8;
typedef __attribute__((ext_vector_type(4))) float f32x4;

__device__ __forceinline__ unsigned short f2h(float f) {
  return __builtin_bit_cast(unsigned short, (_Float16)f);
}
__device__ __forceinline__ float h2f(unsigned short u) {
  return (float)__builtin_bit_cast(_Float16, u);
}

// direct global->LDS DMA, 16B per lane (lane-linear LDS dest required)
__device__ __forceinline__ void gl16(const unsigned short* g, _Float16* l) {
  auto* gp = (const __attribute__((address_space(1))) unsigned int*)(g);
  auto* lp = (__attribute__((address_space(3))) unsigned int*)(l);
  __builtin_amdgcn_global_load_lds(gp, lp, 16, 0, 0);
}

// ---------------------------------------------------------------- weight prep
__global__ __launch_bounds__(256) void wt_single(const float* __restrict__ w,
                                                 unsigned short* __restrict__ wt,
                                                 int K, int C) {
  const int idx = blockIdx.x * 256 + threadIdx.x;
  if (idx < K * C) {
    const int k = idx / C, o = idx % C;
    wt[(size_t)o * K + k] = f2h(w[idx]);
  }
}

// WT1: [64 out][32 k] fp16, k = (di*3+dj)*3+c for k<27, zero-padded to 32.
__global__ __launch_bounds__(256) void wt1_prep(const float* __restrict__ w,
                                                unsigned short* __restrict__ wt) {
  const int idx = blockIdx.x * 256 + threadIdx.x;  // 64*32 = 2048
  if (idx < 2048) {
    const int o = idx >> 5, k = idx & 31;
    wt[idx] = (k < 27) ? f2h(w[(size_t)k * 64 + o]) : (unsigned short)0;
  }
}

__global__ __launch_bounds__(256) void zero_fill(float* __restrict__ p, int n) {
  const int i = blockIdx.x * 256 + threadIdx.x;
  if (i < n) p[i] = 0.f;
}

// ---------------------------------------------------------------- conv1 MFMA
// One block per (output row i, batch b). 256 threads = 4 waves.
// Wave w computes rows j = w*32..w*32+31 (MT=2) x all 64 channels (NT=4).
// K = 32 (27 real taps + 5 zero pad) -> single MFMA per 16x16 tile.
__global__ __launch_bounds__(256) void conv1_mfma(const float* __restrict__ in,
                                                  const unsigned short* __restrict__ wt1,
                                                  unsigned short* __restrict__ out) {
  const int i = blockIdx.x;   // output row 0..127
  const int b = blockIdx.y;   // batch 0..31
  const int tid = threadIdx.x;
  const int lane = tid & 63, wid = tid >> 6;
  const int lrow = lane & 15, quad = lane >> 4;

  // Rows[di][x*3+c], x in 0..256 (x=256 is SAME right-pad, zero)
  __shared__ _Float16 Rows[3][771];

  const float* __restrict__ inb = in + (size_t)b * 196608;  // 256*256*3
#pragma unroll
  for (int di = 0; di < 3; ++di) {
    const int y = 2 * i + di;
    if (y < 256) {
      const float* __restrict__ row = inb + (size_t)y * 768;
      for (int e = tid; e < 768; e += 256) Rows[di][e] = (_Float16)row[e];
    } else {
      for (int e = tid; e < 768; e += 256) Rows[di][e] = (_Float16)0.f;
    }
    if (tid < 3) Rows[di][768 + tid] = (_Float16)0.f;
  }
  __syncthreads();

  // B fragments: all 64 cols, straight from WT1[64][32]
  f16x8 bf[4];
#pragma unroll
  for (int ni = 0; ni < 4; ++ni)
    bf[ni] = *(const f16x8*)(wt1 + (ni * 16 + lrow) * 32 + quad * 8);

  // A fragments: im2col gather from staged rows.
  // k = (di*3+dj)*3 + c -> di=k/9, dj=(k/3)%3, c=k%3
  f16x8 af[2];
#pragma unroll
  for (int mi = 0; mi < 2; ++mi) {
    const int j = wid * 32 + mi * 16 + lrow;
#pragma unroll
    for (int s = 0; s < 8; ++s) {
      const int k = quad * 8 + s;
      if (k < 27) {
        const int di = k / 9, dj = (k / 3) % 3, c = k % 3;
        af[mi][s] = Rows[di][(2 * j + dj) * 3 + c];
      } else {
        af[mi][s] = (_Float16)0.f;
      }
    }
  }

  f32x4 acc[2][4];
#pragma unroll
  for (int mi = 0; mi < 2; ++mi)
#pragma unroll
    for (int ni = 0; ni < 4; ++ni) {
      const f32x4 z = {0.f, 0.f, 0.f, 0.f};
      acc[mi][ni] = __builtin_amdgcn_mfma_f32_16x16x32_f16(af[mi], bf[ni], z, 0, 0, 0);
    }

  // epilogue: row = quad*4+r, col = lrow (tile_conv layout), fused ReLU
  unsigned short* __restrict__ ob = out + (((size_t)b * 128 + i) * 128) * 64;
#pragma unroll
  for (int mi = 0; mi < 2; ++mi)
#pragma unroll
    for (int ni = 0; ni < 4; ++ni)
#pragma unroll
      for (int r = 0; r < 4; ++r) {
        const int j = wid * 32 + mi * 16 + quad * 4 + r;
        const int col = ni * 16 + lrow;
        ob[(size_t)j * 64 + col] = f2h(fmaxf(acc[mi][ni][r], 0.f));
      }
}

// ---------------------------------------------------------------- tile conv
// LDS-tiled implicit-GEMM, global_load_lds staging + XOR swizzle (R11):
//   LDS rows 64 f16 (128B), 8 slots of 16B. Physical slot = logical ^ (row&7)
//   applied on the global SOURCE (stage) and on the ds_read offset (read).
//   Double buffer; per chunk: barrier -> issue gl16 for next -> ds_read+MFMA.
// SPLIT: A/B have hi+lo planes (aLo/bLo el offsets), 3 MFMAs per pair.
// SK>1: split-K over taps, fp32 partial slices to outf.
// BATB: B rows batched by A's batch index (corr).
// OUTF32: write fp32 to outf AND single fp16 hi to outh.
template <int BM, int BN, int CIN, int COUT, int KH, int KW, int STRIDE,
          int SAMEPAD, int SPLIT, int SK, int BATB, int OUTF32, int RELU>
__global__ __launch_bounds__(256) void tile_conv(
    const unsigned short* __restrict__ in, const unsigned short* __restrict__ wt,
    unsigned short* __restrict__ outh, float* __restrict__ outf,
    const unsigned short* __restrict__ zp,
    int Hin, int Win, int Hout, int Wout, int aLo, int bLo) {
  constexpr int CPT = CIN / 64;
  constexpr int LA = BM / 32;
  constexpr int LB = BN / 32;
  constexpr int KTOT = KH * KW * CIN;
  constexpr int MT = BM / 32;
  constexpr int NT = BN / 32;
  constexpr int PL = 1 + SPLIT;
  __shared__ _Float16 As[2][PL * BM * 64];
  __shared__ _Float16 Bs[2][PL * BN * 64];

  const int t = threadIdx.x;
  const int lane = t & 63, wid = t >> 6;
  const int lrow = lane & 15, quad = lane >> 4;
  const int m0 = blockIdx.x * BM;
  const int n0 = blockIdx.y * BN;

  // staging: thread t covers row r=(t>>3)+32i, slot sl=t&7 (16B units).
  // source uses swizzled slot q = sl ^ (r&7); (r&7) is i-invariant.
  const int q8 = ((t & 7) ^ ((t >> 3) & 7)) * 8;

  int pixB[LA], iS[LA], jS[LA];
#pragma unroll
  for (int i = 0; i < LA; ++i) {
    const int r = (t >> 3) + 32 * i;
    const int m = m0 + r;
    const int j = m % Wout;
    const int t2 = m / Wout;
    const int ii = t2 % Hout;
    const int b = t2 / Hout;
    iS[i] = ii * STRIDE;
    jS[i] = j * STRIDE;
    pixB[i] = ((b * Hin + iS[i]) * Win + jS[i]) * CIN + q8;
  }
  const unsigned short* wb = wt;
  if (BATB) wb += (size_t)(m0 / (Hout * Wout)) * COUT * KTOT;
  int bofB[LB];
#pragma unroll
  for (int i = 0; i < LB; ++i) {
    const int r = (t >> 3) + 32 * i;
    bofB[i] = (n0 + r) * KTOT + q8;
  }

  f32x4 acc[MT][NT];
#pragma unroll
  for (int mi = 0; mi < MT; ++mi)
#pragma unroll
    for (int ni = 0; ni < NT; ++ni) acc[mi][ni] = {0.f, 0.f, 0.f, 0.f};

  const int mB = (wid >> 1) * (BM / 2);
  const int nB = (wid & 1) * (BN / 2);

  int tap_lo = 0, tap_hi = KH * KW;
  if (SK > 1) {
    tap_lo = (int)blockIdx.z * KH * KW / SK;
    tap_hi = ((int)blockIdx.z + 1) * KH * KW / SK;
  }
  const int ch_lo = tap_lo * CPT, ch_hi = tap_hi * CPT;

  auto stage = [&](int buf, int ch) {
    const int tap = ch / CPT;
    const int c0 = (ch % CPT) * 64;
    const int di = tap / KW, dj = tap % KW;
    const int toff = (di * Win + dj) * CIN + c0;
    const int woff = tap * CIN + c0;
#pragma unroll
    for (int i = 0; i < LA; ++i) {
      const bool ok = !SAMEPAD || ((iS[i] + di < Hin) && (jS[i] + dj < Win));
      const unsigned short* s0 = ok ? in + pixB[i] + toff : zp + q8;
      gl16(s0, &As[buf][t * 8 + 2048 * i]);
      if (SPLIT) {
        const unsigned short* s1 = ok ? in + pixB[i] + toff + aLo : zp + q8;
        gl16(s1, &As[buf][BM * 64 + t * 8 + 2048 * i]);
      }
    }
#pragma unroll
    for (int i = 0; i < LB; ++i) {
      gl16(wb + bofB[i] + woff, &Bs[buf][t * 8 + 2048 * i]);
      if (SPLIT)
        gl16(wb + bofB[i] + woff + bLo, &Bs[buf][BN * 64 + t * 8 + 2048 * i]);
    }
  };

  stage(0, ch_lo);
  int cur = 0;
  for (int ch = ch_lo; ch < ch_hi; ++ch) {
    __syncthreads();  // drains prev stage (vmcnt0) + all readers of buf cur^1
    if (ch + 1 < ch_hi) stage(cur ^ 1, ch + 1);  // lands during MFMA phase
#pragma unroll
    for (int ks = 0; ks < 2; ++ks) {
      f16x8 af[MT], bf[NT], al[MT], bl[NT];
#pragma unroll
      for (int mi = 0; mi < MT; ++mi) {
        const int row = mB + mi * 16 + lrow;
        const int off = row * 64 + (((ks * 4 + quad) ^ (row & 7)) * 8);
        af[mi] = *(const f16x8*)&As[cur][off];
        if (SPLIT) al[mi] = *(const f16x8*)&As[cur][BM * 64 + off];
      }
#pragma unroll
      for (int ni = 0; ni < NT; ++ni) {
        const int row = nB + ni * 16 + lrow;
        const int off = row * 64 + (((ks * 4 + quad) ^ (row & 7)) * 8);
        bf[ni] = *(const f16x8*)&Bs[cur][off];
        if (SPLIT) bl[ni] = *(const f16x8*)&Bs[cur][BN * 64 + off];
      }
#pragma unroll
      for (int mi = 0; mi < MT; ++mi)
#pragma unroll
        for (int ni = 0; ni < NT; ++ni) {
          if (SPLIT) {
            acc[mi][ni] = __builtin_amdgcn_mfma_f32_16x16x32_f16(af[mi], bl[ni],
                                                                 acc[mi][ni], 0, 0, 0);
            acc[mi][ni] = __builtin_amdgcn_mfma_f32_16x16x32_f16(al[mi], bf[ni],
                                                                 acc[mi][ni], 0, 0, 0);
          }
          acc[mi][ni] = __builtin_amdgcn_mfma_f32_16x16x32_f16(af[mi], bf[ni],
                                                               acc[mi][ni], 0, 0, 0);
        }
    }
    cur ^= 1;
  }
  const size_t slice =
      (SK > 1) ? (size_t)blockIdx.z * ((size_t)gridDim.x * BM * COUT) : 0;
#pragma unroll
  for (int mi = 0; mi < MT; ++mi)
#pragma unroll
    for (int ni = 0; ni < NT; ++ni)
#pragma unroll
      for (int r = 0; r < 4; ++r) {
        const int row = m0 + mB + mi * 16 + quad * 4 + r;
        const int col = n0 + nB + ni * 16 + lrow;
        const size_t idx = (size_t)row * COUT + col;
        float v = acc[mi][ni][r];
        if (SK > 1) {
          outf[slice + idx] = v;
        } else if (OUTF32) {
          outf[idx] = v;
          outh[idx] = f2h(v);
        } else {
          if (RELU) v = fmaxf(v, 0.f);
          outh[idx] = f2h(v);
        }
      }
}

// ---------------------------------------------------------------- direct MFMA
// kept for conv_r2 (tiny), single plane.
template <int MT, int NT, int CIN, int COUT, int KH, int KW, int SK>
__global__ __launch_bounds__(256) void gemm_conv(
    const unsigned short* __restrict__ in, const unsigned short* __restrict__ wt,
    float* __restrict__ outf, int Hin, int Win, int Hout, int Wout) {
  const int KTOT = KH * KW * CIN;
  const int lane = threadIdx.x & 63;
  const int wid = threadIdx.x >> 6;
  const int lrow = lane & 15;
  const int quad = lane >> 4;
  const int m0 = (blockIdx.x * 4 + wid) * (16 * MT);
  const int n0 = blockIdx.y * (16 * NT);

  int pix[MT];
#pragma unroll
  for (int mi = 0; mi < MT; ++mi) {
    const int m = m0 + mi * 16 + lrow;
    const int j = m % Wout;
    const int t = m / Wout;
    const int i = t % Hout;
    const int b = t / Hout;
    pix[mi] = (b * Hin + i) * Win + j;
  }
  const unsigned short* brow[NT];
#pragma unroll
  for (int ni = 0; ni < NT; ++ni)
    brow[ni] = wt + (size_t)(n0 + ni * 16 + lrow) * KTOT + quad * 8;

  f32x4 acc[MT][NT];
#pragma unroll
  for (int mi = 0; mi < MT; ++mi)
#pragma unroll
    for (int ni = 0; ni < NT; ++ni) acc[mi][ni] = {0.f, 0.f, 0.f, 0.f};

  const int tap_lo = (int)blockIdx.z * KH * KW / SK;
  const int tap_hi = ((int)blockIdx.z + 1) * KH * KW / SK;
  for (int tap = tap_lo; tap < tap_hi; ++tap) {
    const int di = tap / KW, dj = tap % KW;
    const unsigned short* ap[MT];
#pragma unroll
    for (int mi = 0; mi < MT; ++mi)
      ap[mi] = in + ((size_t)pix[mi] + di * Win + dj) * CIN + quad * 8;
    const int ko = tap * CIN;
#pragma unroll
    for (int c0 = 0; c0 < CIN; c0 += 32) {
      f16x8 ah[MT], bh[NT];
#pragma unroll
      for (int mi = 0; mi < MT; ++mi) ah[mi] = *(const f16x8*)(ap[mi] + c0);
#pragma unroll
      for (int ni = 0; ni < NT; ++ni) bh[ni] = *(const f16x8*)(brow[ni] + ko + c0);
#pragma unroll
      for (int mi = 0; mi < MT; ++mi)
#pragma unroll
        for (int ni = 0; ni < NT; ++ni)
          acc[mi][ni] = __builtin_amdgcn_mfma_f32_16x16x32_f16(ah[mi], bh[ni],
                                                               acc[mi][ni], 0, 0, 0);
    }
  }
  const size_t slice = (size_t)blockIdx.z * ((size_t)gridDim.x * 64 * MT * COUT);
#pragma unroll
  for (int mi = 0; mi < MT; ++mi)
#pragma unroll
    for (int ni = 0; ni < NT; ++ni)
#pragma unroll
      for (int r = 0; r < 4; ++r) {
        const int row = m0 + mi * 16 + quad * 4 + r;
        const int col = n0 + ni * 16 + lrow;
        outf[slice + (size_t)row * COUT + col] = acc[mi][ni][r];
      }
}

// ---------------------------------------------------------------- split-K epi
__global__ __launch_bounds__(256) void sum_relu_s(const float* __restrict__ p,
                                                  unsigned short* __restrict__ o,
                                                  int n, int parts) {
  const int idx = blockIdx.x * 256 + threadIdx.x;
  if (idx < n) {
    float v = 0.f;
    for (int s = 0; s < parts; ++s) v += p[(size_t)s * n + idx];
    o[idx] = f2h(fmaxf(v, 0.f));
  }
}
__global__ __launch_bounds__(256) void sum_relu_f(const float* __restrict__ p,
                                                  float* __restrict__ o,
                                                  int n, int parts) {
  const int idx = blockIdx.x * 256 + threadIdx.x;
  if (idx < n) {
    float v = 0.f;
    for (int s = 0; s < parts; ++s) v += p[(size_t)s * n + idx];
    o[idx] = fmaxf(v, 0.f);
  }
}

// ---------------------------------------------------------------- l2 normalize
// in: single fp16; out: split pair (hi @y, lo @y+loOff).
__global__ __launch_bounds__(64) void l2norm_k(const unsigned short* __restrict__ x,
                                               unsigned short* __restrict__ y,
                                               int loOff) {
  const int lane = threadIdx.x;
  const f16x8 v = *(const f16x8*)(x + (size_t)blockIdx.x * 512 + lane * 8);
  float f[8];
  float s = 0.f;
#pragma unroll
  for (int k = 0; k < 8; ++k) {
    f[k] = (float)v[k];
    s += f[k] * f[k];
  }
#pragma unroll
  for (int off = 32; off; off >>= 1) s += __shfl_xor(s, off, 64);
  const float inv = 1.f / (sqrtf(s) + 1e-6f);
  f16x8 vh, vl;
#pragma unroll
  for (int k = 0; k < 8; ++k) {
    const float nv = f[k] * inv;
    const _Float16 hi = (_Float16)nv;
    vh[k] = hi;
    vl[k] = (_Float16)(nv - (float)hi);
  }
  unsigned short* ph = y + (size_t)blockIdx.x * 512 + lane * 8;
  *(f16x8*)ph = vh;
  *(f16x8*)(ph + (size_t)loOff) = vl;
}

// ---------------------------------------------------------------- dense
__global__ __launch_bounds__(64) void dense_k(const float* __restrict__ r2,
                                              const float* __restrict__ wd,
                                              const float* __restrict__ bd,
                                              float* __restrict__ geo) {
  const int o = blockIdx.x;
  const int b = blockIdx.y;
  const int lane = threadIdx.x;
  const float* __restrict__ rb = r2 + (size_t)b * 2304;
  float s = 0.f;
  for (int k = lane; k < 2304; k += 64) s += rb[k] * wd[(size_t)k * 18 + o];
#pragma unroll
  for (int off = 32; off; off >>= 1) s += __shfl_xor(s, off, 64);
  if (lane == 0) geo[b * 18 + o] = s + bd[o];
}

// ---------------------------------------------------------------- TPS
// LDS-parallel version (R8). One block (1 wave) per batch.
__device__ __forceinline__ float tps_u(float r) { return r * r * logf(r + 1e-6f); }

__global__ __launch_bounds__(64) void tps_k(const float* __restrict__ geo,
                                            float* __restrict__ axb,
                                            float* __restrict__ ayb) {
  const int b = blockIdx.x;
  const int tid = threadIdx.x;
  __shared__ float M[12][14];
  __shared__ float fel[12];
  __shared__ float dxs[9], dys[9];
  __shared__ float th[2][12];   // [0]=x theta, [1]=y theta
  __shared__ float sW[2][9];
  __shared__ float sA[2][3];
  __shared__ int sPiv;

  const float srcx[9] = {0.f, 0.5f, 1.f, 0.f, 0.5f, 1.f, 0.f, 5.f, 1.f};
  const float srcy[9] = {0.f, 0.f, 0.f, 0.5f, 0.5f, 0.5f, 1.f, 1.f, 1.f};

  // dst points + RHS columns (12,13)
  if (tid < 9) {
    const float mx = geo[b * 18 + 2 * tid], my = geo[b * 18 + 2 * tid + 1];
    dxs[tid] = srcx[tid] + mx;
    dys[tid] = srcy[tid] + my;
    M[tid][12] = -mx;
    M[tid][13] = -my;
  } else if (tid < 12) {
    M[tid][12] = 0.f;
    M[tid][13] = 0.f;
  }
  __syncthreads();
  // K block: 81 tps_u entries in parallel
  for (int e = tid; e < 81; e += 64) {
    const int p = e / 9, q = e % 9;
    const float ddx = dxs[p] - dxs[q], ddy = dys[p] - dys[q];
    const float r = sqrtf(ddx * ddx + ddy * ddy + 1e-12f);
    M[p][q] = tps_u(r);
  }
  // P blocks + zero bottom-right 3x3
  if (tid < 9) {
    M[tid][9] = 1.f;  M[tid][10] = dxs[tid]; M[tid][11] = dys[tid];
    M[9][tid] = 1.f;  M[10][tid] = dxs[tid]; M[11][tid] = dys[tid];
  } else if (tid < 12) {
    M[tid][9] = 0.f; M[tid][10] = 0.f; M[tid][11] = 0.f;
  }
  __syncthreads();

  // Gaussian elimination with partial pivoting (same arithmetic/order as R7)
  for (int k = 0; k < 12; ++k) {
    if (tid == 0) {
      int piv = k;
      float best = fabsf(M[k][k]);
      for (int r = k + 1; r < 12; ++r) {
        const float v = fabsf(M[r][k]);
        if (v > best) { best = v; piv = r; }
      }
      sPiv = piv;
    }
    __syncthreads();
    const int piv = sPiv;
    if (piv != k && tid < 14) {
      const float tmp = M[k][tid];
      M[k][tid] = M[piv][tid];
      M[piv][tid] = tmp;
    }
    __syncthreads();
    if (tid > k && tid < 12) fel[tid] = M[tid][k] / M[k][k];
    __syncthreads();
    for (int e = tid; e < (11 - k) * 14; e += 64) {
      const int r = k + 1 + e / 14, cc = e % 14;
      if (cc >= k) M[r][cc] -= fel[r] * M[k][cc];
    }
    __syncthreads();
  }

  // Back substitution: lanes 0-15 -> x (RHS col 12), lanes 16-31 -> y (col 13)
  const int grp = tid >> 4;
  const int cc = tid & 15;
  for (int k = 11; k >= 0; --k) {
    float prod = 0.f;
    if (grp < 2 && cc > k && cc < 12) prod = M[k][cc] * th[grp][cc];
#pragma unroll
    for (int off = 8; off; off >>= 1) prod += __shfl_xor(prod, off, 16);
    if (grp < 2 && cc == 0) th[grp][k] = (M[k][12 + grp] - prod) / M[k][k];
    __syncthreads();
  }

  // w/a extraction: w[0] = -sum(theta[1..8]), w[p]=theta[p], a = theta[9..11]
  if (tid < 2) {
    float sw = 0.f;
    for (int p = 1; p < 9; ++p) {
      sW[tid][p] = th[tid][p];
      sw += th[tid][p];
    }
    sW[tid][0] = -sw;
    sA[tid][0] = th[tid][9];
    sA[tid][1] = th[tid][10];
    sA[tid][2] = th[tid][11];
  }
  __syncthreads();

  // evaluate warp field on the 16x16 grid (4 points per lane)
  for (int p = tid; p < 256; p += 64) {
    const int pi = p >> 4, pj = p & 15;
    const float x = pj * (1.f / 15.f), y = pi * (1.f / 15.f);
    float zx = sA[0][0] + x * sA[0][1] + y * sA[0][2];
    float zy = sA[1][0] + x * sA[1][1] + y * sA[1][2];
#pragma unroll
    for (int c = 0; c < 9; ++c) {
      const float ddx = x - dxs[c], ddy = y - dys[c];
      const float r = sqrtf(ddx * ddx + ddy * ddy + 1e-12f);
      const float u = tps_u(r);
      zx += u * sW[0][c];
      zy += u * sW[1][c];
    }
    axb[b * 256 + p] = (x + zx) * 15.f;
    ayb[b * 256 + p] = (y + zy) * 15.f;
  }
}

// ---------------------------------------------------------------- masked sum
__global__ __launch_bounds__(256) void masksum_k(const float* __restrict__ corr,
                                                 const float* __restrict__ axb,
                                                 const float* __restrict__ ayb,
                                                 float* __restrict__ out) {
  const int b = blockIdx.x;
  const int pB = threadIdx.x;
  const float ax = axb[b * 256 + pB];
  const float ay = ayb[b * 256 + pB];
  const float* __restrict__ cb = corr + (size_t)b * 65536;
  float s = 0.f;
  for (int i = 0; i < 16; ++i) {
    if (fabsf((float)i - ay) <= 1.0f) {
      const float* __restrict__ ci = cb + (size_t)i * 16 * 256 + pB;
      for (int j = 0; j < 16; ++j) {
        if (fabsf((float)j - ax) <= 1.0f) s += ci[(size_t)j * 256];
      }
    }
  }
  __shared__ float sm[256];
  sm[pB] = s;
  __syncthreads();
  for (int off = 128; off; off >>= 1) {
    if (pB < off) sm[pB] += sm[pB + off];
    __syncthreads();
  }
  if (pB == 0) out[b] = sm[0];
}

// ---------------------------------------------------------------- launch
extern "C" void kernel_launch(void* const* d_in, const int* in_sizes, int n_in,
                              void* d_out, int out_size, void* d_ws, size_t ws_size,
                              hipStream_t stream) {
  const float* imgA = (const float*)d_in[0];
  const float* imgB = (const float*)d_in[1];
  const float* W1 = (const float*)d_in[2];
  const float* W2 = (const float*)d_in[3];
  const float* W3 = (const float*)d_in[4];
  const float* W4 = (const float*)d_in[5];
  const float* Wr1 = (const float*)d_in[6];
  const float* Wr2 = (const float*)d_in[7];
  const float* Wd = (const float*)d_in[8];
  const float* bd = (const float*)d_in[9];

  float* ws = (float*)d_ws;
  unsigned short* WT2 = (unsigned short*)(ws + 0);
  unsigned short* WT3 = (unsigned short*)(ws + 36864);
  unsigned short* WT4 = (unsigned short*)(ws + 184320);
  unsigned short* WTr1 = (unsigned short*)(ws + 774144);
  unsigned short* WTr2 = (unsigned short*)(ws + 1576960);
  unsigned short* FEATs = (unsigned short*)(ws + 1679360);
  unsigned short* S2 = (unsigned short*)(ws + 5873664);
  unsigned short* S1 = (unsigned short*)(ws + 14262272);
  unsigned short* S3 = (unsigned short*)(ws + 14262272);    // overlays S1
  unsigned short* FEATsp = (unsigned short*)(ws + 5873664); // overlays S2
  float* CORRf = ws + 14262272;                             // overlays S1/S3
  unsigned short* CORRh = (unsigned short*)(ws + 16359424);
  float* R1p = ws + 17408000;
  unsigned short* R1h = (unsigned short*)(ws + 20275200);
  float* R2p = ws + 20480000;
  float* R2f = ws + 22323200;
  float* GEOb = ws + 22396928;
  float* AXb = ws + 22397504;
  float* AYb = ws + 22405696;
  unsigned short* WT1 = (unsigned short*)(ws + 31039488);   // after S1 end
  float* ZPf = ws + 31040512;                               // zero page (4KB)
  const unsigned short* ZP = (const unsigned short*)ZPf;

  // weight prep + zero page (ws is poisoned by harness every iteration)
  zero_fill<<<4, 256, 0, stream>>>(ZPf, 1024);
  wt1_prep<<<8, 256, 0, stream>>>(W1, WT1);
  wt_single<<<288, 256, 0, stream>>>(W2, WT2, 576, 128);
  wt_single<<<1152, 256, 0, stream>>>(W3, WT3, 1152, 256);
  wt_single<<<4608, 256, 0, stream>>>(W4, WT4, 2304, 512);
  wt_single<<<6272, 256, 0, stream>>>(Wr1, WTr1, 12544, 128);
  wt_single<<<800, 256, 0, stream>>>(Wr2, WTr2, 3200, 64);

  for (int img = 0; img < 2; ++img) {
    const float* src = img ? imgB : imgA;
    conv1_mfma<<<dim3(128, 32), 256, 0, stream>>>(src, WT1, S1);
    // conv2: M = 32*4096 = 131072 -> 1024 blocks of 128x128
    tile_conv<128, 128, 64, 128, 3, 3, 2, 1, 0, 1, 0, 0, 1>
        <<<dim3(1024, 1), 256, 0, stream>>>(S1, WT2, S2, nullptr, ZP,
                                            128, 128, 64, 64, 0, 0);
    // conv3: M = 32768 -> 256x2
    tile_conv<128, 128, 128, 256, 3, 3, 2, 1, 0, 1, 0, 0, 1>
        <<<dim3(256, 2), 256, 0, stream>>>(S2, WT3, S3, nullptr, ZP,
                                           64, 64, 32, 32, 0, 0);
    // conv4: M = 8192 -> 128x4 of 64x128
    tile_conv<64, 128, 256, 512, 3, 3, 2, 1, 0, 1, 0, 0, 1>
        <<<dim3(128, 4), 256, 0, stream>>>(S3, WT4, FEATs + (size_t)img * 4194304,
                                           nullptr, ZP, 32, 32, 16, 16, 0, 0);
  }

  // l2norm: FEATs (single) -> FEATsp (split pair, lo at +8388608 el)
  l2norm_k<<<16384, 64, 0, stream>>>(FEATs, FEATsp, 8388608);
  // corr: tiled split GEMM (batched B), fp32 out + single fp16 hi out
  tile_conv<64, 64, 512, 256, 1, 1, 1, 0, 1, 1, 1, 1, 0>
      <<<dim3(128, 4), 256, 0, stream>>>(FEATsp, FEATsp + 4194304, CORRh, CORRf,
                                         ZP, 16, 16, 16, 16, 8388608, 8388608);
  // conv_r1: tiled single fp16, split-K 7 -> fp32 partials
  tile_conv<64, 128, 256, 128, 7, 7, 1, 0, 0, 7, 0, 0, 0>
      <<<dim3(50, 1, 7), 256, 0, stream>>>(CORRh, WTr1, nullptr, R1p, ZP,
                                           16, 16, 10, 10, 0, 0);
  sum_relu_s<<<1600, 256, 0, stream>>>(R1p, R1h, 409600, 7);
  // conv_r2: direct single fp16, split-K 25
  gemm_conv<1, 4, 128, 64, 5, 5, 25>
      <<<dim3(18, 1, 25), 256, 0, stream>>>(R1h, WTr2, R2p, 10, 10, 6, 6);
  sum_relu_f<<<288, 256, 0, stream>>>(R2p, R2f, 73728, 25);
  dense_k<<<dim3(18, 32), 64, 0, stream>>>(R2f, Wd, bd, GEOb);
  tps_k<<<32, 64, 0, stream>>>(GEOb, AXb, AYb);
  masksum_k<<<32, 256, 0, stream>>>(CORRf, AXb, AYb, (float*)d_out);
}

// Round 5
// 477.956 us; speedup vs baseline: 1.0423x; 1.0423x over previous
//
#include <hip/hip_runtime.h>
#include <math.h>

// ---------------------------------------------------------------------------
// Round 12: tile_conv -> counted-vmcnt 2-deep pipeline (T4).
//   R10 (reg dbuf, drain) = 473us; R11 (gl16+swizzle, drain) = 498us.
//   Swizzle killed bank conflicts (2.36M -> 0) but timing flat -> drain-bound
//   (catalog m218: "8-phase-with-drain0 ~= 1-phase"; T4 is the gate).
//   Now: 2 chunks in flight via global_load_lds; per iter
//   s_waitcnt vmcnt(LPS) (newest stage stays in flight) + sched_barrier +
//   raw s_barrier -> MFMA -> raw s_barrier (no drain) -> stage(ch+2).
//   Last iter waits vmcnt(0). Uniform barrier counts; staged buffer was
//   barrier-confirmed fully read.
//
//   conv1: conv1_mfma (R9). tps_k: LDS-parallel gauss (R8).
//   conv2/3/4: tile_conv single fp16; corr: tile_conv SPLIT (hi+lo, 3xMFMA)
//   conv_r1: tile_conv split-K 7; conv_r2: gemm_conv split-K 25.
//
// Workspace (float units), peak 124.17 MB (<127.8 MB proven round 5):
//   WT2@0(36864) WT3@36864(147456) WT4@184320(589824)
//   WTr1@774144(802816,single) WTr2@1576960(102400,single)
//   FEATs @1679360 (4194304)   single fp16, 2 img x 8192 x 512
//   S2    @5873664 (8388608)   full img 32x64x64x128 fp16
//   S1    @14262272 (16777216) full img 32x128x128x64 fp16
//   S3    overlays S1 @14262272 (4194304)
//   post-chain: FEATsp @5873664 (8388608, hi+lo; overlays S2)
//     CORRf@14262272(2097152) CORRh@16359424(1048576, single)
//     R1p@17408000(7x409600) R1h@20275200(204800, single)
//     R2p@20480000(25x73728) R2f@22323200(73728)
//     GEO@22396928 AX@22397504 AY@22405696 -> end 22413888
//   WT1@31039488 (1024)  ZP@31040512 (1024, zeroed every launch)
// ---------------------------------------------------------------------------

typedef __attribute__((ext_vector_type(8))) _Float16 f16x8;
typedef __attribute__((ext_vector_type(4))) float f32x4;

__device__ __forceinline__ unsigned short f2h(float f) {
  return __builtin_bit_cast(unsigned short, (_Float16)f);
}
__device__ __forceinline__ float h2f(unsigned short u) {
  return (float)__builtin_bit_cast(_Float16, u);
}

// direct global->LDS DMA, 16B per lane (lane-linear LDS dest required)
__device__ __forceinline__ void gl16(const unsigned short* g, _Float16* l) {
  auto* gp = (const __attribute__((address_space(1))) unsigned int*)(g);
  auto* lp = (__attribute__((address_space(3))) unsigned int*)(l);
  __builtin_amdgcn_global_load_lds(gp, lp, 16, 0, 0);
}

// ---------------------------------------------------------------- weight prep
__global__ __launch_bounds__(256) void wt_single(const float* __restrict__ w,
                                                 unsigned short* __restrict__ wt,
                                                 int K, int C) {
  const int idx = blockIdx.x * 256 + threadIdx.x;
  if (idx < K * C) {
    const int k = idx / C, o = idx % C;
    wt[(size_t)o * K + k] = f2h(w[idx]);
  }
}

// WT1: [64 out][32 k] fp16, k = (di*3+dj)*3+c for k<27, zero-padded to 32.
__global__ __launch_bounds__(256) void wt1_prep(const float* __restrict__ w,
                                                unsigned short* __restrict__ wt) {
  const int idx = blockIdx.x * 256 + threadIdx.x;  // 64*32 = 2048
  if (idx < 2048) {
    const int o = idx >> 5, k = idx & 31;
    wt[idx] = (k < 27) ? f2h(w[(size_t)k * 64 + o]) : (unsigned short)0;
  }
}

__global__ __launch_bounds__(256) void zero_fill(float* __restrict__ p, int n) {
  const int i = blockIdx.x * 256 + threadIdx.x;
  if (i < n) p[i] = 0.f;
}

// ---------------------------------------------------------------- conv1 MFMA
// One block per (output row i, batch b). 256 threads = 4 waves.
// Wave w computes rows j = w*32..w*32+31 (MT=2) x all 64 channels (NT=4).
// K = 32 (27 real taps + 5 zero pad) -> single MFMA per 16x16 tile.
__global__ __launch_bounds__(256) void conv1_mfma(const float* __restrict__ in,
                                                  const unsigned short* __restrict__ wt1,
                                                  unsigned short* __restrict__ out) {
  const int i = blockIdx.x;   // output row 0..127
  const int b = blockIdx.y;   // batch 0..31
  const int tid = threadIdx.x;
  const int lane = tid & 63, wid = tid >> 6;
  const int lrow = lane & 15, quad = lane >> 4;

  // Rows[di][x*3+c], x in 0..256 (x=256 is SAME right-pad, zero)
  __shared__ _Float16 Rows[3][771];

  const float* __restrict__ inb = in + (size_t)b * 196608;  // 256*256*3
#pragma unroll
  for (int di = 0; di < 3; ++di) {
    const int y = 2 * i + di;
    if (y < 256) {
      const float* __restrict__ row = inb + (size_t)y * 768;
      for (int e = tid; e < 768; e += 256) Rows[di][e] = (_Float16)row[e];
    } else {
      for (int e = tid; e < 768; e += 256) Rows[di][e] = (_Float16)0.f;
    }
    if (tid < 3) Rows[di][768 + tid] = (_Float16)0.f;
  }
  __syncthreads();

  // B fragments: all 64 cols, straight from WT1[64][32]
  f16x8 bf[4];
#pragma unroll
  for (int ni = 0; ni < 4; ++ni)
    bf[ni] = *(const f16x8*)(wt1 + (ni * 16 + lrow) * 32 + quad * 8);

  // A fragments: im2col gather from staged rows.
  // k = (di*3+dj)*3 + c -> di=k/9, dj=(k/3)%3, c=k%3
  f16x8 af[2];
#pragma unroll
  for (int mi = 0; mi < 2; ++mi) {
    const int j = wid * 32 + mi * 16 + lrow;
#pragma unroll
    for (int s = 0; s < 8; ++s) {
      const int k = quad * 8 + s;
      if (k < 27) {
        const int di = k / 9, dj = (k / 3) % 3, c = k % 3;
        af[mi][s] = Rows[di][(2 * j + dj) * 3 + c];
      } else {
        af[mi][s] = (_Float16)0.f;
      }
    }
  }

  f32x4 acc[2][4];
#pragma unroll
  for (int mi = 0; mi < 2; ++mi)
#pragma unroll
    for (int ni = 0; ni < 4; ++ni) {
      const f32x4 z = {0.f, 0.f, 0.f, 0.f};
      acc[mi][ni] = __builtin_amdgcn_mfma_f32_16x16x32_f16(af[mi], bf[ni], z, 0, 0, 0);
    }

  // epilogue: row = quad*4+r, col = lrow (tile_conv layout), fused ReLU
  unsigned short* __restrict__ ob = out + (((size_t)b * 128 + i) * 128) * 64;
#pragma unroll
  for (int mi = 0; mi < 2; ++mi)
#pragma unroll
    for (int ni = 0; ni < 4; ++ni)
#pragma unroll
      for (int r = 0; r < 4; ++r) {
        const int j = wid * 32 + mi * 16 + quad * 4 + r;
        const int col = ni * 16 + lrow;
        ob[(size_t)j * 64 + col] = f2h(fmaxf(acc[mi][ni][r], 0.f));
      }
}

// ---------------------------------------------------------------- tile conv
// LDS-tiled implicit-GEMM, gl16 staging + XOR swizzle + 2-DEEP COUNTED
// PIPELINE (R12):
//   prologue: stage(buf0,c0); stage(buf1,c1)          [2*LPS loads in flight]
//   iter ch:  s_waitcnt vmcnt(LPS) (last: 0) -> sched_barrier -> s_barrier
//             ds_read buf[cur] + MFMA
//             s_barrier (raw, no drain)
//             stage(buf[cur], ch+2)                   [LPS more in flight]
// LDS rows 64 f16 (128B), 8 slots of 16B, slot ^= row&7 both sides.
// SPLIT: A/B hi+lo planes (aLo/bLo el offsets), 3 MFMAs per pair.
// SK>1: split-K over taps, fp32 partial slices. BATB: B batched by A batch.
// OUTF32: fp32 out + fp16 hi out.
template <int BM, int BN, int CIN, int COUT, int KH, int KW, int STRIDE,
          int SAMEPAD, int SPLIT, int SK, int BATB, int OUTF32, int RELU>
__global__ __launch_bounds__(256) void tile_conv(
    const unsigned short* __restrict__ in, const unsigned short* __restrict__ wt,
    unsigned short* __restrict__ outh, float* __restrict__ outf,
    const unsigned short* __restrict__ zp,
    int Hin, int Win, int Hout, int Wout, int aLo, int bLo) {
  constexpr int CPT = CIN / 64;
  constexpr int LA = BM / 32;
  constexpr int LB = BN / 32;
  constexpr int KTOT = KH * KW * CIN;
  constexpr int MT = BM / 32;
  constexpr int NT = BN / 32;
  constexpr int PL = 1 + SPLIT;
  constexpr int LPS = PL * (LA + LB);  // gl16 issues per thread per stage
  // s_waitcnt imm: vmcnt[3:0]|exp[6:4]|lgkm[11:8]|vmcnt_hi[15:14]
  constexpr unsigned WCN =
      (unsigned)((LPS & 0xF) | (0x7 << 4) | (0xF << 8) | ((LPS >> 4) << 14));
  constexpr unsigned WC0 = (unsigned)((0x7 << 4) | (0xF << 8));
  __shared__ _Float16 As[2][PL * BM * 64];
  __shared__ _Float16 Bs[2][PL * BN * 64];

  const int t = threadIdx.x;
  const int lane = t & 63, wid = t >> 6;
  const int lrow = lane & 15, quad = lane >> 4;
  const int m0 = blockIdx.x * BM;
  const int n0 = blockIdx.y * BN;

  // staging: thread t covers row r=(t>>3)+32i, slot sl=t&7 (16B units).
  // source uses swizzled slot q = sl ^ (r&7); (r&7) is i-invariant.
  const int q8 = ((t & 7) ^ ((t >> 3) & 7)) * 8;

  int pixB[LA], iS[LA], jS[LA];
#pragma unroll
  for (int i = 0; i < LA; ++i) {
    const int r = (t >> 3) + 32 * i;
    const int m = m0 + r;
    const int j = m % Wout;
    const int t2 = m / Wout;
    const int ii = t2 % Hout;
    const int b = t2 / Hout;
    iS[i] = ii * STRIDE;
    jS[i] = j * STRIDE;
    pixB[i] = ((b * Hin + iS[i]) * Win + jS[i]) * CIN + q8;
  }
  const unsigned short* wb = wt;
  if (BATB) wb += (size_t)(m0 / (Hout * Wout)) * COUT * KTOT;
  int bofB[LB];
#pragma unroll
  for (int i = 0; i < LB; ++i) {
    const int r = (t >> 3) + 32 * i;
    bofB[i] = (n0 + r) * KTOT + q8;
  }

  f32x4 acc[MT][NT];
#pragma unroll
  for (int mi = 0; mi < MT; ++mi)
#pragma unroll
    for (int ni = 0; ni < NT; ++ni) acc[mi][ni] = {0.f, 0.f, 0.f, 0.f};

  const int mB = (wid >> 1) * (BM / 2);
  const int nB = (wid & 1) * (BN / 2);

  int tap_lo = 0, tap_hi = KH * KW;
  if (SK > 1) {
    tap_lo = (int)blockIdx.z * KH * KW / SK;
    tap_hi = ((int)blockIdx.z + 1) * KH * KW / SK;
  }
  const int ch_lo = tap_lo * CPT, ch_hi = tap_hi * CPT;

  auto stage = [&](int buf, int ch) {
    const int tap = ch / CPT;
    const int c0 = (ch % CPT) * 64;
    const int di = tap / KW, dj = tap % KW;
    const int toff = (di * Win + dj) * CIN + c0;
    const int woff = tap * CIN + c0;
#pragma unroll
    for (int i = 0; i < LA; ++i) {
      const bool ok = !SAMEPAD || ((iS[i] + di < Hin) && (jS[i] + dj < Win));
      const unsigned short* s0 = ok ? in + pixB[i] + toff : zp + q8;
      gl16(s0, &As[buf][t * 8 + 2048 * i]);
      if (SPLIT) {
        const unsigned short* s1 = ok ? in + pixB[i] + toff + aLo : zp + q8;
        gl16(s1, &As[buf][BM * 64 + t * 8 + 2048 * i]);
      }
    }
#pragma unroll
    for (int i = 0; i < LB; ++i) {
      gl16(wb + bofB[i] + woff, &Bs[buf][t * 8 + 2048 * i]);
      if (SPLIT)
        gl16(wb + bofB[i] + woff + bLo, &Bs[buf][BN * 64 + t * 8 + 2048 * i]);
    }
  };

  stage(0, ch_lo);
  if (ch_lo + 1 < ch_hi) stage(1, ch_lo + 1);
  int cur = 0;
  for (int ch = ch_lo; ch < ch_hi; ++ch) {
    // oldest stage (chunk ch) landed; newest (ch+1) stays in flight
    if (ch + 1 < ch_hi) __builtin_amdgcn_s_waitcnt(WCN);
    else __builtin_amdgcn_s_waitcnt(WC0);
    __builtin_amdgcn_sched_barrier(0);
    __builtin_amdgcn_s_barrier();       // all waves' chunk-ch data visible
    __builtin_amdgcn_sched_barrier(0);
#pragma unroll
    for (int ks = 0; ks < 2; ++ks) {
      f16x8 af[MT], bf[NT], al[MT], bl[NT];
#pragma unroll
      for (int mi = 0; mi < MT; ++mi) {
        const int row = mB + mi * 16 + lrow;
        const int off = row * 64 + (((ks * 4 + quad) ^ (row & 7)) * 8);
        af[mi] = *(const f16x8*)&As[cur][off];
        if (SPLIT) al[mi] = *(const f16x8*)&As[cur][BM * 64 + off];
      }
#pragma unroll
      for (int ni = 0; ni < NT; ++ni) {
        const int row = nB + ni * 16 + lrow;
        const int off = row * 64 + (((ks * 4 + quad) ^ (row & 7)) * 8);
        bf[ni] = *(const f16x8*)&Bs[cur][off];
        if (SPLIT) bl[ni] = *(const f16x8*)&Bs[cur][BN * 64 + off];
      }
#pragma unroll
      for (int mi = 0; mi < MT; ++mi)
#pragma unroll
        for (int ni = 0; ni < NT; ++ni) {
          if (SPLIT) {
            acc[mi][ni] = __builtin_amdgcn_mfma_f32_16x16x32_f16(af[mi], bl[ni],
                                                                 acc[mi][ni], 0, 0, 0);
            acc[mi][ni] = __builtin_amdgcn_mfma_f32_16x16x32_f16(al[mi], bf[ni],
                                                                 acc[mi][ni], 0, 0, 0);
          }
          acc[mi][ni] = __builtin_amdgcn_mfma_f32_16x16x32_f16(af[mi], bf[ni],
                                                               acc[mi][ni], 0, 0, 0);
        }
    }
    __builtin_amdgcn_sched_barrier(0);
    __builtin_amdgcn_s_barrier();       // all waves done reading buf[cur]
    __builtin_amdgcn_sched_barrier(0);
    if (ch + 2 < ch_hi) stage(cur, ch + 2);  // overwrite just-freed buffer
    cur ^= 1;
  }
  const size_t slice =
      (SK > 1) ? (size_t)blockIdx.z * ((size_t)gridDim.x * BM * COUT) : 0;
#pragma unroll
  for (int mi = 0; mi < MT; ++mi)
#pragma unroll
    for (int ni = 0; ni < NT; ++ni)
#pragma unroll
      for (int r = 0; r < 4; ++r) {
        const int row = m0 + mB + mi * 16 + quad * 4 + r;
        const int col = n0 + nB + ni * 16 + lrow;
        const size_t idx = (size_t)row * COUT + col;
        float v = acc[mi][ni][r];
        if (SK > 1) {
          outf[slice + idx] = v;
        } else if (OUTF32) {
          outf[idx] = v;
          outh[idx] = f2h(v);
        } else {
          if (RELU) v = fmaxf(v, 0.f);
          outh[idx] = f2h(v);
        }
      }
}

// ---------------------------------------------------------------- direct MFMA
// kept for conv_r2 (tiny), single plane.
template <int MT, int NT, int CIN, int COUT, int KH, int KW, int SK>
__global__ __launch_bounds__(256) void gemm_conv(
    const unsigned short* __restrict__ in, const unsigned short* __restrict__ wt,
    float* __restrict__ outf, int Hin, int Win, int Hout, int Wout) {
  const int KTOT = KH * KW * CIN;
  const int lane = threadIdx.x & 63;
  const int wid = threadIdx.x >> 6;
  const int lrow = lane & 15;
  const int quad = lane >> 4;
  const int m0 = (blockIdx.x * 4 + wid) * (16 * MT);
  const int n0 = blockIdx.y * (16 * NT);

  int pix[MT];
#pragma unroll
  for (int mi = 0; mi < MT; ++mi) {
    const int m = m0 + mi * 16 + lrow;
    const int j = m % Wout;
    const int t = m / Wout;
    const int i = t % Hout;
    const int b = t / Hout;
    pix[mi] = (b * Hin + i) * Win + j;
  }
  const unsigned short* brow[NT];
#pragma unroll
  for (int ni = 0; ni < NT; ++ni)
    brow[ni] = wt + (size_t)(n0 + ni * 16 + lrow) * KTOT + quad * 8;

  f32x4 acc[MT][NT];
#pragma unroll
  for (int mi = 0; mi < MT; ++mi)
#pragma unroll
    for (int ni = 0; ni < NT; ++ni) acc[mi][ni] = {0.f, 0.f, 0.f, 0.f};

  const int tap_lo = (int)blockIdx.z * KH * KW / SK;
  const int tap_hi = ((int)blockIdx.z + 1) * KH * KW / SK;
  for (int tap = tap_lo; tap < tap_hi; ++tap) {
    const int di = tap / KW, dj = tap % KW;
    const unsigned short* ap[MT];
#pragma unroll
    for (int mi = 0; mi < MT; ++mi)
      ap[mi] = in + ((size_t)pix[mi] + di * Win + dj) * CIN + quad * 8;
    const int ko = tap * CIN;
#pragma unroll
    for (int c0 = 0; c0 < CIN; c0 += 32) {
      f16x8 ah[MT], bh[NT];
#pragma unroll
      for (int mi = 0; mi < MT; ++mi) ah[mi] = *(const f16x8*)(ap[mi] + c0);
#pragma unroll
      for (int ni = 0; ni < NT; ++ni) bh[ni] = *(const f16x8*)(brow[ni] + ko + c0);
#pragma unroll
      for (int mi = 0; mi < MT; ++mi)
#pragma unroll
        for (int ni = 0; ni < NT; ++ni)
          acc[mi][ni] = __builtin_amdgcn_mfma_f32_16x16x32_f16(ah[mi], bh[ni],
                                                               acc[mi][ni], 0, 0, 0);
    }
  }
  const size_t slice = (size_t)blockIdx.z * ((size_t)gridDim.x * 64 * MT * COUT);
#pragma unroll
  for (int mi = 0; mi < MT; ++mi)
#pragma unroll
    for (int ni = 0; ni < NT; ++ni)
#pragma unroll
      for (int r = 0; r < 4; ++r) {
        const int row = m0 + mi * 16 + quad * 4 + r;
        const int col = n0 + ni * 16 + lrow;
        outf[slice + (size_t)row * COUT + col] = acc[mi][ni][r];
      }
}

// ---------------------------------------------------------------- split-K epi
__global__ __launch_bounds__(256) void sum_relu_s(const float* __restrict__ p,
                                                  unsigned short* __restrict__ o,
                                                  int n, int parts) {
  const int idx = blockIdx.x * 256 + threadIdx.x;
  if (idx < n) {
    float v = 0.f;
    for (int s = 0; s < parts; ++s) v += p[(size_t)s * n + idx];
    o[idx] = f2h(fmaxf(v, 0.f));
  }
}
__global__ __launch_bounds__(256) void sum_relu_f(const float* __restrict__ p,
                                                  float* __restrict__ o,
                                                  int n, int parts) {
  const int idx = blockIdx.x * 256 + threadIdx.x;
  if (idx < n) {
    float v = 0.f;
    for (int s = 0; s < parts; ++s) v += p[(size_t)s * n + idx];
    o[idx] = fmaxf(v, 0.f);
  }
}

// ---------------------------------------------------------------- l2 normalize
// in: single fp16; out: split pair (hi @y, lo @y+loOff).
__global__ __launch_bounds__(64) void l2norm_k(const unsigned short* __restrict__ x,
                                               unsigned short* __restrict__ y,
                                               int loOff) {
  const int lane = threadIdx.x;
  const f16x8 v = *(const f16x8*)(x + (size_t)blockIdx.x * 512 + lane * 8);
  float f[8];
  float s = 0.f;
#pragma unroll
  for (int k = 0; k < 8; ++k) {
    f[k] = (float)v[k];
    s += f[k] * f[k];
  }
#pragma unroll
  for (int off = 32; off; off >>= 1) s += __shfl_xor(s, off, 64);
  const float inv = 1.f / (sqrtf(s) + 1e-6f);
  f16x8 vh, vl;
#pragma unroll
  for (int k = 0; k < 8; ++k) {
    const float nv = f[k] * inv;
    const _Float16 hi = (_Float16)nv;
    vh[k] = hi;
    vl[k] = (_Float16)(nv - (float)hi);
  }
  unsigned short* ph = y + (size_t)blockIdx.x * 512 + lane * 8;
  *(f16x8*)ph = vh;
  *(f16x8*)(ph + (size_t)loOff) = vl;
}

// ---------------------------------------------------------------- dense
__global__ __launch_bounds__(64) void dense_k(const float* __restrict__ r2,
                                              const float* __restrict__ wd,
                                              const float* __restrict__ bd,
                                              float* __restrict__ geo) {
  const int o = blockIdx.x;
  const int b = blockIdx.y;
  const int lane = threadIdx.x;
  const float* __restrict__ rb = r2 + (size_t)b * 2304;
  float s = 0.f;
  for (int k = lane; k < 2304; k += 64) s += rb[k] * wd[(size_t)k * 18 + o];
#pragma unroll
  for (int off = 32; off; off >>= 1) s += __shfl_xor(s, off, 64);
  if (lane == 0) geo[b * 18 + o] = s + bd[o];
}

// ---------------------------------------------------------------- TPS
// LDS-parallel version (R8). One block (1 wave) per batch.
__device__ __forceinline__ float tps_u(float r) { return r * r * logf(r + 1e-6f); }

__global__ __launch_bounds__(64) void tps_k(const float* __restrict__ geo,
                                            float* __restrict__ axb,
                                            float* __restrict__ ayb) {
  const int b = blockIdx.x;
  const int tid = threadIdx.x;
  __shared__ float M[12][14];
  __shared__ float fel[12];
  __shared__ float dxs[9], dys[9];
  __shared__ float th[2][12];   // [0]=x theta, [1]=y theta
  __shared__ float sW[2][9];
  __shared__ float sA[2][3];
  __shared__ int sPiv;

  const float srcx[9] = {0.f, 0.5f, 1.f, 0.f, 0.5f, 1.f, 0.f, 5.f, 1.f};
  const float srcy[9] = {0.f, 0.f, 0.f, 0.5f, 0.5f, 0.5f, 1.f, 1.f, 1.f};

  // dst points + RHS columns (12,13)
  if (tid < 9) {
    const float mx = geo[b * 18 + 2 * tid], my = geo[b * 18 + 2 * tid + 1];
    dxs[tid] = srcx[tid] + mx;
    dys[tid] = srcy[tid] + my;
    M[tid][12] = -mx;
    M[tid][13] = -my;
  } else if (tid < 12) {
    M[tid][12] = 0.f;
    M[tid][13] = 0.f;
  }
  __syncthreads();
  // K block: 81 tps_u entries in parallel
  for (int e = tid; e < 81; e += 64) {
    const int p = e / 9, q = e % 9;
    const float ddx = dxs[p] - dxs[q], ddy = dys[p] - dys[q];
    const float r = sqrtf(ddx * ddx + ddy * ddy + 1e-12f);
    M[p][q] = tps_u(r);
  }
  // P blocks + zero bottom-right 3x3
  if (tid < 9) {
    M[tid][9] = 1.f;  M[tid][10] = dxs[tid]; M[tid][11] = dys[tid];
    M[9][tid] = 1.f;  M[10][tid] = dxs[tid]; M[11][tid] = dys[tid];
  } else if (tid < 12) {
    M[tid][9] = 0.f; M[tid][10] = 0.f; M[tid][11] = 0.f;
  }
  __syncthreads();

  // Gaussian elimination with partial pivoting (same arithmetic/order as R7)
  for (int k = 0; k < 12; ++k) {
    if (tid == 0) {
      int piv = k;
      float best = fabsf(M[k][k]);
      for (int r = k + 1; r < 12; ++r) {
        const float v = fabsf(M[r][k]);
        if (v > best) { best = v; piv = r; }
      }
      sPiv = piv;
    }
    __syncthreads();
    const int piv = sPiv;
    if (piv != k && tid < 14) {
      const float tmp = M[k][tid];
      M[k][tid] = M[piv][tid];
      M[piv][tid] = tmp;
    }
    __syncthreads();
    if (tid > k && tid < 12) fel[tid] = M[tid][k] / M[k][k];
    __syncthreads();
    for (int e = tid; e < (11 - k) * 14; e += 64) {
      const int r = k + 1 + e / 14, cc = e % 14;
      if (cc >= k) M[r][cc] -= fel[r] * M[k][cc];
    }
    __syncthreads();
  }

  // Back substitution: lanes 0-15 -> x (RHS col 12), lanes 16-31 -> y (col 13)
  const int grp = tid >> 4;
  const int cc = tid & 15;
  for (int k = 11; k >= 0; --k) {
    float prod = 0.f;
    if (grp < 2 && cc > k && cc < 12) prod = M[k][cc] * th[grp][cc];
#pragma unroll
    for (int off = 8; off; off >>= 1) prod += __shfl_xor(prod, off, 16);
    if (grp < 2 && cc == 0) th[grp][k] = (M[k][12 + grp] - prod) / M[k][k];
    __syncthreads();
  }

  // w/a extraction: w[0] = -sum(theta[1..8]), w[p]=theta[p], a = theta[9..11]
  if (tid < 2) {
    float sw = 0.f;
    for (int p = 1; p < 9; ++p) {
      sW[tid][p] = th[tid][p];
      sw += th[tid][p];
    }
    sW[tid][0] = -sw;
    sA[tid][0] = th[tid][9];
    sA[tid][1] = th[tid][10];
    sA[tid][2] = th[tid][11];
  }
  __syncthreads();

  // evaluate warp field on the 16x16 grid (4 points per lane)
  for (int p = tid; p < 256; p += 64) {
    const int pi = p >> 4, pj = p & 15;
    const float x = pj * (1.f / 15.f), y = pi * (1.f / 15.f);
    float zx = sA[0][0] + x * sA[0][1] + y * sA[0][2];
    float zy = sA[1][0] + x * sA[1][1] + y * sA[1][2];
#pragma unroll
    for (int c = 0; c < 9; ++c) {
      const float ddx = x - dxs[c], ddy = y - dys[c];
      const float r = sqrtf(ddx * ddx + ddy * ddy + 1e-12f);
      const float u = tps_u(r);
      zx += u * sW[0][c];
      zy += u * sW[1][c];
    }
    axb[b * 256 + p] = (x + zx) * 15.f;
    ayb[b * 256 + p] = (y + zy) * 15.f;
  }
}

// ---------------------------------------------------------------- masked sum
__global__ __launch_bounds__(256) void masksum_k(const float* __restrict__ corr,
                                                 const float* __restrict__ axb,
                                                 const float* __restrict__ ayb,
                                                 float* __restrict__ out) {
  const int b = blockIdx.x;
  const int pB = threadIdx.x;
  const float ax = axb[b * 256 + pB];
  const float ay = ayb[b * 256 + pB];
  const float* __restrict__ cb = corr + (size_t)b * 65536;
  float s = 0.f;
  for (int i = 0; i < 16; ++i) {
    if (fabsf((float)i - ay) <= 1.0f) {
      const float* __restrict__ ci = cb + (size_t)i * 16 * 256 + pB;
      for (int j = 0; j < 16; ++j) {
        if (fabsf((float)j - ax) <= 1.0f) s += ci[(size_t)j * 256];
      }
    }
  }
  __shared__ float sm[256];
  sm[pB] = s;
  __syncthreads();
  for (int off = 128; off; off >>= 1) {
    if (pB < off) sm[pB] += sm[pB + off];
    __syncthreads();
  }
  if (pB == 0) out[b] = sm[0];
}

// ---------------------------------------------------------------- launch
extern "C" void kernel_launch(void* const* d_in, const int* in_sizes, int n_in,
                              void* d_out, int out_size, void* d_ws, size_t ws_size,
                              hipStream_t stream) {
  const float* imgA = (const float*)d_in[0];
  const float* imgB = (const float*)d_in[1];
  const float* W1 = (const float*)d_in[2];
  const float* W2 = (const float*)d_in[3];
  const float* W3 = (const float*)d_in[4];
  const float* W4 = (const float*)d_in[5];
  const float* Wr1 = (const float*)d_in[6];
  const float* Wr2 = (const float*)d_in[7];
  const float* Wd = (const float*)d_in[8];
  const float* bd = (const float*)d_in[9];

  float* ws = (float*)d_ws;
  unsigned short* WT2 = (unsigned short*)(ws + 0);
  unsigned short* WT3 = (unsigned short*)(ws + 36864);
  unsigned short* WT4 = (unsigned short*)(ws + 184320);
  unsigned short* WTr1 = (unsigned short*)(ws + 774144);
  unsigned short* WTr2 = (unsigned short*)(ws + 1576960);
  unsigned short* FEATs = (unsigned short*)(ws + 1679360);
  unsigned short* S2 = (unsigned short*)(ws + 5873664);
  unsigned short* S1 = (unsigned short*)(ws + 14262272);
  unsigned short* S3 = (unsigned short*)(ws + 14262272);    // overlays S1
  unsigned short* FEATsp = (unsigned short*)(ws + 5873664); // overlays S2
  float* CORRf = ws + 14262272;                             // overlays S1/S3
  unsigned short* CORRh = (unsigned short*)(ws + 16359424);
  float* R1p = ws + 17408000;
  unsigned short* R1h = (unsigned short*)(ws + 20275200);
  float* R2p = ws + 20480000;
  float* R2f = ws + 22323200;
  float* GEOb = ws + 22396928;
  float* AXb = ws + 22397504;
  float* AYb = ws + 22405696;
  unsigned short* WT1 = (unsigned short*)(ws + 31039488);   // after S1 end
  float* ZPf = ws + 31040512;                               // zero page (4KB)
  const unsigned short* ZP = (const unsigned short*)ZPf;

  // weight prep + zero page (ws is poisoned by harness every iteration)
  zero_fill<<<4, 256, 0, stream>>>(ZPf, 1024);
  wt1_prep<<<8, 256, 0, stream>>>(W1, WT1);
  wt_single<<<288, 256, 0, stream>>>(W2, WT2, 576, 128);
  wt_single<<<1152, 256, 0, stream>>>(W3, WT3, 1152, 256);
  wt_single<<<4608, 256, 0, stream>>>(W4, WT4, 2304, 512);
  wt_single<<<6272, 256, 0, stream>>>(Wr1, WTr1, 12544, 128);
  wt_single<<<800, 256, 0, stream>>>(Wr2, WTr2, 3200, 64);

  for (int img = 0; img < 2; ++img) {
    const float* src = img ? imgB : imgA;
    conv1_mfma<<<dim3(128, 32), 256, 0, stream>>>(src, WT1, S1);
    // conv2: M = 32*4096 = 131072 -> 1024 blocks of 128x128
    tile_conv<128, 128, 64, 128, 3, 3, 2, 1, 0, 1, 0, 0, 1>
        <<<dim3(1024, 1), 256, 0, stream>>>(S1, WT2, S2, nullptr, ZP,
                                            128, 128, 64, 64, 0, 0);
    // conv3: M = 32768 -> 256x2
    tile_conv<128, 128, 128, 256, 3, 3, 2, 1, 0, 1, 0, 0, 1>
        <<<dim3(256, 2), 256, 0, stream>>>(S2, WT3, S3, nullptr, ZP,
                                           64, 64, 32, 32, 0, 0);
    // conv4: M = 8192 -> 128x4 of 64x128
    tile_conv<64, 128, 256, 512, 3, 3, 2, 1, 0, 1, 0, 0, 1>
        <<<dim3(128, 4), 256, 0, stream>>>(S3, WT4, FEATs + (size_t)img * 4194304,
                                           nullptr, ZP, 32, 32, 16, 16, 0, 0);
  }

  // l2norm: FEATs (single) -> FEATsp (split pair, lo at +8388608 el)
  l2norm_k<<<16384, 64, 0, stream>>>(FEATs, FEATsp, 8388608);
  // corr: tiled split GEMM (batched B), fp32 out + single fp16 hi out
  tile_conv<64, 64, 512, 256, 1, 1, 1, 0, 1, 1, 1, 1, 0>
      <<<dim3(128, 4), 256, 0, stream>>>(FEATsp, FEATsp + 4194304, CORRh, CORRf,
                                         ZP, 16, 16, 16, 16, 8388608, 8388608);
  // conv_r1: tiled single fp16, split-K 7 -> fp32 partials
  tile_conv<64, 128, 256, 128, 7, 7, 1, 0, 0, 7, 0, 0, 0>
      <<<dim3(50, 1, 7), 256, 0, stream>>>(CORRh, WTr1, nullptr, R1p, ZP,
                                           16, 16, 10, 10, 0, 0);
  sum_relu_s<<<1600, 256, 0, stream>>>(R1p, R1h, 409600, 7);
  // conv_r2: direct single fp16, split-K 25
  gemm_conv<1, 4, 128, 64, 5, 5, 25>
      <<<dim3(18, 1, 25), 256, 0, stream>>>(R1h, WTr2, R2p, 10, 10, 6, 6);
  sum_relu_f<<<288, 256, 0, stream>>>(R2p, R2f, 73728, 25);
  dense_k<<<dim3(18, 32), 64, 0, stream>>>(R2f, Wd, bd, GEOb);
  tps_k<<<32, 64, 0, stream>>>(GEOb, AXb, AYb);
  masksum_k<<<32, 256, 0, stream>>>(CORRf, AXb, AYb, (float*)d_out);
}

// Round 6
// 470.220 us; speedup vs baseline: 1.0595x; 1.0165x over previous
//
#include <hip/hip_runtime.h>
#include <math.h>

// ---------------------------------------------------------------------------
// Round 13: TLP for the thin-phase kernels (conv4, conv_r1).
//   R12 counters: conv4/conv_r1 (49KB class) at 41us each, MfmaUtil 17%,
//   Occ 18% (2 blocks/CU) -- 16 MFMAs/wave/phase cannot cover vmcnt latency,
//   and 8 waves/CU give no TLP. conv2/3 (fat 128^2 tiles) are fine.
//   Fix: conv4 -> 64x64 tiles (grid 1024, LDS 32KB, 5 blocks/CU = 20 waves);
//   conv_r1 -> 64x64 tiles + split-K 25 (grid 2500). Workspace relayout for
//   25 partial slices. Template (gl16 + XOR swizzle + counted-vmcnt 2-deep
//   pipeline) unchanged from R12.
//
//   conv1: conv1_mfma (R9). tps_k: LDS-parallel gauss (R8).
//
// Workspace (float units), peak 118.7MB used (<124.2 proven; WT1/ZP kept at
// R11 offsets which the harness already accepted):
//   WT2@0(36864) WT3@36864(147456) WT4@184320(589824)
//   WTr1@774144(802816,single) WTr2@1576960(102400,single)
//   FEATs @1679360 (4194304)   single fp16, 2 img x 8192 x 512
//   S2    @5873664 (8388608)   full img 32x64x64x128 fp16
//   S1    @14262272 (16777216) full img 32x128x128x64 fp16
//   S3    overlays S1 @14262272 (4194304)
//   post-chain: FEATsp @5873664 (hi+lo; overlays S2)
//     CORRf@14262272(2097152) CORRh@16359424(1048576 fp16 = 524288 fl)
//     R1p@17408000(25x409600 -> end 27648000)
//     R1h@27648000(204800 fp16 = 102400 fl) R2p@27750400(25x73728)
//     R2f@29593600(73728) GEO@29667328 AX@29667904 AY@29676096
//     -> end 29684288
//   WT1@31039488 (1024)  ZP@31040512 (1024, zeroed every launch)
// ---------------------------------------------------------------------------

typedef __attribute__((ext_vector_type(8))) _Float16 f16x8;
typedef __attribute__((ext_vector_type(4))) float f32x4;

__device__ __forceinline__ unsigned short f2h(float f) {
  return __builtin_bit_cast(unsigned short, (_Float16)f);
}
__device__ __forceinline__ float h2f(unsigned short u) {
  return (float)__builtin_bit_cast(_Float16, u);
}

// direct global->LDS DMA, 16B per lane (lane-linear LDS dest required)
__device__ __forceinline__ void gl16(const unsigned short* g, _Float16* l) {
  auto* gp = (const __attribute__((address_space(1))) unsigned int*)(g);
  auto* lp = (__attribute__((address_space(3))) unsigned int*)(l);
  __builtin_amdgcn_global_load_lds(gp, lp, 16, 0, 0);
}

// ---------------------------------------------------------------- weight prep
__global__ __launch_bounds__(256) void wt_single(const float* __restrict__ w,
                                                 unsigned short* __restrict__ wt,
                                                 int K, int C) {
  const int idx = blockIdx.x * 256 + threadIdx.x;
  if (idx < K * C) {
    const int k = idx / C, o = idx % C;
    wt[(size_t)o * K + k] = f2h(w[idx]);
  }
}

// WT1: [64 out][32 k] fp16, k = (di*3+dj)*3+c for k<27, zero-padded to 32.
__global__ __launch_bounds__(256) void wt1_prep(const float* __restrict__ w,
                                                unsigned short* __restrict__ wt) {
  const int idx = blockIdx.x * 256 + threadIdx.x;  // 64*32 = 2048
  if (idx < 2048) {
    const int o = idx >> 5, k = idx & 31;
    wt[idx] = (k < 27) ? f2h(w[(size_t)k * 64 + o]) : (unsigned short)0;
  }
}

__global__ __launch_bounds__(256) void zero_fill(float* __restrict__ p, int n) {
  const int i = blockIdx.x * 256 + threadIdx.x;
  if (i < n) p[i] = 0.f;
}

// ---------------------------------------------------------------- conv1 MFMA
// One block per (output row i, batch b). 256 threads = 4 waves.
// Wave w computes rows j = w*32..w*32+31 (MT=2) x all 64 channels (NT=4).
// K = 32 (27 real taps + 5 zero pad) -> single MFMA per 16x16 tile.
__global__ __launch_bounds__(256) void conv1_mfma(const float* __restrict__ in,
                                                  const unsigned short* __restrict__ wt1,
                                                  unsigned short* __restrict__ out) {
  const int i = blockIdx.x;   // output row 0..127
  const int b = blockIdx.y;   // batch 0..31
  const int tid = threadIdx.x;
  const int lane = tid & 63, wid = tid >> 6;
  const int lrow = lane & 15, quad = lane >> 4;

  // Rows[di][x*3+c], x in 0..256 (x=256 is SAME right-pad, zero)
  __shared__ _Float16 Rows[3][771];

  const float* __restrict__ inb = in + (size_t)b * 196608;  // 256*256*3
#pragma unroll
  for (int di = 0; di < 3; ++di) {
    const int y = 2 * i + di;
    if (y < 256) {
      const float* __restrict__ row = inb + (size_t)y * 768;
      for (int e = tid; e < 768; e += 256) Rows[di][e] = (_Float16)row[e];
    } else {
      for (int e = tid; e < 768; e += 256) Rows[di][e] = (_Float16)0.f;
    }
    if (tid < 3) Rows[di][768 + tid] = (_Float16)0.f;
  }
  __syncthreads();

  // B fragments: all 64 cols, straight from WT1[64][32]
  f16x8 bf[4];
#pragma unroll
  for (int ni = 0; ni < 4; ++ni)
    bf[ni] = *(const f16x8*)(wt1 + (ni * 16 + lrow) * 32 + quad * 8);

  // A fragments: im2col gather from staged rows.
  // k = (di*3+dj)*3 + c -> di=k/9, dj=(k/3)%3, c=k%3
  f16x8 af[2];
#pragma unroll
  for (int mi = 0; mi < 2; ++mi) {
    const int j = wid * 32 + mi * 16 + lrow;
#pragma unroll
    for (int s = 0; s < 8; ++s) {
      const int k = quad * 8 + s;
      if (k < 27) {
        const int di = k / 9, dj = (k / 3) % 3, c = k % 3;
        af[mi][s] = Rows[di][(2 * j + dj) * 3 + c];
      } else {
        af[mi][s] = (_Float16)0.f;
      }
    }
  }

  f32x4 acc[2][4];
#pragma unroll
  for (int mi = 0; mi < 2; ++mi)
#pragma unroll
    for (int ni = 0; ni < 4; ++ni) {
      const f32x4 z = {0.f, 0.f, 0.f, 0.f};
      acc[mi][ni] = __builtin_amdgcn_mfma_f32_16x16x32_f16(af[mi], bf[ni], z, 0, 0, 0);
    }

  // epilogue: row = quad*4+r, col = lrow (tile_conv layout), fused ReLU
  unsigned short* __restrict__ ob = out + (((size_t)b * 128 + i) * 128) * 64;
#pragma unroll
  for (int mi = 0; mi < 2; ++mi)
#pragma unroll
    for (int ni = 0; ni < 4; ++ni)
#pragma unroll
      for (int r = 0; r < 4; ++r) {
        const int j = wid * 32 + mi * 16 + quad * 4 + r;
        const int col = ni * 16 + lrow;
        ob[(size_t)j * 64 + col] = f2h(fmaxf(acc[mi][ni][r], 0.f));
      }
}

// ---------------------------------------------------------------- tile conv
// LDS-tiled implicit-GEMM, gl16 staging + XOR swizzle + 2-DEEP COUNTED
// PIPELINE (R12):
//   prologue: stage(buf0,c0); stage(buf1,c1)          [2*LPS loads in flight]
//   iter ch:  s_waitcnt vmcnt(LPS) (last: 0) -> sched_barrier -> s_barrier
//             ds_read buf[cur] + MFMA
//             s_barrier (raw, no drain)
//             stage(buf[cur], ch+2)                   [LPS more in flight]
// LDS rows 64 f16 (128B), 8 slots of 16B, slot ^= row&7 both sides.
// SPLIT: A/B hi+lo planes (aLo/bLo el offsets), 3 MFMAs per pair.
// SK>1: split-K over taps, fp32 partial slices. BATB: B batched by A batch.
// OUTF32: fp32 out + fp16 hi out.
template <int BM, int BN, int CIN, int COUT, int KH, int KW, int STRIDE,
          int SAMEPAD, int SPLIT, int SK, int BATB, int OUTF32, int RELU>
__global__ __launch_bounds__(256) void tile_conv(
    const unsigned short* __restrict__ in, const unsigned short* __restrict__ wt,
    unsigned short* __restrict__ outh, float* __restrict__ outf,
    const unsigned short* __restrict__ zp,
    int Hin, int Win, int Hout, int Wout, int aLo, int bLo) {
  constexpr int CPT = CIN / 64;
  constexpr int LA = BM / 32;
  constexpr int LB = BN / 32;
  constexpr int KTOT = KH * KW * CIN;
  constexpr int MT = BM / 32;
  constexpr int NT = BN / 32;
  constexpr int PL = 1 + SPLIT;
  constexpr int LPS = PL * (LA + LB);  // gl16 issues per thread per stage
  // s_waitcnt imm: vmcnt[3:0]|exp[6:4]|lgkm[11:8]|vmcnt_hi[15:14]
  constexpr unsigned WCN =
      (unsigned)((LPS & 0xF) | (0x7 << 4) | (0xF << 8) | ((LPS >> 4) << 14));
  constexpr unsigned WC0 = (unsigned)((0x7 << 4) | (0xF << 8));
  __shared__ _Float16 As[2][PL * BM * 64];
  __shared__ _Float16 Bs[2][PL * BN * 64];

  const int t = threadIdx.x;
  const int lane = t & 63, wid = t >> 6;
  const int lrow = lane & 15, quad = lane >> 4;
  const int m0 = blockIdx.x * BM;
  const int n0 = blockIdx.y * BN;

  // staging: thread t covers row r=(t>>3)+32i, slot sl=t&7 (16B units).
  // source uses swizzled slot q = sl ^ (r&7); (r&7) is i-invariant.
  const int q8 = ((t & 7) ^ ((t >> 3) & 7)) * 8;

  int pixB[LA], iS[LA], jS[LA];
#pragma unroll
  for (int i = 0; i < LA; ++i) {
    const int r = (t >> 3) + 32 * i;
    const int m = m0 + r;
    const int j = m % Wout;
    const int t2 = m / Wout;
    const int ii = t2 % Hout;
    const int b = t2 / Hout;
    iS[i] = ii * STRIDE;
    jS[i] = j * STRIDE;
    pixB[i] = ((b * Hin + iS[i]) * Win + jS[i]) * CIN + q8;
  }
  const unsigned short* wb = wt;
  if (BATB) wb += (size_t)(m0 / (Hout * Wout)) * COUT * KTOT;
  int bofB[LB];
#pragma unroll
  for (int i = 0; i < LB; ++i) {
    const int r = (t >> 3) + 32 * i;
    bofB[i] = (n0 + r) * KTOT + q8;
  }

  f32x4 acc[MT][NT];
#pragma unroll
  for (int mi = 0; mi < MT; ++mi)
#pragma unroll
    for (int ni = 0; ni < NT; ++ni) acc[mi][ni] = {0.f, 0.f, 0.f, 0.f};

  const int mB = (wid >> 1) * (BM / 2);
  const int nB = (wid & 1) * (BN / 2);

  int tap_lo = 0, tap_hi = KH * KW;
  if (SK > 1) {
    tap_lo = (int)blockIdx.z * KH * KW / SK;
    tap_hi = ((int)blockIdx.z + 1) * KH * KW / SK;
  }
  const int ch_lo = tap_lo * CPT, ch_hi = tap_hi * CPT;

  auto stage = [&](int buf, int ch) {
    const int tap = ch / CPT;
    const int c0 = (ch % CPT) * 64;
    const int di = tap / KW, dj = tap % KW;
    const int toff = (di * Win + dj) * CIN + c0;
    const int woff = tap * CIN + c0;
#pragma unroll
    for (int i = 0; i < LA; ++i) {
      const bool ok = !SAMEPAD || ((iS[i] + di < Hin) && (jS[i] + dj < Win));
      const unsigned short* s0 = ok ? in + pixB[i] + toff : zp + q8;
      gl16(s0, &As[buf][t * 8 + 2048 * i]);
      if (SPLIT) {
        const unsigned short* s1 = ok ? in + pixB[i] + toff + aLo : zp + q8;
        gl16(s1, &As[buf][BM * 64 + t * 8 + 2048 * i]);
      }
    }
#pragma unroll
    for (int i = 0; i < LB; ++i) {
      gl16(wb + bofB[i] + woff, &Bs[buf][t * 8 + 2048 * i]);
      if (SPLIT)
        gl16(wb + bofB[i] + woff + bLo, &Bs[buf][BN * 64 + t * 8 + 2048 * i]);
    }
  };

  stage(0, ch_lo);
  if (ch_lo + 1 < ch_hi) stage(1, ch_lo + 1);
  int cur = 0;
  for (int ch = ch_lo; ch < ch_hi; ++ch) {
    // oldest stage (chunk ch) landed; newest (ch+1) stays in flight
    if (ch + 1 < ch_hi) __builtin_amdgcn_s_waitcnt(WCN);
    else __builtin_amdgcn_s_waitcnt(WC0);
    __builtin_amdgcn_sched_barrier(0);
    __builtin_amdgcn_s_barrier();       // all waves' chunk-ch data visible
    __builtin_amdgcn_sched_barrier(0);
#pragma unroll
    for (int ks = 0; ks < 2; ++ks) {
      f16x8 af[MT], bf[NT], al[MT], bl[NT];
#pragma unroll
      for (int mi = 0; mi < MT; ++mi) {
        const int row = mB + mi * 16 + lrow;
        const int off = row * 64 + (((ks * 4 + quad) ^ (row & 7)) * 8);
        af[mi] = *(const f16x8*)&As[cur][off];
        if (SPLIT) al[mi] = *(const f16x8*)&As[cur][BM * 64 + off];
      }
#pragma unroll
      for (int ni = 0; ni < NT; ++ni) {
        const int row = nB + ni * 16 + lrow;
        const int off = row * 64 + (((ks * 4 + quad) ^ (row & 7)) * 8);
        bf[ni] = *(const f16x8*)&Bs[cur][off];
        if (SPLIT) bl[ni] = *(const f16x8*)&Bs[cur][BN * 64 + off];
      }
#pragma unroll
      for (int mi = 0; mi < MT; ++mi)
#pragma unroll
        for (int ni = 0; ni < NT; ++ni) {
          if (SPLIT) {
            acc[mi][ni] = __builtin_amdgcn_mfma_f32_16x16x32_f16(af[mi], bl[ni],
                                                                 acc[mi][ni], 0, 0, 0);
            acc[mi][ni] = __builtin_amdgcn_mfma_f32_16x16x32_f16(al[mi], bf[ni],
                                                                 acc[mi][ni], 0, 0, 0);
          }
          acc[mi][ni] = __builtin_amdgcn_mfma_f32_16x16x32_f16(af[mi], bf[ni],
                                                               acc[mi][ni], 0, 0, 0);
        }
    }
    __builtin_amdgcn_sched_barrier(0);
    __builtin_amdgcn_s_barrier();       // all waves done reading buf[cur]
    __builtin_amdgcn_sched_barrier(0);
    if (ch + 2 < ch_hi) stage(cur, ch + 2);  // overwrite just-freed buffer
    cur ^= 1;
  }
  const size_t slice =
      (SK > 1) ? (size_t)blockIdx.z * ((size_t)gridDim.x * BM * COUT) : 0;
#pragma unroll
  for (int mi = 0; mi < MT; ++mi)
#pragma unroll
    for (int ni = 0; ni < NT; ++ni)
#pragma unroll
      for (int r = 0; r < 4; ++r) {
        const int row = m0 + mB + mi * 16 + quad * 4 + r;
        const int col = n0 + nB + ni * 16 + lrow;
        const size_t idx = (size_t)row * COUT + col;
        float v = acc[mi][ni][r];
        if (SK > 1) {
          outf[slice + idx] = v;
        } else if (OUTF32) {
          outf[idx] = v;
          outh[idx] = f2h(v);
        } else {
          if (RELU) v = fmaxf(v, 0.f);
          outh[idx] = f2h(v);
        }
      }
}

// ---------------------------------------------------------------- direct MFMA
// kept for conv_r2 (tiny), single plane.
template <int MT, int NT, int CIN, int COUT, int KH, int KW, int SK>
__global__ __launch_bounds__(256) void gemm_conv(
    const unsigned short* __restrict__ in, const unsigned short* __restrict__ wt,
    float* __restrict__ outf, int Hin, int Win, int Hout, int Wout) {
  const int KTOT = KH * KW * CIN;
  const int lane = threadIdx.x & 63;
  const int wid = threadIdx.x >> 6;
  const int lrow = lane & 15;
  const int quad = lane >> 4;
  const int m0 = (blockIdx.x * 4 + wid) * (16 * MT);
  const int n0 = blockIdx.y * (16 * NT);

  int pix[MT];
#pragma unroll
  for (int mi = 0; mi < MT; ++mi) {
    const int m = m0 + mi * 16 + lrow;
    const int j = m % Wout;
    const int t = m / Wout;
    const int i = t % Hout;
    const int b = t / Hout;
    pix[mi] = (b * Hin + i) * Win + j;
  }
  const unsigned short* brow[NT];
#pragma unroll
  for (int ni = 0; ni < NT; ++ni)
    brow[ni] = wt + (size_t)(n0 + ni * 16 + lrow) * KTOT + quad * 8;

  f32x4 acc[MT][NT];
#pragma unroll
  for (int mi = 0; mi < MT; ++mi)
#pragma unroll
    for (int ni = 0; ni < NT; ++ni) acc[mi][ni] = {0.f, 0.f, 0.f, 0.f};

  const int tap_lo = (int)blockIdx.z * KH * KW / SK;
  const int tap_hi = ((int)blockIdx.z + 1) * KH * KW / SK;
  for (int tap = tap_lo; tap < tap_hi; ++tap) {
    const int di = tap / KW, dj = tap % KW;
    const unsigned short* ap[MT];
#pragma unroll
    for (int mi = 0; mi < MT; ++mi)
      ap[mi] = in + ((size_t)pix[mi] + di * Win + dj) * CIN + quad * 8;
    const int ko = tap * CIN;
#pragma unroll
    for (int c0 = 0; c0 < CIN; c0 += 32) {
      f16x8 ah[MT], bh[NT];
#pragma unroll
      for (int mi = 0; mi < MT; ++mi) ah[mi] = *(const f16x8*)(ap[mi] + c0);
#pragma unroll
      for (int ni = 0; ni < NT; ++ni) bh[ni] = *(const f16x8*)(brow[ni] + ko + c0);
#pragma unroll
      for (int mi = 0; mi < MT; ++mi)
#pragma unroll
        for (int ni = 0; ni < NT; ++ni)
          acc[mi][ni] = __builtin_amdgcn_mfma_f32_16x16x32_f16(ah[mi], bh[ni],
                                                               acc[mi][ni], 0, 0, 0);
    }
  }
  const size_t slice = (size_t)blockIdx.z * ((size_t)gridDim.x * 64 * MT * COUT);
#pragma unroll
  for (int mi = 0; mi < MT; ++mi)
#pragma unroll
    for (int ni = 0; ni < NT; ++ni)
#pragma unroll
      for (int r = 0; r < 4; ++r) {
        const int row = m0 + mi * 16 + quad * 4 + r;
        const int col = n0 + ni * 16 + lrow;
        outf[slice + (size_t)row * COUT + col] = acc[mi][ni][r];
      }
}

// ---------------------------------------------------------------- split-K epi
__global__ __launch_bounds__(256) void sum_relu_s(const float* __restrict__ p,
                                                  unsigned short* __restrict__ o,
                                                  int n, int parts) {
  const int idx = blockIdx.x * 256 + threadIdx.x;
  if (idx < n) {
    float v = 0.f;
    for (int s = 0; s < parts; ++s) v += p[(size_t)s * n + idx];
    o[idx] = f2h(fmaxf(v, 0.f));
  }
}
__global__ __launch_bounds__(256) void sum_relu_f(const float* __restrict__ p,
                                                  float* __restrict__ o,
                                                  int n, int parts) {
  const int idx = blockIdx.x * 256 + threadIdx.x;
  if (idx < n) {
    float v = 0.f;
    for (int s = 0; s < parts; ++s) v += p[(size_t)s * n + idx];
    o[idx] = fmaxf(v, 0.f);
  }
}

// ---------------------------------------------------------------- l2 normalize
// in: single fp16; out: split pair (hi @y, lo @y+loOff).
__global__ __launch_bounds__(64) void l2norm_k(const unsigned short* __restrict__ x,
                                               unsigned short* __restrict__ y,
                                               int loOff) {
  const int lane = threadIdx.x;
  const f16x8 v = *(const f16x8*)(x + (size_t)blockIdx.x * 512 + lane * 8);
  float f[8];
  float s = 0.f;
#pragma unroll
  for (int k = 0; k < 8; ++k) {
    f[k] = (float)v[k];
    s += f[k] * f[k];
  }
#pragma unroll
  for (int off = 32; off; off >>= 1) s += __shfl_xor(s, off, 64);
  const float inv = 1.f / (sqrtf(s) + 1e-6f);
  f16x8 vh, vl;
#pragma unroll
  for (int k = 0; k < 8; ++k) {
    const float nv = f[k] * inv;
    const _Float16 hi = (_Float16)nv;
    vh[k] = hi;
    vl[k] = (_Float16)(nv - (float)hi);
  }
  unsigned short* ph = y + (size_t)blockIdx.x * 512 + lane * 8;
  *(f16x8*)ph = vh;
  *(f16x8*)(ph + (size_t)loOff) = vl;
}

// ---------------------------------------------------------------- dense
__global__ __launch_bounds__(64) void dense_k(const float* __restrict__ r2,
                                              const float* __restrict__ wd,
                                              const float* __restrict__ bd,
                                              float* __restrict__ geo) {
  const int o = blockIdx.x;
  const int b = blockIdx.y;
  const int lane = threadIdx.x;
  const float* __restrict__ rb = r2 + (size_t)b * 2304;
  float s = 0.f;
  for (int k = lane; k < 2304; k += 64) s += rb[k] * wd[(size_t)k * 18 + o];
#pragma unroll
  for (int off = 32; off; off >>= 1) s += __shfl_xor(s, off, 64);
  if (lane == 0) geo[b * 18 + o] = s + bd[o];
}

// ---------------------------------------------------------------- TPS
// LDS-parallel version (R8). One block (1 wave) per batch.
__device__ __forceinline__ float tps_u(float r) { return r * r * logf(r + 1e-6f); }

__global__ __launch_bounds__(64) void tps_k(const float* __restrict__ geo,
                                            float* __restrict__ axb,
                                            float* __restrict__ ayb) {
  const int b = blockIdx.x;
  const int tid = threadIdx.x;
  __shared__ float M[12][14];
  __shared__ float fel[12];
  __shared__ float dxs[9], dys[9];
  __shared__ float th[2][12];   // [0]=x theta, [1]=y theta
  __shared__ float sW[2][9];
  __shared__ float sA[2][3];
  __shared__ int sPiv;

  const float srcx[9] = {0.f, 0.5f, 1.f, 0.f, 0.5f, 1.f, 0.f, 5.f, 1.f};
  const float srcy[9] = {0.f, 0.f, 0.f, 0.5f, 0.5f, 0.5f, 1.f, 1.f, 1.f};

  // dst points + RHS columns (12,13)
  if (tid < 9) {
    const float mx = geo[b * 18 + 2 * tid], my = geo[b * 18 + 2 * tid + 1];
    dxs[tid] = srcx[tid] + mx;
    dys[tid] = srcy[tid] + my;
    M[tid][12] = -mx;
    M[tid][13] = -my;
  } else if (tid < 12) {
    M[tid][12] = 0.f;
    M[tid][13] = 0.f;
  }
  __syncthreads();
  // K block: 81 tps_u entries in parallel
  for (int e = tid; e < 81; e += 64) {
    const int p = e / 9, q = e % 9;
    const float ddx = dxs[p] - dxs[q], ddy = dys[p] - dys[q];
    const float r = sqrtf(ddx * ddx + ddy * ddy + 1e-12f);
    M[p][q] = tps_u(r);
  }
  // P blocks + zero bottom-right 3x3
  if (tid < 9) {
    M[tid][9] = 1.f;  M[tid][10] = dxs[tid]; M[tid][11] = dys[tid];
    M[9][tid] = 1.f;  M[10][tid] = dxs[tid]; M[11][tid] = dys[tid];
  } else if (tid < 12) {
    M[tid][9] = 0.f; M[tid][10] = 0.f; M[tid][11] = 0.f;
  }
  __syncthreads();

  // Gaussian elimination with partial pivoting (same arithmetic/order as R7)
  for (int k = 0; k < 12; ++k) {
    if (tid == 0) {
      int piv = k;
      float best = fabsf(M[k][k]);
      for (int r = k + 1; r < 12; ++r) {
        const float v = fabsf(M[r][k]);
        if (v > best) { best = v; piv = r; }
      }
      sPiv = piv;
    }
    __syncthreads();
    const int piv = sPiv;
    if (piv != k && tid < 14) {
      const float tmp = M[k][tid];
      M[k][tid] = M[piv][tid];
      M[piv][tid] = tmp;
    }
    __syncthreads();
    if (tid > k && tid < 12) fel[tid] = M[tid][k] / M[k][k];
    __syncthreads();
    for (int e = tid; e < (11 - k) * 14; e += 64) {
      const int r = k + 1 + e / 14, cc = e % 14;
      if (cc >= k) M[r][cc] -= fel[r] * M[k][cc];
    }
    __syncthreads();
  }

  // Back substitution: lanes 0-15 -> x (RHS col 12), lanes 16-31 -> y (col 13)
  const int grp = tid >> 4;
  const int cc = tid & 15;
  for (int k = 11; k >= 0; --k) {
    float prod = 0.f;
    if (grp < 2 && cc > k && cc < 12) prod = M[k][cc] * th[grp][cc];
#pragma unroll
    for (int off = 8; off; off >>= 1) prod += __shfl_xor(prod, off, 16);
    if (grp < 2 && cc == 0) th[grp][k] = (M[k][12 + grp] - prod) / M[k][k];
    __syncthreads();
  }

  // w/a extraction: w[0] = -sum(theta[1..8]), w[p]=theta[p], a = theta[9..11]
  if (tid < 2) {
    float sw = 0.f;
    for (int p = 1; p < 9; ++p) {
      sW[tid][p] = th[tid][p];
      sw += th[tid][p];
    }
    sW[tid][0] = -sw;
    sA[tid][0] = th[tid][9];
    sA[tid][1] = th[tid][10];
    sA[tid][2] = th[tid][11];
  }
  __syncthreads();

  // evaluate warp field on the 16x16 grid (4 points per lane)
  for (int p = tid; p < 256; p += 64) {
    const int pi = p >> 4, pj = p & 15;
    const float x = pj * (1.f / 15.f), y = pi * (1.f / 15.f);
    float zx = sA[0][0] + x * sA[0][1] + y * sA[0][2];
    float zy = sA[1][0] + x * sA[1][1] + y * sA[1][2];
#pragma unroll
    for (int c = 0; c < 9; ++c) {
      const float ddx = x - dxs[c], ddy = y - dys[c];
      const float r = sqrtf(ddx * ddx + ddy * ddy + 1e-12f);
      const float u = tps_u(r);
      zx += u * sW[0][c];
      zy += u * sW[1][c];
    }
    axb[b * 256 + p] = (x + zx) * 15.f;
    ayb[b * 256 + p] = (y + zy) * 15.f;
  }
}

// ---------------------------------------------------------------- masked sum
__global__ __launch_bounds__(256) void masksum_k(const float* __restrict__ corr,
                                                 const float* __restrict__ axb,
                                                 const float* __restrict__ ayb,
                                                 float* __restrict__ out) {
  const int b = blockIdx.x;
  const int pB = threadIdx.x;
  const float ax = axb[b * 256 + pB];
  const float ay = ayb[b * 256 + pB];
  const float* __restrict__ cb = corr + (size_t)b * 65536;
  float s = 0.f;
  for (int i = 0; i < 16; ++i) {
    if (fabsf((float)i - ay) <= 1.0f) {
      const float* __restrict__ ci = cb + (size_t)i * 16 * 256 + pB;
      for (int j = 0; j < 16; ++j) {
        if (fabsf((float)j - ax) <= 1.0f) s += ci[(size_t)j * 256];
      }
    }
  }
  __shared__ float sm[256];
  sm[pB] = s;
  __syncthreads();
  for (int off = 128; off; off >>= 1) {
    if (pB < off) sm[pB] += sm[pB + off];
    __syncthreads();
  }
  if (pB == 0) out[b] = sm[0];
}

// ---------------------------------------------------------------- launch
extern "C" void kernel_launch(void* const* d_in, const int* in_sizes, int n_in,
                              void* d_out, int out_size, void* d_ws, size_t ws_size,
                              hipStream_t stream) {
  const float* imgA = (const float*)d_in[0];
  const float* imgB = (const float*)d_in[1];
  const float* W1 = (const float*)d_in[2];
  const float* W2 = (const float*)d_in[3];
  const float* W3 = (const float*)d_in[4];
  const float* W4 = (const float*)d_in[5];
  const float* Wr1 = (const float*)d_in[6];
  const float* Wr2 = (const float*)d_in[7];
  const float* Wd = (const float*)d_in[8];
  const float* bd = (const float*)d_in[9];

  float* ws = (float*)d_ws;
  unsigned short* WT2 = (unsigned short*)(ws + 0);
  unsigned short* WT3 = (unsigned short*)(ws + 36864);
  unsigned short* WT4 = (unsigned short*)(ws + 184320);
  unsigned short* WTr1 = (unsigned short*)(ws + 774144);
  unsigned short* WTr2 = (unsigned short*)(ws + 1576960);
  unsigned short* FEATs = (unsigned short*)(ws + 1679360);
  unsigned short* S2 = (unsigned short*)(ws + 5873664);
  unsigned short* S1 = (unsigned short*)(ws + 14262272);
  unsigned short* S3 = (unsigned short*)(ws + 14262272);    // overlays S1
  unsigned short* FEATsp = (unsigned short*)(ws + 5873664); // overlays S2
  float* CORRf = ws + 14262272;                             // overlays S1/S3
  unsigned short* CORRh = (unsigned short*)(ws + 16359424);
  float* R1p = ws + 17408000;                               // 25 x 409600
  unsigned short* R1h = (unsigned short*)(ws + 27648000);
  float* R2p = ws + 27750400;                               // 25 x 73728
  float* R2f = ws + 29593600;
  float* GEOb = ws + 29667328;
  float* AXb = ws + 29667904;
  float* AYb = ws + 29676096;
  unsigned short* WT1 = (unsigned short*)(ws + 31039488);   // after S1 end
  float* ZPf = ws + 31040512;                               // zero page (4KB)
  const unsigned short* ZP = (const unsigned short*)ZPf;

  // weight prep + zero page (ws is poisoned by harness every iteration)
  zero_fill<<<4, 256, 0, stream>>>(ZPf, 1024);
  wt1_prep<<<8, 256, 0, stream>>>(W1, WT1);
  wt_single<<<288, 256, 0, stream>>>(W2, WT2, 576, 128);
  wt_single<<<1152, 256, 0, stream>>>(W3, WT3, 1152, 256);
  wt_single<<<4608, 256, 0, stream>>>(W4, WT4, 2304, 512);
  wt_single<<<6272, 256, 0, stream>>>(Wr1, WTr1, 12544, 128);
  wt_single<<<800, 256, 0, stream>>>(Wr2, WTr2, 3200, 64);

  for (int img = 0; img < 2; ++img) {
    const float* src = img ? imgB : imgA;
    conv1_mfma<<<dim3(128, 32), 256, 0, stream>>>(src, WT1, S1);
    // conv2: M = 32*4096 = 131072 -> 1024 blocks of 128x128
    tile_conv<128, 128, 64, 128, 3, 3, 2, 1, 0, 1, 0, 0, 1>
        <<<dim3(1024, 1), 256, 0, stream>>>(S1, WT2, S2, nullptr, ZP,
                                            128, 128, 64, 64, 0, 0);
    // conv3: M = 32768 -> 256x2
    tile_conv<128, 128, 128, 256, 3, 3, 2, 1, 0, 1, 0, 0, 1>
        <<<dim3(256, 2), 256, 0, stream>>>(S2, WT3, S3, nullptr, ZP,
                                           64, 64, 32, 32, 0, 0);
    // conv4: M = 8192 -> 128x8 of 64x64 (R13: TLP, 5 blocks/CU)
    tile_conv<64, 64, 256, 512, 3, 3, 2, 1, 0, 1, 0, 0, 1>
        <<<dim3(128, 8), 256, 0, stream>>>(S3, WT4, FEATs + (size_t)img * 4194304,
                                           nullptr, ZP, 32, 32, 16, 16, 0, 0);
  }

  // l2norm: FEATs (single) -> FEATsp (split pair, lo at +8388608 el)
  l2norm_k<<<16384, 64, 0, stream>>>(FEATs, FEATsp, 8388608);
  // corr: tiled split GEMM (batched B), fp32 out + single fp16 hi out
  tile_conv<64, 64, 512, 256, 1, 1, 1, 0, 1, 1, 1, 1, 0>
      <<<dim3(128, 4), 256, 0, stream>>>(FEATsp, FEATsp + 4194304, CORRh, CORRf,
                                         ZP, 16, 16, 16, 16, 8388608, 8388608);
  // conv_r1: 64x64 tiles, split-K 25 (R13) -> fp32 partials
  tile_conv<64, 64, 256, 128, 7, 7, 1, 0, 0, 25, 0, 0, 0>
      <<<dim3(50, 2, 25), 256, 0, stream>>>(CORRh, WTr1, nullptr, R1p, ZP,
                                            16, 16, 10, 10, 0, 0);
  sum_relu_s<<<1600, 256, 0, stream>>>(R1p, R1h, 409600, 25);
  // conv_r2: direct single fp16, split-K 25
  gemm_conv<1, 4, 128, 64, 5, 5, 25>
      <<<dim3(18, 1, 25), 256, 0, stream>>>(R1h, WTr2, R2p, 10, 10, 6, 6);
  sum_relu_f<<<288, 256, 0, stream>>>(R2p, R2f, 73728, 25);
  dense_k<<<dim3(18, 32), 64, 0, stream>>>(R2f, Wd, bd, GEOb);
  tps_k<<<32, 64, 0, stream>>>(GEOb, AXb, AYb);
  masksum_k<<<32, 256, 0, stream>>>(CORRf, AXb, AYb, (float*)d_out);
}

// Round 7
// 454.021 us; speedup vs baseline: 1.0973x; 1.0357x over previous
//
#include <hip/hip_runtime.h>
#include <math.h>

// ---------------------------------------------------------------------------
// Round 14: batch-merge both images + single prep kernel (launch-count cut).
//   R13 counters: no own kernel >39us; time is spread across 24 serialized
//   dispatches. Poison-fill counter proves ws = 256 MiB (single 268MB memset)
//   -> both images' activations fit simultaneously.
//   conv1..conv4 now process BOTH images in one launch each (8 -> 4
//   dispatches); all weight preps + zero-page fused into prep_all (7 -> 1).
//   tile_conv/gemm_conv internals unchanged from R12/R13 (gl16 + XOR swizzle
//   + counted-vmcnt 2-deep pipeline).
//
// Workspace (float units), end 64595968 fl = 258.4 MB < 268.4 MB (256 MiB,
// proven by fill WRITE_SIZE):
//   WT2@0(36864) WT3@36864(147456) WT4@184320(589824)
//   WTr1@774144(802816) WTr2@1576960(102400) -> 1679360
//   FEATs @1679360 (4194304)   both img, 16384 x 512 fp16
//   S3both@5873664 (8388608)   64 x 32x32x256 fp16   [conv3 -> conv4]
//   S2both@14262272 (16777216) 64 x 64x64x128 fp16   [conv2 -> conv3]
//   S1both@31039488 (33554432) 64 x 128x128x64 fp16  [conv1 -> conv2]
//   WT1@64593920 (1024) ZP@64594944 (1024)
//   post-chain overlays (S1/S2/S3 dead after conv4):
//     FEATsp@5873664 (8388608, hi+lo)  CORRf@14262272(2097152)
//     CORRh@16359424(524288)  R1p@17408000(25x409600 -> 27648000)
//     R1h@27648000(102400) R2p@27750400(25x73728) R2f@29593600(73728)
//     GEO@29667328 AX@29667904 AY@29676096 -> end 29684288
// ---------------------------------------------------------------------------

typedef __attribute__((ext_vector_type(8))) _Float16 f16x8;
typedef __attribute__((ext_vector_type(4))) float f32x4;

__device__ __forceinline__ unsigned short f2h(float f) {
  return __builtin_bit_cast(unsigned short, (_Float16)f);
}
__device__ __forceinline__ float h2f(unsigned short u) {
  return (float)__builtin_bit_cast(_Float16, u);
}

// direct global->LDS DMA, 16B per lane (lane-linear LDS dest required)
__device__ __forceinline__ void gl16(const unsigned short* g, _Float16* l) {
  auto* gp = (const __attribute__((address_space(1))) unsigned int*)(g);
  auto* lp = (__attribute__((address_space(3))) unsigned int*)(l);
  __builtin_amdgcn_global_load_lds(gp, lp, 16, 0, 0);
}

// ---------------------------------------------------------------- prep (all)
// One kernel: zero page + WT1 (K-pad transpose) + 5 weight transposes.
__global__ __launch_bounds__(256) void prep_all(
    const float* __restrict__ W1, const float* __restrict__ W2,
    const float* __restrict__ W3, const float* __restrict__ W4,
    const float* __restrict__ Wr1, const float* __restrict__ Wr2,
    unsigned short* __restrict__ WT1, unsigned short* __restrict__ WT2,
    unsigned short* __restrict__ WT3, unsigned short* __restrict__ WT4,
    unsigned short* __restrict__ WTr1, unsigned short* __restrict__ WTr2,
    float* __restrict__ ZPf) {
  long idx = (long)blockIdx.x * 256 + threadIdx.x;
  if (idx < 1024) { ZPf[idx] = 0.f; return; }
  idx -= 1024;
  if (idx < 2048) {  // WT1: [64 out][32 k], k=(di*3+dj)*3+c, zero-pad 27..31
    const int o = (int)idx >> 5, k = (int)idx & 31;
    WT1[idx] = (k < 27) ? f2h(W1[(size_t)k * 64 + o]) : (unsigned short)0;
    return;
  }
  idx -= 2048;
  if (idx < 73728) {  // WT2: K=576, C=128
    const int k = (int)idx / 128, o = (int)idx % 128;
    WT2[(size_t)o * 576 + k] = f2h(W2[idx]);
    return;
  }
  idx -= 73728;
  if (idx < 294912) {  // WT3: K=1152, C=256
    const int k = (int)idx / 256, o = (int)idx % 256;
    WT3[(size_t)o * 1152 + k] = f2h(W3[idx]);
    return;
  }
  idx -= 294912;
  if (idx < 1179648) {  // WT4: K=2304, C=512
    const int k = (int)idx / 512, o = (int)idx % 512;
    WT4[(size_t)o * 2304 + k] = f2h(W4[idx]);
    return;
  }
  idx -= 1179648;
  if (idx < 1605632) {  // WTr1: K=12544, C=128
    const int k = (int)idx / 128, o = (int)idx % 128;
    WTr1[(size_t)o * 12544 + k] = f2h(Wr1[idx]);
    return;
  }
  idx -= 1605632;
  if (idx < 204800) {  // WTr2: K=3200, C=64
    const int k = (int)idx / 64, o = (int)idx % 64;
    WTr2[(size_t)o * 3200 + k] = f2h(Wr2[idx]);
  }
}

// ---------------------------------------------------------------- conv1 MFMA
// Both images in one launch: b = blockIdx.y in 0..63 (img = b>>5).
// One block per (output row i, virtual batch b). 256 threads = 4 waves.
// K = 32 (27 real taps + 5 zero pad) -> single MFMA per 16x16 tile.
__global__ __launch_bounds__(256) void conv1_mfma(const float* __restrict__ inA,
                                                  const float* __restrict__ inB,
                                                  const unsigned short* __restrict__ wt1,
                                                  unsigned short* __restrict__ out) {
  const int i = blockIdx.x;   // output row 0..127
  const int b = blockIdx.y;   // virtual batch 0..63
  const int tid = threadIdx.x;
  const int lane = tid & 63, wid = tid >> 6;
  const int lrow = lane & 15, quad = lane >> 4;

  // Rows[di][x*3+c], x in 0..256 (x=256 is SAME right-pad, zero)
  __shared__ _Float16 Rows[3][771];

  const float* __restrict__ img = (b < 32) ? inA : inB;
  const float* __restrict__ inb = img + (size_t)(b & 31) * 196608;  // 256*256*3
#pragma unroll
  for (int di = 0; di < 3; ++di) {
    const int y = 2 * i + di;
    if (y < 256) {
      const float* __restrict__ row = inb + (size_t)y * 768;
      for (int e = tid; e < 768; e += 256) Rows[di][e] = (_Float16)row[e];
    } else {
      for (int e = tid; e < 768; e += 256) Rows[di][e] = (_Float16)0.f;
    }
    if (tid < 3) Rows[di][768 + tid] = (_Float16)0.f;
  }
  __syncthreads();

  // B fragments: all 64 cols, straight from WT1[64][32]
  f16x8 bf[4];
#pragma unroll
  for (int ni = 0; ni < 4; ++ni)
    bf[ni] = *(const f16x8*)(wt1 + (ni * 16 + lrow) * 32 + quad * 8);

  // A fragments: im2col gather. k=(di*3+dj)*3+c -> di=k/9, dj=(k/3)%3, c=k%3
  f16x8 af[2];
#pragma unroll
  for (int mi = 0; mi < 2; ++mi) {
    const int j = wid * 32 + mi * 16 + lrow;
#pragma unroll
    for (int s = 0; s < 8; ++s) {
      const int k = quad * 8 + s;
      if (k < 27) {
        const int di = k / 9, dj = (k / 3) % 3, c = k % 3;
        af[mi][s] = Rows[di][(2 * j + dj) * 3 + c];
      } else {
        af[mi][s] = (_Float16)0.f;
      }
    }
  }

  f32x4 acc[2][4];
#pragma unroll
  for (int mi = 0; mi < 2; ++mi)
#pragma unroll
    for (int ni = 0; ni < 4; ++ni) {
      const f32x4 z = {0.f, 0.f, 0.f, 0.f};
      acc[mi][ni] = __builtin_amdgcn_mfma_f32_16x16x32_f16(af[mi], bf[ni], z, 0, 0, 0);
    }

  // epilogue: row = quad*4+r, col = lrow (tile_conv layout), fused ReLU
  unsigned short* __restrict__ ob = out + (((size_t)b * 128 + i) * 128) * 64;
#pragma unroll
  for (int mi = 0; mi < 2; ++mi)
#pragma unroll
    for (int ni = 0; ni < 4; ++ni)
#pragma unroll
      for (int r = 0; r < 4; ++r) {
        const int j = wid * 32 + mi * 16 + quad * 4 + r;
        const int col = ni * 16 + lrow;
        ob[(size_t)j * 64 + col] = f2h(fmaxf(acc[mi][ni][r], 0.f));
      }
}

// ---------------------------------------------------------------- tile conv
// LDS-tiled implicit-GEMM, gl16 staging + XOR swizzle + 2-DEEP COUNTED
// PIPELINE (R12):
//   prologue: stage(buf0,c0); stage(buf1,c1)          [2*LPS loads in flight]
//   iter ch:  s_waitcnt vmcnt(LPS) (last: 0) -> sched_barrier -> s_barrier
//             ds_read buf[cur] + MFMA
//             s_barrier (raw, no drain)
//             stage(buf[cur], ch+2)                   [LPS more in flight]
// LDS rows 64 f16 (128B), 8 slots of 16B, slot ^= row&7 both sides.
// SPLIT: A/B hi+lo planes (aLo/bLo el offsets), 3 MFMAs per pair.
// SK>1: split-K over taps, fp32 partial slices. BATB: B batched by A batch.
// OUTF32: fp32 out + fp16 hi out.
template <int BM, int BN, int CIN, int COUT, int KH, int KW, int STRIDE,
          int SAMEPAD, int SPLIT, int SK, int BATB, int OUTF32, int RELU>
__global__ __launch_bounds__(256) void tile_conv(
    const unsigned short* __restrict__ in, const unsigned short* __restrict__ wt,
    unsigned short* __restrict__ outh, float* __restrict__ outf,
    const unsigned short* __restrict__ zp,
    int Hin, int Win, int Hout, int Wout, int aLo, int bLo) {
  constexpr int CPT = CIN / 64;
  constexpr int LA = BM / 32;
  constexpr int LB = BN / 32;
  constexpr int KTOT = KH * KW * CIN;
  constexpr int MT = BM / 32;
  constexpr int NT = BN / 32;
  constexpr int PL = 1 + SPLIT;
  constexpr int LPS = PL * (LA + LB);  // gl16 issues per thread per stage
  // s_waitcnt imm: vmcnt[3:0]|exp[6:4]|lgkm[11:8]|vmcnt_hi[15:14]
  constexpr unsigned WCN =
      (unsigned)((LPS & 0xF) | (0x7 << 4) | (0xF << 8) | ((LPS >> 4) << 14));
  constexpr unsigned WC0 = (unsigned)((0x7 << 4) | (0xF << 8));
  __shared__ _Float16 As[2][PL * BM * 64];
  __shared__ _Float16 Bs[2][PL * BN * 64];

  const int t = threadIdx.x;
  const int lane = t & 63, wid = t >> 6;
  const int lrow = lane & 15, quad = lane >> 4;
  const int m0 = blockIdx.x * BM;
  const int n0 = blockIdx.y * BN;

  // staging: thread t covers row r=(t>>3)+32i, slot sl=t&7 (16B units).
  // source uses swizzled slot q = sl ^ (r&7); (r&7) is i-invariant.
  const int q8 = ((t & 7) ^ ((t >> 3) & 7)) * 8;

  int pixB[LA], iS[LA], jS[LA];
#pragma unroll
  for (int i = 0; i < LA; ++i) {
    const int r = (t >> 3) + 32 * i;
    const int m = m0 + r;
    const int j = m % Wout;
    const int t2 = m / Wout;
    const int ii = t2 % Hout;
    const int b = t2 / Hout;
    iS[i] = ii * STRIDE;
    jS[i] = j * STRIDE;
    pixB[i] = ((b * Hin + iS[i]) * Win + jS[i]) * CIN + q8;
  }
  const unsigned short* wb = wt;
  if (BATB) wb += (size_t)(m0 / (Hout * Wout)) * COUT * KTOT;
  int bofB[LB];
#pragma unroll
  for (int i = 0; i < LB; ++i) {
    const int r = (t >> 3) + 32 * i;
    bofB[i] = (n0 + r) * KTOT + q8;
  }

  f32x4 acc[MT][NT];
#pragma unroll
  for (int mi = 0; mi < MT; ++mi)
#pragma unroll
    for (int ni = 0; ni < NT; ++ni) acc[mi][ni] = {0.f, 0.f, 0.f, 0.f};

  const int mB = (wid >> 1) * (BM / 2);
  const int nB = (wid & 1) * (BN / 2);

  int tap_lo = 0, tap_hi = KH * KW;
  if (SK > 1) {
    tap_lo = (int)blockIdx.z * KH * KW / SK;
    tap_hi = ((int)blockIdx.z + 1) * KH * KW / SK;
  }
  const int ch_lo = tap_lo * CPT, ch_hi = tap_hi * CPT;

  auto stage = [&](int buf, int ch) {
    const int tap = ch / CPT;
    const int c0 = (ch % CPT) * 64;
    const int di = tap / KW, dj = tap % KW;
    const int toff = (di * Win + dj) * CIN + c0;
    const int woff = tap * CIN + c0;
#pragma unroll
    for (int i = 0; i < LA; ++i) {
      const bool ok = !SAMEPAD || ((iS[i] + di < Hin) && (jS[i] + dj < Win));
      const unsigned short* s0 = ok ? in + pixB[i] + toff : zp + q8;
      gl16(s0, &As[buf][t * 8 + 2048 * i]);
      if (SPLIT) {
        const unsigned short* s1 = ok ? in + pixB[i] + toff + aLo : zp + q8;
        gl16(s1, &As[buf][BM * 64 + t * 8 + 2048 * i]);
      }
    }
#pragma unroll
    for (int i = 0; i < LB; ++i) {
      gl16(wb + bofB[i] + woff, &Bs[buf][t * 8 + 2048 * i]);
      if (SPLIT)
        gl16(wb + bofB[i] + woff + bLo, &Bs[buf][BN * 64 + t * 8 + 2048 * i]);
    }
  };

  stage(0, ch_lo);
  if (ch_lo + 1 < ch_hi) stage(1, ch_lo + 1);
  int cur = 0;
  for (int ch = ch_lo; ch < ch_hi; ++ch) {
    // oldest stage (chunk ch) landed; newest (ch+1) stays in flight
    if (ch + 1 < ch_hi) __builtin_amdgcn_s_waitcnt(WCN);
    else __builtin_amdgcn_s_waitcnt(WC0);
    __builtin_amdgcn_sched_barrier(0);
    __builtin_amdgcn_s_barrier();       // all waves' chunk-ch data visible
    __builtin_amdgcn_sched_barrier(0);
#pragma unroll
    for (int ks = 0; ks < 2; ++ks) {
      f16x8 af[MT], bf[NT], al[MT], bl[NT];
#pragma unroll
      for (int mi = 0; mi < MT; ++mi) {
        const int row = mB + mi * 16 + lrow;
        const int off = row * 64 + (((ks * 4 + quad) ^ (row & 7)) * 8);
        af[mi] = *(const f16x8*)&As[cur][off];
        if (SPLIT) al[mi] = *(const f16x8*)&As[cur][BM * 64 + off];
      }
#pragma unroll
      for (int ni = 0; ni < NT; ++ni) {
        const int row = nB + ni * 16 + lrow;
        const int off = row * 64 + (((ks * 4 + quad) ^ (row & 7)) * 8);
        bf[ni] = *(const f16x8*)&Bs[cur][off];
        if (SPLIT) bl[ni] = *(const f16x8*)&Bs[cur][BN * 64 + off];
      }
#pragma unroll
      for (int mi = 0; mi < MT; ++mi)
#pragma unroll
        for (int ni = 0; ni < NT; ++ni) {
          if (SPLIT) {
            acc[mi][ni] = __builtin_amdgcn_mfma_f32_16x16x32_f16(af[mi], bl[ni],
                                                                 acc[mi][ni], 0, 0, 0);
            acc[mi][ni] = __builtin_amdgcn_mfma_f32_16x16x32_f16(al[mi], bf[ni],
                                                                 acc[mi][ni], 0, 0, 0);
          }
          acc[mi][ni] = __builtin_amdgcn_mfma_f32_16x16x32_f16(af[mi], bf[ni],
                                                               acc[mi][ni], 0, 0, 0);
        }
    }
    __builtin_amdgcn_sched_barrier(0);
    __builtin_amdgcn_s_barrier();       // all waves done reading buf[cur]
    __builtin_amdgcn_sched_barrier(0);
    if (ch + 2 < ch_hi) stage(cur, ch + 2);  // overwrite just-freed buffer
    cur ^= 1;
  }
  const size_t slice =
      (SK > 1) ? (size_t)blockIdx.z * ((size_t)gridDim.x * BM * COUT) : 0;
#pragma unroll
  for (int mi = 0; mi < MT; ++mi)
#pragma unroll
    for (int ni = 0; ni < NT; ++ni)
#pragma unroll
      for (int r = 0; r < 4; ++r) {
        const int row = m0 + mB + mi * 16 + quad * 4 + r;
        const int col = n0 + nB + ni * 16 + lrow;
        const size_t idx = (size_t)row * COUT + col;
        float v = acc[mi][ni][r];
        if (SK > 1) {
          outf[slice + idx] = v;
        } else if (OUTF32) {
          outf[idx] = v;
          outh[idx] = f2h(v);
        } else {
          if (RELU) v = fmaxf(v, 0.f);
          outh[idx] = f2h(v);
        }
      }
}

// ---------------------------------------------------------------- direct MFMA
// kept for conv_r2 (tiny), single plane.
template <int MT, int NT, int CIN, int COUT, int KH, int KW, int SK>
__global__ __launch_bounds__(256) void gemm_conv(
    const unsigned short* __restrict__ in, const unsigned short* __restrict__ wt,
    float* __restrict__ outf, int Hin, int Win, int Hout, int Wout) {
  const int KTOT = KH * KW * CIN;
  const int lane = threadIdx.x & 63;
  const int wid = threadIdx.x >> 6;
  const int lrow = lane & 15;
  const int quad = lane >> 4;
  const int m0 = (blockIdx.x * 4 + wid) * (16 * MT);
  const int n0 = blockIdx.y * (16 * NT);

  int pix[MT];
#pragma unroll
  for (int mi = 0; mi < MT; ++mi) {
    const int m = m0 + mi * 16 + lrow;
    const int j = m % Wout;
    const int t = m / Wout;
    const int i = t % Hout;
    const int b = t / Hout;
    pix[mi] = (b * Hin + i) * Win + j;
  }
  const unsigned short* brow[NT];
#pragma unroll
  for (int ni = 0; ni < NT; ++ni)
    brow[ni] = wt + (size_t)(n0 + ni * 16 + lrow) * KTOT + quad * 8;

  f32x4 acc[MT][NT];
#pragma unroll
  for (int mi = 0; mi < MT; ++mi)
#pragma unroll
    for (int ni = 0; ni < NT; ++ni) acc[mi][ni] = {0.f, 0.f, 0.f, 0.f};

  const int tap_lo = (int)blockIdx.z * KH * KW / SK;
  const int tap_hi = ((int)blockIdx.z + 1) * KH * KW / SK;
  for (int tap = tap_lo; tap < tap_hi; ++tap) {
    const int di = tap / KW, dj = tap % KW;
    const unsigned short* ap[MT];
#pragma unroll
    for (int mi = 0; mi < MT; ++mi)
      ap[mi] = in + ((size_t)pix[mi] + di * Win + dj) * CIN + quad * 8;
    const int ko = tap * CIN;
#pragma unroll
    for (int c0 = 0; c0 < CIN; c0 += 32) {
      f16x8 ah[MT], bh[NT];
#pragma unroll
      for (int mi = 0; mi < MT; ++mi) ah[mi] = *(const f16x8*)(ap[mi] + c0);
#pragma unroll
      for (int ni = 0; ni < NT; ++ni) bh[ni] = *(const f16x8*)(brow[ni] + ko + c0);
#pragma unroll
      for (int mi = 0; mi < MT; ++mi)
#pragma unroll
        for (int ni = 0; ni < NT; ++ni)
          acc[mi][ni] = __builtin_amdgcn_mfma_f32_16x16x32_f16(ah[mi], bh[ni],
                                                               acc[mi][ni], 0, 0, 0);
    }
  }
  const size_t slice = (size_t)blockIdx.z * ((size_t)gridDim.x * 64 * MT * COUT);
#pragma unroll
  for (int mi = 0; mi < MT; ++mi)
#pragma unroll
    for (int ni = 0; ni < NT; ++ni)
#pragma unroll
      for (int r = 0; r < 4; ++r) {
        const int row = m0 + mi * 16 + quad * 4 + r;
        const int col = n0 + ni * 16 + lrow;
        outf[slice + (size_t)row * COUT + col] = acc[mi][ni][r];
      }
}

// ---------------------------------------------------------------- split-K epi
__global__ __launch_bounds__(256) void sum_relu_s(const float* __restrict__ p,
                                                  unsigned short* __restrict__ o,
                                                  int n, int parts) {
  const int idx = blockIdx.x * 256 + threadIdx.x;
  if (idx < n) {
    float v = 0.f;
    for (int s = 0; s < parts; ++s) v += p[(size_t)s * n + idx];
    o[idx] = f2h(fmaxf(v, 0.f));
  }
}
__global__ __launch_bounds__(256) void sum_relu_f(const float* __restrict__ p,
                                                  float* __restrict__ o,
                                                  int n, int parts) {
  const int idx = blockIdx.x * 256 + threadIdx.x;
  if (idx < n) {
    float v = 0.f;
    for (int s = 0; s < parts; ++s) v += p[(size_t)s * n + idx];
    o[idx] = fmaxf(v, 0.f);
  }
}

// ---------------------------------------------------------------- l2 normalize
// in: single fp16; out: split pair (hi @y, lo @y+loOff).
__global__ __launch_bounds__(64) void l2norm_k(const unsigned short* __restrict__ x,
                                               unsigned short* __restrict__ y,
                                               int loOff) {
  const int lane = threadIdx.x;
  const f16x8 v = *(const f16x8*)(x + (size_t)blockIdx.x * 512 + lane * 8);
  float f[8];
  float s = 0.f;
#pragma unroll
  for (int k = 0; k < 8; ++k) {
    f[k] = (float)v[k];
    s += f[k] * f[k];
  }
#pragma unroll
  for (int off = 32; off; off >>= 1) s += __shfl_xor(s, off, 64);
  const float inv = 1.f / (sqrtf(s) + 1e-6f);
  f16x8 vh, vl;
#pragma unroll
  for (int k = 0; k < 8; ++k) {
    const float nv = f[k] * inv;
    const _Float16 hi = (_Float16)nv;
    vh[k] = hi;
    vl[k] = (_Float16)(nv - (float)hi);
  }
  unsigned short* ph = y + (size_t)blockIdx.x * 512 + lane * 8;
  *(f16x8*)ph = vh;
  *(f16x8*)(ph + (size_t)loOff) = vl;
}

// ---------------------------------------------------------------- dense
__global__ __launch_bounds__(64) void dense_k(const float* __restrict__ r2,
                                              const float* __restrict__ wd,
                                              const float* __restrict__ bd,
                                              float* __restrict__ geo) {
  const int o = blockIdx.x;
  const int b = blockIdx.y;
  const int lane = threadIdx.x;
  const float* __restrict__ rb = r2 + (size_t)b * 2304;
  float s = 0.f;
  for (int k = lane; k < 2304; k += 64) s += rb[k] * wd[(size_t)k * 18 + o];
#pragma unroll
  for (int off = 32; off; off >>= 1) s += __shfl_xor(s, off, 64);
  if (lane == 0) geo[b * 18 + o] = s + bd[o];
}

// ---------------------------------------------------------------- TPS
// LDS-parallel version (R8). One block (1 wave) per batch.
__device__ __forceinline__ float tps_u(float r) { return r * r * logf(r + 1e-6f); }

__global__ __launch_bounds__(64) void tps_k(const float* __restrict__ geo,
                                            float* __restrict__ axb,
                                            float* __restrict__ ayb) {
  const int b = blockIdx.x;
  const int tid = threadIdx.x;
  __shared__ float M[12][14];
  __shared__ float fel[12];
  __shared__ float dxs[9], dys[9];
  __shared__ float th[2][12];   // [0]=x theta, [1]=y theta
  __shared__ float sW[2][9];
  __shared__ float sA[2][3];
  __shared__ int sPiv;

  const float srcx[9] = {0.f, 0.5f, 1.f, 0.f, 0.5f, 1.f, 0.f, 5.f, 1.f};
  const float srcy[9] = {0.f, 0.f, 0.f, 0.5f, 0.5f, 0.5f, 1.f, 1.f, 1.f};

  // dst points + RHS columns (12,13)
  if (tid < 9) {
    const float mx = geo[b * 18 + 2 * tid], my = geo[b * 18 + 2 * tid + 1];
    dxs[tid] = srcx[tid] + mx;
    dys[tid] = srcy[tid] + my;
    M[tid][12] = -mx;
    M[tid][13] = -my;
  } else if (tid < 12) {
    M[tid][12] = 0.f;
    M[tid][13] = 0.f;
  }
  __syncthreads();
  // K block: 81 tps_u entries in parallel
  for (int e = tid; e < 81; e += 64) {
    const int p = e / 9, q = e % 9;
    const float ddx = dxs[p] - dxs[q], ddy = dys[p] - dys[q];
    const float r = sqrtf(ddx * ddx + ddy * ddy + 1e-12f);
    M[p][q] = tps_u(r);
  }
  // P blocks + zero bottom-right 3x3
  if (tid < 9) {
    M[tid][9] = 1.f;  M[tid][10] = dxs[tid]; M[tid][11] = dys[tid];
    M[9][tid] = 1.f;  M[10][tid] = dxs[tid]; M[11][tid] = dys[tid];
  } else if (tid < 12) {
    M[tid][9] = 0.f; M[tid][10] = 0.f; M[tid][11] = 0.f;
  }
  __syncthreads();

  // Gaussian elimination with partial pivoting (same arithmetic/order as R7)
  for (int k = 0; k < 12; ++k) {
    if (tid == 0) {
      int piv = k;
      float best = fabsf(M[k][k]);
      for (int r = k + 1; r < 12; ++r) {
        const float v = fabsf(M[r][k]);
        if (v > best) { best = v; piv = r; }
      }
      sPiv = piv;
    }
    __syncthreads();
    const int piv = sPiv;
    if (piv != k && tid < 14) {
      const float tmp = M[k][tid];
      M[k][tid] = M[piv][tid];
      M[piv][tid] = tmp;
    }
    __syncthreads();
    if (tid > k && tid < 12) fel[tid] = M[tid][k] / M[k][k];
    __syncthreads();
    for (int e = tid; e < (11 - k) * 14; e += 64) {
      const int r = k + 1 + e / 14, cc = e % 14;
      if (cc >= k) M[r][cc] -= fel[r] * M[k][cc];
    }
    __syncthreads();
  }

  // Back substitution: lanes 0-15 -> x (RHS col 12), lanes 16-31 -> y (col 13)
  const int grp = tid >> 4;
  const int cc = tid & 15;
  for (int k = 11; k >= 0; --k) {
    float prod = 0.f;
    if (grp < 2 && cc > k && cc < 12) prod = M[k][cc] * th[grp][cc];
#pragma unroll
    for (int off = 8; off; off >>= 1) prod += __shfl_xor(prod, off, 16);
    if (grp < 2 && cc == 0) th[grp][k] = (M[k][12 + grp] - prod) / M[k][k];
    __syncthreads();
  }

  // w/a extraction: w[0] = -sum(theta[1..8]), w[p]=theta[p], a = theta[9..11]
  if (tid < 2) {
    float sw = 0.f;
    for (int p = 1; p < 9; ++p) {
      sW[tid][p] = th[tid][p];
      sw += th[tid][p];
    }
    sW[tid][0] = -sw;
    sA[tid][0] = th[tid][9];
    sA[tid][1] = th[tid][10];
    sA[tid][2] = th[tid][11];
  }
  __syncthreads();

  // evaluate warp field on the 16x16 grid (4 points per lane)
  for (int p = tid; p < 256; p += 64) {
    const int pi = p >> 4, pj = p & 15;
    const float x = pj * (1.f / 15.f), y = pi * (1.f / 15.f);
    float zx = sA[0][0] + x * sA[0][1] + y * sA[0][2];
    float zy = sA[1][0] + x * sA[1][1] + y * sA[1][2];
#pragma unroll
    for (int c = 0; c < 9; ++c) {
      const float ddx = x - dxs[c], ddy = y - dys[c];
      const float r = sqrtf(ddx * ddx + ddy * ddy + 1e-12f);
      const float u = tps_u(r);
      zx += u * sW[0][c];
      zy += u * sW[1][c];
    }
    axb[b * 256 + p] = (x + zx) * 15.f;
    ayb[b * 256 + p] = (y + zy) * 15.f;
  }
}

// ---------------------------------------------------------------- masked sum
__global__ __launch_bounds__(256) void masksum_k(const float* __restrict__ corr,
                                                 const float* __restrict__ axb,
                                                 const float* __restrict__ ayb,
                                                 float* __restrict__ out) {
  const int b = blockIdx.x;
  const int pB = threadIdx.x;
  const float ax = axb[b * 256 + pB];
  const float ay = ayb[b * 256 + pB];
  const float* __restrict__ cb = corr + (size_t)b * 65536;
  float s = 0.f;
  for (int i = 0; i < 16; ++i) {
    if (fabsf((float)i - ay) <= 1.0f) {
      const float* __restrict__ ci = cb + (size_t)i * 16 * 256 + pB;
      for (int j = 0; j < 16; ++j) {
        if (fabsf((float)j - ax) <= 1.0f) s += ci[(size_t)j * 256];
      }
    }
  }
  __shared__ float sm[256];
  sm[pB] = s;
  __syncthreads();
  for (int off = 128; off; off >>= 1) {
    if (pB < off) sm[pB] += sm[pB + off];
    __syncthreads();
  }
  if (pB == 0) out[b] = sm[0];
}

// ---------------------------------------------------------------- launch
extern "C" void kernel_launch(void* const* d_in, const int* in_sizes, int n_in,
                              void* d_out, int out_size, void* d_ws, size_t ws_size,
                              hipStream_t stream) {
  const float* imgA = (const float*)d_in[0];
  const float* imgB = (const float*)d_in[1];
  const float* W1 = (const float*)d_in[2];
  const float* W2 = (const float*)d_in[3];
  const float* W3 = (const float*)d_in[4];
  const float* W4 = (const float*)d_in[5];
  const float* Wr1 = (const float*)d_in[6];
  const float* Wr2 = (const float*)d_in[7];
  const float* Wd = (const float*)d_in[8];
  const float* bd = (const float*)d_in[9];

  float* ws = (float*)d_ws;
  unsigned short* WT2 = (unsigned short*)(ws + 0);
  unsigned short* WT3 = (unsigned short*)(ws + 36864);
  unsigned short* WT4 = (unsigned short*)(ws + 184320);
  unsigned short* WTr1 = (unsigned short*)(ws + 774144);
  unsigned short* WTr2 = (unsigned short*)(ws + 1576960);
  unsigned short* FEATs = (unsigned short*)(ws + 1679360);
  unsigned short* S3both = (unsigned short*)(ws + 5873664);
  unsigned short* S2both = (unsigned short*)(ws + 14262272);
  unsigned short* S1both = (unsigned short*)(ws + 31039488);
  unsigned short* FEATsp = (unsigned short*)(ws + 5873664);  // overlays S3both
  float* CORRf = ws + 14262272;                              // overlays S2both
  unsigned short* CORRh = (unsigned short*)(ws + 16359424);
  float* R1p = ws + 17408000;                                // 25 x 409600
  unsigned short* R1h = (unsigned short*)(ws + 27648000);
  float* R2p = ws + 27750400;                                // 25 x 73728
  float* R2f = ws + 29593600;
  float* GEOb = ws + 29667328;
  float* AXb = ws + 29667904;
  float* AYb = ws + 29676096;
  unsigned short* WT1 = (unsigned short*)(ws + 64593920);    // after S1both
  float* ZPf = ws + 64594944;                                // zero page (4KB)
  const unsigned short* ZP = (const unsigned short*)ZPf;

  // single prep kernel: zero page + all weight transposes (ws poisoned/iter)
  prep_all<<<13132, 256, 0, stream>>>(W1, W2, W3, W4, Wr1, Wr2,
                                      WT1, WT2, WT3, WT4, WTr1, WTr2, ZPf);

  // feature chain, both images per launch
  conv1_mfma<<<dim3(128, 64), 256, 0, stream>>>(imgA, imgB, WT1, S1both);
  // conv2: M = 64*4096 = 262144 -> 2048 blocks of 128x128
  tile_conv<128, 128, 64, 128, 3, 3, 2, 1, 0, 1, 0, 0, 1>
      <<<dim3(2048, 1), 256, 0, stream>>>(S1both, WT2, S2both, nullptr, ZP,
                                          128, 128, 64, 64, 0, 0);
  // conv3: M = 64*1024 = 65536 -> 512x2 of 128x128
  tile_conv<128, 128, 128, 256, 3, 3, 2, 1, 0, 1, 0, 0, 1>
      <<<dim3(512, 2), 256, 0, stream>>>(S2both, WT3, S3both, nullptr, ZP,
                                         64, 64, 32, 32, 0, 0);
  // conv4: M = 64*256 = 16384 -> 256x8 of 64x64 (writes both imgs' FEATs)
  tile_conv<64, 64, 256, 512, 3, 3, 2, 1, 0, 1, 0, 0, 1>
      <<<dim3(256, 8), 256, 0, stream>>>(S3both, WT4, FEATs, nullptr, ZP,
                                         32, 32, 16, 16, 0, 0);

  // l2norm: FEATs (single) -> FEATsp (split pair, lo at +8388608 el)
  l2norm_k<<<16384, 64, 0, stream>>>(FEATs, FEATsp, 8388608);
  // corr: tiled split GEMM (batched B), fp32 out + single fp16 hi out
  tile_conv<64, 64, 512, 256, 1, 1, 1, 0, 1, 1, 1, 1, 0>
      <<<dim3(128, 4), 256, 0, stream>>>(FEATsp, FEATsp + 4194304, CORRh, CORRf,
                                         ZP, 16, 16, 16, 16, 8388608, 8388608);
  // conv_r1: 64x64 tiles, split-K 25 -> fp32 partials
  tile_conv<64, 64, 256, 128, 7, 7, 1, 0, 0, 25, 0, 0, 0>
      <<<dim3(50, 2, 25), 256, 0, stream>>>(CORRh, WTr1, nullptr, R1p, ZP,
                                            16, 16, 10, 10, 0, 0);
  sum_relu_s<<<1600, 256, 0, stream>>>(R1p, R1h, 409600, 25);
  // conv_r2: direct single fp16, split-K 25
  gemm_conv<1, 4, 128, 64, 5, 5, 25>
      <<<dim3(18, 1, 25), 256, 0, stream>>>(R1h, WTr2, R2p, 10, 10, 6, 6);
  sum_relu_f<<<288, 256, 0, stream>>>(R2p, R2f, 73728, 25);
  dense_k<<<dim3(18, 32), 64, 0, stream>>>(R2f, Wd, bd, GEOb);
  tps_k<<<32, 64, 0, stream>>>(GEOb, AXb, AYb);
  masksum_k<<<32, 256, 0, stream>>>(CORRf, AXb, AYb, (float*)d_out);
}

// Round 9
// 443.012 us; speedup vs baseline: 1.1245x; 1.0249x over previous
//
#include <hip/hip_runtime.h>
#include <math.h>

// ---------------------------------------------------------------------------
// Round 16 = Round 15 resubmit (container failed twice = infra flake; kernel
// audit found no compile/alignment/barrier hazards).
//   R15: vectorized conv1 staging + LDS-bounce coalesced epilogues.
//   R14 counters: conv1_mfma 69us (HBM 31% vs 29us floor; scalar f32 staging
//   loads + 32 scalar ushort stores/thread); tile_conv epilogues likewise 64
//   scalar stores/thread (~20% tail).
//   conv1 stages via float4->f16x4; all non-SK tile_conv epilogues and
//   conv1's epilogue bounce acc through XOR-swizzled LDS and emit 16B
//   coalesced stores. K-loop schedule (gl16 + XOR swizzle + counted-vmcnt
//   2-deep pipeline) untouched.
//
// Workspace (float units), end 64595968 fl = 258.4 MB < 268.4 MB (256 MiB):
//   WT2@0(36864) WT3@36864(147456) WT4@184320(589824)
//   WTr1@774144(802816) WTr2@1576960(102400) -> 1679360
//   FEATs @1679360 (4194304)   both img, 16384 x 512 fp16
//   S3both@5873664 (8388608)   64 x 32x32x256 fp16
//   S2both@14262272 (16777216) 64 x 64x64x128 fp16
//   S1both@31039488 (33554432) 64 x 128x128x64 fp16
//   WT1@64593920 (1024) ZP@64594944 (1024)
//   post-chain overlays: FEATsp@5873664 CORRf@14262272(2097152)
//     CORRh@16359424(524288) R1p@17408000(25x409600) R1h@27648000
//     R2p@27750400(25x73728) R2f@29593600 GEO@29667328 AX@29667904
//     AY@29676096 -> end 29684288
// ---------------------------------------------------------------------------

typedef __attribute__((ext_vector_type(8))) _Float16 f16x8;
typedef __attribute__((ext_vector_type(4))) _Float16 f16x4;
typedef __attribute__((ext_vector_type(4))) float f32x4;

__device__ __forceinline__ unsigned short f2h(float f) {
  return __builtin_bit_cast(unsigned short, (_Float16)f);
}

// direct global->LDS DMA, 16B per lane (lane-linear LDS dest required)
__device__ __forceinline__ void gl16(const unsigned short* g, _Float16* l) {
  auto* gp = (const __attribute__((address_space(1))) unsigned int*)(g);
  auto* lp = (__attribute__((address_space(3))) unsigned int*)(l);
  __builtin_amdgcn_global_load_lds(gp, lp, 16, 0, 0);
}

// ---------------------------------------------------------------- prep (all)
__global__ __launch_bounds__(256) void prep_all(
    const float* __restrict__ W1, const float* __restrict__ W2,
    const float* __restrict__ W3, const float* __restrict__ W4,
    const float* __restrict__ Wr1, const float* __restrict__ Wr2,
    unsigned short* __restrict__ WT1, unsigned short* __restrict__ WT2,
    unsigned short* __restrict__ WT3, unsigned short* __restrict__ WT4,
    unsigned short* __restrict__ WTr1, unsigned short* __restrict__ WTr2,
    float* __restrict__ ZPf) {
  long idx = (long)blockIdx.x * 256 + threadIdx.x;
  if (idx < 1024) { ZPf[idx] = 0.f; return; }
  idx -= 1024;
  if (idx < 2048) {  // WT1: [64 out][32 k], k=(di*3+dj)*3+c, zero-pad 27..31
    const int o = (int)idx >> 5, k = (int)idx & 31;
    WT1[idx] = (k < 27) ? f2h(W1[(size_t)k * 64 + o]) : (unsigned short)0;
    return;
  }
  idx -= 2048;
  if (idx < 73728) {  // WT2: K=576, C=128
    const int k = (int)idx / 128, o = (int)idx % 128;
    WT2[(size_t)o * 576 + k] = f2h(W2[idx]);
    return;
  }
  idx -= 73728;
  if (idx < 294912) {  // WT3: K=1152, C=256
    const int k = (int)idx / 256, o = (int)idx % 256;
    WT3[(size_t)o * 1152 + k] = f2h(W3[idx]);
    return;
  }
  idx -= 294912;
  if (idx < 1179648) {  // WT4: K=2304, C=512
    const int k = (int)idx / 512, o = (int)idx % 512;
    WT4[(size_t)o * 2304 + k] = f2h(W4[idx]);
    return;
  }
  idx -= 1179648;
  if (idx < 1605632) {  // WTr1: K=12544, C=128
    const int k = (int)idx / 128, o = (int)idx % 128;
    WTr1[(size_t)o * 12544 + k] = f2h(Wr1[idx]);
    return;
  }
  idx -= 1605632;
  if (idx < 204800) {  // WTr2: K=3200, C=64
    const int k = (int)idx / 64, o = (int)idx % 64;
    WTr2[(size_t)o * 3200 + k] = f2h(Wr2[idx]);
  }
}

// ---------------------------------------------------------------- conv1 MFMA
// Both images per launch (b 0..63). One block per (out row i, batch b).
// float4 vector staging; LDS-bounce epilogue with 16B coalesced stores.
__global__ __launch_bounds__(256) void conv1_mfma(const float* __restrict__ inA,
                                                  const float* __restrict__ inB,
                                                  const unsigned short* __restrict__ wt1,
                                                  unsigned short* __restrict__ out) {
  const int i = blockIdx.x;   // output row 0..127
  const int b = blockIdx.y;   // virtual batch 0..63
  const int tid = threadIdx.x;
  const int lane = tid & 63, wid = tid >> 6;
  const int lrow = lane & 15, quad = lane >> 4;

  __shared__ _Float16 Rows[3][776];   // 8B-aligned rows; [768..770] = pad
  __shared__ _Float16 OutB[8192];     // 128 j x 64 ch bounce

  const float* __restrict__ img = (b < 32) ? inA : inB;
  const float* __restrict__ inb = img + (size_t)(b & 31) * 196608;
  const f16x4 z4 = {0, 0, 0, 0};
#pragma unroll
  for (int di = 0; di < 3; ++di) {
    const int y = 2 * i + di;
    if (tid < 192) {
      f16x4 h4 = z4;
      if (y < 256) {
        const float4 v4 = *(const float4*)(inb + (size_t)y * 768 + tid * 4);
        h4[0] = (_Float16)v4.x; h4[1] = (_Float16)v4.y;
        h4[2] = (_Float16)v4.z; h4[3] = (_Float16)v4.w;
      }
      *(f16x4*)&Rows[di][tid * 4] = h4;
    }
    if (tid < 3) Rows[di][768 + tid] = (_Float16)0.f;
  }
  __syncthreads();

  // B fragments: all 64 cols, straight from WT1[64][32]
  f16x8 bf[4];
#pragma unroll
  for (int ni = 0; ni < 4; ++ni)
    bf[ni] = *(const f16x8*)(wt1 + (ni * 16 + lrow) * 32 + quad * 8);

  // A fragments: im2col gather. k=(di*3+dj)*3+c -> di=k/9, dj=(k/3)%3, c=k%3
  f16x8 af[2];
#pragma unroll
  for (int mi = 0; mi < 2; ++mi) {
    const int j = wid * 32 + mi * 16 + lrow;
#pragma unroll
    for (int s = 0; s < 8; ++s) {
      const int k = quad * 8 + s;
      if (k < 27) {
        const int di = k / 9, dj = (k / 3) % 3, c = k % 3;
        af[mi][s] = Rows[di][(2 * j + dj) * 3 + c];
      } else {
        af[mi][s] = (_Float16)0.f;
      }
    }
  }

  f32x4 acc[2][4];
#pragma unroll
  for (int mi = 0; mi < 2; ++mi)
#pragma unroll
    for (int ni = 0; ni < 4; ++ni) {
      const f32x4 z = {0.f, 0.f, 0.f, 0.f};
      acc[mi][ni] = __builtin_amdgcn_mfma_f32_16x16x32_f16(af[mi], bf[ni], z, 0, 0, 0);
    }

  // bounce: j = wid*32+mi*16+quad*4+r, ch = ni*16+lrow; swizzle ch bits 4-5
#pragma unroll
  for (int mi = 0; mi < 2; ++mi)
#pragma unroll
    for (int ni = 0; ni < 4; ++ni)
#pragma unroll
      for (int r = 0; r < 4; ++r) {
        const int j = wid * 32 + mi * 16 + quad * 4 + r;
        const int ch = ni * 16 + lrow;
        OutB[j * 64 + (ch ^ (((j >> 2) & 3) << 4))] =
            (_Float16)fmaxf(acc[mi][ni][r], 0.f);
      }
  __syncthreads();

  unsigned short* __restrict__ ob = out + (((size_t)b * 128 + i) * 128) * 64;
#pragma unroll
  for (int q2 = 0; q2 < 4; ++q2) {
    const int v = tid + 256 * q2;
    const int j = v >> 3, c0 = (v & 7) * 8;
    const f16x8 pack = *(const f16x8*)&OutB[j * 64 + (c0 ^ (((j >> 2) & 3) << 4))];
    *(f16x8*)&ob[(size_t)j * 64 + c0] = pack;
  }
}

// ---------------------------------------------------------------- tile conv
// LDS-tiled implicit-GEMM, gl16 staging + XOR swizzle + 2-deep counted
// pipeline (R12). Non-SK epilogues bounce fp16 output through As
// (dead after final s_barrier) -> 16B coalesced stores.
template <int BM, int BN, int CIN, int COUT, int KH, int KW, int STRIDE,
          int SAMEPAD, int SPLIT, int SK, int BATB, int OUTF32, int RELU>
__global__ __launch_bounds__(256) void tile_conv(
    const unsigned short* __restrict__ in, const unsigned short* __restrict__ wt,
    unsigned short* __restrict__ outh, float* __restrict__ outf,
    const unsigned short* __restrict__ zp,
    int Hin, int Win, int Hout, int Wout, int aLo, int bLo) {
  constexpr int CPT = CIN / 64;
  constexpr int LA = BM / 32;
  constexpr int LB = BN / 32;
  constexpr int KTOT = KH * KW * CIN;
  constexpr int MT = BM / 32;
  constexpr int NT = BN / 32;
  constexpr int PL = 1 + SPLIT;
  constexpr int LPS = PL * (LA + LB);  // gl16 issues per thread per stage
  // s_waitcnt imm: vmcnt[3:0]|exp[6:4]|lgkm[11:8]|vmcnt_hi[15:14]
  constexpr unsigned WCN =
      (unsigned)((LPS & 0xF) | (0x7 << 4) | (0xF << 8) | ((LPS >> 4) << 14));
  constexpr unsigned WC0 = (unsigned)((0x7 << 4) | (0xF << 8));
  __shared__ _Float16 As[2][PL * BM * 64];
  __shared__ _Float16 Bs[2][PL * BN * 64];
  static_assert(SK > 1 || (size_t)BM * BN <= sizeof(As) / sizeof(_Float16),
                "bounce must fit in As");

  const int t = threadIdx.x;
  const int lane = t & 63, wid = t >> 6;
  const int lrow = lane & 15, quad = lane >> 4;
  const int m0 = blockIdx.x * BM;
  const int n0 = blockIdx.y * BN;

  // staging: thread t covers row r=(t>>3)+32i, slot sl=t&7 (16B units).
  // source uses swizzled slot q = sl ^ (r&7); (r&7) is i-invariant.
  const int q8 = ((t & 7) ^ ((t >> 3) & 7)) * 8;

  int pixB[LA], iS[LA], jS[LA];
#pragma unroll
  for (int i = 0; i < LA; ++i) {
    const int r = (t >> 3) + 32 * i;
    const int m = m0 + r;
    const int j = m % Wout;
    const int t2 = m / Wout;
    const int ii = t2 % Hout;
    const int b = t2 / Hout;
    iS[i] = ii * STRIDE;
    jS[i] = j * STRIDE;
    pixB[i] = ((b * Hin + iS[i]) * Win + jS[i]) * CIN + q8;
  }
  const unsigned short* wb = wt;
  if (BATB) wb += (size_t)(m0 / (Hout * Wout)) * COUT * KTOT;
  int bofB[LB];
#pragma unroll
  for (int i = 0; i < LB; ++i) {
    const int r = (t >> 3) + 32 * i;
    bofB[i] = (n0 + r) * KTOT + q8;
  }

  f32x4 acc[MT][NT];
#pragma unroll
  for (int mi = 0; mi < MT; ++mi)
#pragma unroll
    for (int ni = 0; ni < NT; ++ni) acc[mi][ni] = {0.f, 0.f, 0.f, 0.f};

  const int mB = (wid >> 1) * (BM / 2);
  const int nB = (wid & 1) * (BN / 2);

  int tap_lo = 0, tap_hi = KH * KW;
  if (SK > 1) {
    tap_lo = (int)blockIdx.z * KH * KW / SK;
    tap_hi = ((int)blockIdx.z + 1) * KH * KW / SK;
  }
  const int ch_lo = tap_lo * CPT, ch_hi = tap_hi * CPT;

  auto stage = [&](int buf, int ch) {
    const int tap = ch / CPT;
    const int c0 = (ch % CPT) * 64;
    const int di = tap / KW, dj = tap % KW;
    const int toff = (di * Win + dj) * CIN + c0;
    const int woff = tap * CIN + c0;
#pragma unroll
    for (int i = 0; i < LA; ++i) {
      const bool ok = !SAMEPAD || ((iS[i] + di < Hin) && (jS[i] + dj < Win));
      const unsigned short* s0 = ok ? in + pixB[i] + toff : zp + q8;
      gl16(s0, &As[buf][t * 8 + 2048 * i]);
      if (SPLIT) {
        const unsigned short* s1 = ok ? in + pixB[i] + toff + aLo : zp + q8;
        gl16(s1, &As[buf][BM * 64 + t * 8 + 2048 * i]);
      }
    }
#pragma unroll
    for (int i = 0; i < LB; ++i) {
      gl16(wb + bofB[i] + woff, &Bs[buf][t * 8 + 2048 * i]);
      if (SPLIT)
        gl16(wb + bofB[i] + woff + bLo, &Bs[buf][BN * 64 + t * 8 + 2048 * i]);
    }
  };

  stage(0, ch_lo);
  if (ch_lo + 1 < ch_hi) stage(1, ch_lo + 1);
  int cur = 0;
  for (int ch = ch_lo; ch < ch_hi; ++ch) {
    // oldest stage (chunk ch) landed; newest (ch+1) stays in flight
    if (ch + 1 < ch_hi) __builtin_amdgcn_s_waitcnt(WCN);
    else __builtin_amdgcn_s_waitcnt(WC0);
    __builtin_amdgcn_sched_barrier(0);
    __builtin_amdgcn_s_barrier();       // all waves' chunk-ch data visible
    __builtin_amdgcn_sched_barrier(0);
#pragma unroll
    for (int ks = 0; ks < 2; ++ks) {
      f16x8 af[MT], bf[NT], al[MT], bl[NT];
#pragma unroll
      for (int mi = 0; mi < MT; ++mi) {
        const int row = mB + mi * 16 + lrow;
        const int off = row * 64 + (((ks * 4 + quad) ^ (row & 7)) * 8);
        af[mi] = *(const f16x8*)&As[cur][off];
        if (SPLIT) al[mi] = *(const f16x8*)&As[cur][BM * 64 + off];
      }
#pragma unroll
      for (int ni = 0; ni < NT; ++ni) {
        const int row = nB + ni * 16 + lrow;
        const int off = row * 64 + (((ks * 4 + quad) ^ (row & 7)) * 8);
        bf[ni] = *(const f16x8*)&Bs[cur][off];
        if (SPLIT) bl[ni] = *(const f16x8*)&Bs[cur][BN * 64 + off];
      }
#pragma unroll
      for (int mi = 0; mi < MT; ++mi)
#pragma unroll
        for (int ni = 0; ni < NT; ++ni) {
          if (SPLIT) {
            acc[mi][ni] = __builtin_amdgcn_mfma_f32_16x16x32_f16(af[mi], bl[ni],
                                                                 acc[mi][ni], 0, 0, 0);
            acc[mi][ni] = __builtin_amdgcn_mfma_f32_16x16x32_f16(al[mi], bf[ni],
                                                                 acc[mi][ni], 0, 0, 0);
          }
          acc[mi][ni] = __builtin_amdgcn_mfma_f32_16x16x32_f16(af[mi], bf[ni],
                                                               acc[mi][ni], 0, 0, 0);
        }
    }
    __builtin_amdgcn_sched_barrier(0);
    __builtin_amdgcn_s_barrier();       // all waves done reading buf[cur]
    __builtin_amdgcn_sched_barrier(0);
    if (ch + 2 < ch_hi) stage(cur, ch + 2);  // overwrite just-freed buffer
    cur ^= 1;
  }

  if (SK > 1) {
    const size_t slice = (size_t)blockIdx.z * ((size_t)gridDim.x * BM * COUT);
#pragma unroll
    for (int mi = 0; mi < MT; ++mi)
#pragma unroll
      for (int ni = 0; ni < NT; ++ni)
#pragma unroll
        for (int r = 0; r < 4; ++r) {
          const int row = m0 + mB + mi * 16 + quad * 4 + r;
          const int col = n0 + nB + ni * 16 + lrow;
          outf[slice + (size_t)row * COUT + col] = acc[mi][ni][r];
        }
  } else {
    // LDS bounce (As is dead: final s_barrier above). Swizzle col bits 4-5.
    _Float16* bounce = &As[0][0];
#pragma unroll
    for (int mi = 0; mi < MT; ++mi)
#pragma unroll
      for (int ni = 0; ni < NT; ++ni)
#pragma unroll
        for (int r = 0; r < 4; ++r) {
          const int row = mB + mi * 16 + quad * 4 + r;
          const int col = nB + ni * 16 + lrow;
          float v = acc[mi][ni][r];
          if (OUTF32) {
            outf[(size_t)(m0 + row) * COUT + n0 + col] = v;
          } else if (RELU) {
            v = fmaxf(v, 0.f);
          }
          bounce[row * BN + (col ^ (((row >> 2) & 3) << 4))] = (_Float16)v;
        }
    __syncthreads();
    constexpr int VPT = (BM * BN / 8) / 256;
#pragma unroll
    for (int q2 = 0; q2 < VPT; ++q2) {
      const int v = t + 256 * q2;
      const int rowL = v / (BN / 8);
      const int c0 = (v % (BN / 8)) * 8;
      const f16x8 pack =
          *(const f16x8*)&bounce[rowL * BN + (c0 ^ (((rowL >> 2) & 3) << 4))];
      *(f16x8*)&outh[(size_t)(m0 + rowL) * COUT + n0 + c0] = pack;
    }
  }
}

// ---------------------------------------------------------------- direct MFMA
// kept for conv_r2 (tiny), single plane.
template <int MT, int NT, int CIN, int COUT, int KH, int KW, int SK>
__global__ __launch_bounds__(256) void gemm_conv(
    const unsigned short* __restrict__ in, const unsigned short* __restrict__ wt,
    float* __restrict__ outf, int Hin, int Win, int Hout, int Wout) {
  const int KTOT = KH * KW * CIN;
  const int lane = threadIdx.x & 63;
  const int wid = threadIdx.x >> 6;
  const int lrow = lane & 15;
  const int quad = lane >> 4;
  const int m0 = (blockIdx.x * 4 + wid) * (16 * MT);
  const int n0 = blockIdx.y * (16 * NT);

  int pix[MT];
#pragma unroll
  for (int mi = 0; mi < MT; ++mi) {
    const int m = m0 + mi * 16 + lrow;
    const int j = m % Wout;
    const int t = m / Wout;
    const int i = t % Hout;
    const int b = t / Hout;
    pix[mi] = (b * Hin + i) * Win + j;
  }
  const unsigned short* brow[NT];
#pragma unroll
  for (int ni = 0; ni < NT; ++ni)
    brow[ni] = wt + (size_t)(n0 + ni * 16 + lrow) * KTOT + quad * 8;

  f32x4 acc[MT][NT];
#pragma unroll
  for (int mi = 0; mi < MT; ++mi)
#pragma unroll
    for (int ni = 0; ni < NT; ++ni) acc[mi][ni] = {0.f, 0.f, 0.f, 0.f};

  const int tap_lo = (int)blockIdx.z * KH * KW / SK;
  const int tap_hi = ((int)blockIdx.z + 1) * KH * KW / SK;
  for (int tap = tap_lo; tap < tap_hi; ++tap) {
    const int di = tap / KW, dj = tap % KW;
    const unsigned short* ap[MT];
#pragma unroll
    for (int mi = 0; mi < MT; ++mi)
      ap[mi] = in + ((size_t)pix[mi] + di * Win + dj) * CIN + quad * 8;
    const int ko = tap * CIN;
#pragma unroll
    for (int c0 = 0; c0 < CIN; c0 += 32) {
      f16x8 ah[MT], bh[NT];
#pragma unroll
      for (int mi = 0; mi < MT; ++mi) ah[mi] = *(const f16x8*)(ap[mi] + c0);
#pragma unroll
      for (int ni = 0; ni < NT; ++ni) bh[ni] = *(const f16x8*)(brow[ni] + ko + c0);
#pragma unroll
      for (int mi = 0; mi < MT; ++mi)
#pragma unroll
        for (int ni = 0; ni < NT; ++ni)
          acc[mi][ni] = __builtin_amdgcn_mfma_f32_16x16x32_f16(ah[mi], bh[ni],
                                                               acc[mi][ni], 0, 0, 0);
    }
  }
  const size_t slice = (size_t)blockIdx.z * ((size_t)gridDim.x * 64 * MT * COUT);
#pragma unroll
  for (int mi = 0; mi < MT; ++mi)
#pragma unroll
    for (int ni = 0; ni < NT; ++ni)
#pragma unroll
      for (int r = 0; r < 4; ++r) {
        const int row = m0 + mi * 16 + quad * 4 + r;
        const int col = n0 + ni * 16 + lrow;
        outf[slice + (size_t)row * COUT + col] = acc[mi][ni][r];
      }
}

// ---------------------------------------------------------------- split-K epi
__global__ __launch_bounds__(256) void sum_relu_s(const float* __restrict__ p,
                                                  unsigned short* __restrict__ o,
                                                  int n, int parts) {
  const int idx = blockIdx.x * 256 + threadIdx.x;
  if (idx < n) {
    float v = 0.f;
    for (int s = 0; s < parts; ++s) v += p[(size_t)s * n + idx];
    o[idx] = f2h(fmaxf(v, 0.f));
  }
}
__global__ __launch_bounds__(256) void sum_relu_f(const float* __restrict__ p,
                                                  float* __restrict__ o,
                                                  int n, int parts) {
  const int idx = blockIdx.x * 256 + threadIdx.x;
  if (idx < n) {
    float v = 0.f;
    for (int s = 0; s < parts; ++s) v += p[(size_t)s * n + idx];
    o[idx] = fmaxf(v, 0.f);
  }
}

// ---------------------------------------------------------------- l2 normalize
// in: single fp16; out: split pair (hi @y, lo @y+loOff).
__global__ __launch_bounds__(64) void l2norm_k(const unsigned short* __restrict__ x,
                                               unsigned short* __restrict__ y,
                                               int loOff) {
  const int lane = threadIdx.x;
  const f16x8 v = *(const f16x8*)(x + (size_t)blockIdx.x * 512 + lane * 8);
  float f[8];
  float s = 0.f;
#pragma unroll
  for (int k = 0; k < 8; ++k) {
    f[k] = (float)v[k];
    s += f[k] * f[k];
  }
#pragma unroll
  for (int off = 32; off; off >>= 1) s += __shfl_xor(s, off, 64);
  const float inv = 1.f / (sqrtf(s) + 1e-6f);
  f16x8 vh, vl;
#pragma unroll
  for (int k = 0; k < 8; ++k) {
    const float nv = f[k] * inv;
    const _Float16 hi = (_Float16)nv;
    vh[k] = hi;
    vl[k] = (_Float16)(nv - (float)hi);
  }
  unsigned short* ph = y + (size_t)blockIdx.x * 512 + lane * 8;
  *(f16x8*)ph = vh;
  *(f16x8*)(ph + (size_t)loOff) = vl;
}

// ---------------------------------------------------------------- dense
__global__ __launch_bounds__(64) void dense_k(const float* __restrict__ r2,
                                              const float* __restrict__ wd,
                                              const float* __restrict__ bd,
                                              float* __restrict__ geo) {
  const int o = blockIdx.x;
  const int b = blockIdx.y;
  const int lane = threadIdx.x;
  const float* __restrict__ rb = r2 + (size_t)b * 2304;
  float s = 0.f;
  for (int k = lane; k < 2304; k += 64) s += rb[k] * wd[(size_t)k * 18 + o];
#pragma unroll
  for (int off = 32; off; off >>= 1) s += __shfl_xor(s, off, 64);
  if (lane == 0) geo[b * 18 + o] = s + bd[o];
}

// ---------------------------------------------------------------- TPS
// LDS-parallel version (R8). One block (1 wave) per batch.
__device__ __forceinline__ float tps_u(float r) { return r * r * logf(r + 1e-6f); }

__global__ __launch_bounds__(64) void tps_k(const float* __restrict__ geo,
                                            float* __restrict__ axb,
                                            float* __restrict__ ayb) {
  const int b = blockIdx.x;
  const int tid = threadIdx.x;
  __shared__ float M[12][14];
  __shared__ float fel[12];
  __shared__ float dxs[9], dys[9];
  __shared__ float th[2][12];   // [0]=x theta, [1]=y theta
  __shared__ float sW[2][9];
  __shared__ float sA[2][3];
  __shared__ int sPiv;

  const float srcx[9] = {0.f, 0.5f, 1.f, 0.f, 0.5f, 1.f, 0.f, 5.f, 1.f};
  const float srcy[9] = {0.f, 0.f, 0.f, 0.5f, 0.5f, 0.5f, 1.f, 1.f, 1.f};

  // dst points + RHS columns (12,13)
  if (tid < 9) {
    const float mx = geo[b * 18 + 2 * tid], my = geo[b * 18 + 2 * tid + 1];
    dxs[tid] = srcx[tid] + mx;
    dys[tid] = srcy[tid] + my;
    M[tid][12] = -mx;
    M[tid][13] = -my;
  } else if (tid < 12) {
    M[tid][12] = 0.f;
    M[tid][13] = 0.f;
  }
  __syncthreads();
  // K block: 81 tps_u entries in parallel
  for (int e = tid; e < 81; e += 64) {
    const int p = e / 9, q = e % 9;
    const float ddx = dxs[p] - dxs[q], ddy = dys[p] - dys[q];
    const float r = sqrtf(ddx * ddx + ddy * ddy + 1e-12f);
    M[p][q] = tps_u(r);
  }
  // P blocks + zero bottom-right 3x3
  if (tid < 9) {
    M[tid][9] = 1.f;  M[tid][10] = dxs[tid]; M[tid][11] = dys[tid];
    M[9][tid] = 1.f;  M[10][tid] = dxs[tid]; M[11][tid] = dys[tid];
  } else if (tid < 12) {
    M[tid][9] = 0.f; M[tid][10] = 0.f; M[tid][11] = 0.f;
  }
  __syncthreads();

  // Gaussian elimination with partial pivoting (same arithmetic/order as R7)
  for (int k = 0; k < 12; ++k) {
    if (tid == 0) {
      int piv = k;
      float best = fabsf(M[k][k]);
      for (int r = k + 1; r < 12; ++r) {
        const float v = fabsf(M[r][k]);
        if (v > best) { best = v; piv = r; }
      }
      sPiv = piv;
    }
    __syncthreads();
    const int piv = sPiv;
    if (piv != k && tid < 14) {
      const float tmp = M[k][tid];
      M[k][tid] = M[piv][tid];
      M[piv][tid] = tmp;
    }
    __syncthreads();
    if (tid > k && tid < 12) fel[tid] = M[tid][k] / M[k][k];
    __syncthreads();
    for (int e = tid; e < (11 - k) * 14; e += 64) {
      const int r = k + 1 + e / 14, cc = e % 14;
      if (cc >= k) M[r][cc] -= fel[r] * M[k][cc];
    }
    __syncthreads();
  }

  // Back substitution: lanes 0-15 -> x (RHS col 12), lanes 16-31 -> y (col 13)
  const int grp = tid >> 4;
  const int cc = tid & 15;
  for (int k = 11; k >= 0; --k) {
    float prod = 0.f;
    if (grp < 2 && cc > k && cc < 12) prod = M[k][cc] * th[grp][cc];
#pragma unroll
    for (int off = 8; off; off >>= 1) prod += __shfl_xor(prod, off, 16);
    if (grp < 2 && cc == 0) th[grp][k] = (M[k][12 + grp] - prod) / M[k][k];
    __syncthreads();
  }

  // w/a extraction: w[0] = -sum(theta[1..8]), w[p]=theta[p], a = theta[9..11]
  if (tid < 2) {
    float sw = 0.f;
    for (int p = 1; p < 9; ++p) {
      sW[tid][p] = th[tid][p];
      sw += th[tid][p];
    }
    sW[tid][0] = -sw;
    sA[tid][0] = th[tid][9];
    sA[tid][1] = th[tid][10];
    sA[tid][2] = th[tid][11];
  }
  __syncthreads();

  // evaluate warp field on the 16x16 grid (4 points per lane)
  for (int p = tid; p < 256; p += 64) {
    const int pi = p >> 4, pj = p & 15;
    const float x = pj * (1.f / 15.f), y = pi * (1.f / 15.f);
    float zx = sA[0][0] + x * sA[0][1] + y * sA[0][2];
    float zy = sA[1][0] + x * sA[1][1] + y * sA[1][2];
#pragma unroll
    for (int c = 0; c < 9; ++c) {
      const float ddx = x - dxs[c], ddy = y - dys[c];
      const float r = sqrtf(ddx * ddx + ddy * ddy + 1e-12f);
      const float u = tps_u(r);
      zx += u * sW[0][c];
      zy += u * sW[1][c];
    }
    axb[b * 256 + p] = (x + zx) * 15.f;
    ayb[b * 256 + p] = (y + zy) * 15.f;
  }
}

// ---------------------------------------------------------------- masked sum
__global__ __launch_bounds__(256) void masksum_k(const float* __restrict__ corr,
                                                 const float* __restrict__ axb,
                                                 const float* __restrict__ ayb,
                                                 float* __restrict__ out) {
  const int b = blockIdx.x;
  const int pB = threadIdx.x;
  const float ax = axb[b * 256 + pB];
  const float ay = ayb[b * 256 + pB];
  const float* __restrict__ cb = corr + (size_t)b * 65536;
  float s = 0.f;
  for (int i = 0; i < 16; ++i) {
    if (fabsf((float)i - ay) <= 1.0f) {
      const float* __restrict__ ci = cb + (size_t)i * 16 * 256 + pB;
      for (int j = 0; j < 16; ++j) {
        if (fabsf((float)j - ax) <= 1.0f) s += ci[(size_t)j * 256];
      }
    }
  }
  __shared__ float sm[256];
  sm[pB] = s;
  __syncthreads();
  for (int off = 128; off; off >>= 1) {
    if (pB < off) sm[pB] += sm[pB + off];
    __syncthreads();
  }
  if (pB == 0) out[b] = sm[0];
}

// ---------------------------------------------------------------- launch
extern "C" void kernel_launch(void* const* d_in, const int* in_sizes, int n_in,
                              void* d_out, int out_size, void* d_ws, size_t ws_size,
                              hipStream_t stream) {
  const float* imgA = (const float*)d_in[0];
  const float* imgB = (const float*)d_in[1];
  const float* W1 = (const float*)d_in[2];
  const float* W2 = (const float*)d_in[3];
  const float* W3 = (const float*)d_in[4];
  const float* W4 = (const float*)d_in[5];
  const float* Wr1 = (const float*)d_in[6];
  const float* Wr2 = (const float*)d_in[7];
  const float* Wd = (const float*)d_in[8];
  const float* bd = (const float*)d_in[9];

  float* ws = (float*)d_ws;
  unsigned short* WT2 = (unsigned short*)(ws + 0);
  unsigned short* WT3 = (unsigned short*)(ws + 36864);
  unsigned short* WT4 = (unsigned short*)(ws + 184320);
  unsigned short* WTr1 = (unsigned short*)(ws + 774144);
  unsigned short* WTr2 = (unsigned short*)(ws + 1576960);
  unsigned short* FEATs = (unsigned short*)(ws + 1679360);
  unsigned short* S3both = (unsigned short*)(ws + 5873664);
  unsigned short* S2both = (unsigned short*)(ws + 14262272);
  unsigned short* S1both = (unsigned short*)(ws + 31039488);
  unsigned short* FEATsp = (unsigned short*)(ws + 5873664);  // overlays S3both
  float* CORRf = ws + 14262272;                              // overlays S2both
  unsigned short* CORRh = (unsigned short*)(ws + 16359424);
  float* R1p = ws + 17408000;                                // 25 x 409600
  unsigned short* R1h = (unsigned short*)(ws + 27648000);
  float* R2p = ws + 27750400;                                // 25 x 73728
  float* R2f = ws + 29593600;
  float* GEOb = ws + 29667328;
  float* AXb = ws + 29667904;
  float* AYb = ws + 29676096;
  unsigned short* WT1 = (unsigned short*)(ws + 64593920);    // after S1both
  float* ZPf = ws + 64594944;                                // zero page (4KB)
  const unsigned short* ZP = (const unsigned short*)ZPf;

  // single prep kernel: zero page + all weight transposes (ws poisoned/iter)
  prep_all<<<13132, 256, 0, stream>>>(W1, W2, W3, W4, Wr1, Wr2,
                                      WT1, WT2, WT3, WT4, WTr1, WTr2, ZPf);

  // feature chain, both images per launch
  conv1_mfma<<<dim3(128, 64), 256, 0, stream>>>(imgA, imgB, WT1, S1both);
  // conv2: M = 64*4096 = 262144 -> 2048 blocks of 128x128
  tile_conv<128, 128, 64, 128, 3, 3, 2, 1, 0, 1, 0, 0, 1>
      <<<dim3(2048, 1), 256, 0, stream>>>(S1both, WT2, S2both, nullptr, ZP,
                                          128, 128, 64, 64, 0, 0);
  // conv3: M = 64*1024 = 65536 -> 512x2 of 128x128
  tile_conv<128, 128, 128, 256, 3, 3, 2, 1, 0, 1, 0, 0, 1>
      <<<dim3(512, 2), 256, 0, stream>>>(S2both, WT3, S3both, nullptr, ZP,
                                         64, 64, 32, 32, 0, 0);
  // conv4: M = 64*256 = 16384 -> 256x8 of 64x64
  tile_conv<64, 64, 256, 512, 3, 3, 2, 1, 0, 1, 0, 0, 1>
      <<<dim3(256, 8), 256, 0, stream>>>(S3both, WT4, FEATs, nullptr, ZP,
                                         32, 32, 16, 16, 0, 0);

  // l2norm: FEATs (single) -> FEATsp (split pair, lo at +8388608 el)
  l2norm_k<<<16384, 64, 0, stream>>>(FEATs, FEATsp, 8388608);
  // corr: tiled split GEMM (batched B), fp32 out + single fp16 hi out
  tile_conv<64, 64, 512, 256, 1, 1, 1, 0, 1, 1, 1, 1, 0>
      <<<dim3(128, 4), 256, 0, stream>>>(FEATsp, FEATsp + 4194304, CORRh, CORRf,
                                         ZP, 16, 16, 16, 16, 8388608, 8388608);
  // conv_r1: 64x64 tiles, split-K 25 -> fp32 partials
  tile_conv<64, 64, 256, 128, 7, 7, 1, 0, 0, 25, 0, 0, 0>
      <<<dim3(50, 2, 25), 256, 0, stream>>>(CORRh, WTr1, nullptr, R1p, ZP,
                                            16, 16, 10, 10, 0, 0);
  sum_relu_s<<<1600, 256, 0, stream>>>(R1p, R1h, 409600, 25);
  // conv_r2: direct single fp16, split-K 25
  gemm_conv<1, 4, 128, 64, 5, 5, 25>
      <<<dim3(18, 1, 25), 256, 0, stream>>>(R1h, WTr2, R2p, 10, 10, 6, 6);
  sum_relu_f<<<288, 256, 0, stream>>>(R2p, R2f, 73728, 25);
  dense_k<<<dim3(18, 32), 64, 0, stream>>>(R2f, Wd, bd, GEOb);
  tps_k<<<32, 64, 0, stream>>>(GEOb, AXb, AYb);
  masksum_k<<<32, 256, 0, stream>>>(CORRf, AXb, AYb, (float*)d_out);
}

// Round 10
// 434.397 us; speedup vs baseline: 1.1468x; 1.0198x over previous
//
#include <hip/hip_runtime.h>
#include <math.h>

// ---------------------------------------------------------------------------
// Round 17: fat tiles for conv4 / conv_r1 (LDS-read-ratio fix).
//   R16 counters: conv4 (64x64 tiles) = 70us, VALUBusy 46% > MfmaUtil 22%,
//   HBM 15%. Per chunk a 32x32-per-wave tile issues 1 ds_read_b128 per MFMA
//   (8:8) -> LDS-read + addressing bound. conv2 (128x128, 0.5 reads/MFMA,
//   same 38.7 GFLOP, worse HBM) is faster (<69us) -- within-harness A/B.
//   conv4 -> <128,128> grid (128,4); conv_r1 -> <128,128> grid (25,1,25)
//   (partial-slice layout unchanged: 25 x 409600). Template untouched.
//
//   R15: vectorized conv1 staging + LDS-bounce coalesced epilogues.
//   R12-14: gl16 + XOR swizzle + counted-vmcnt 2-deep pipeline; both images
//   batched; single prep kernel.
//
// Workspace (float units), end 64595968 fl = 258.4 MB < 268.4 MB (256 MiB):
//   WT2@0(36864) WT3@36864(147456) WT4@184320(589824)
//   WTr1@774144(802816) WTr2@1576960(102400) -> 1679360
//   FEATs @1679360 (4194304)   both img, 16384 x 512 fp16
//   S3both@5873664 (8388608)   64 x 32x32x256 fp16
//   S2both@14262272 (16777216) 64 x 64x64x128 fp16
//   S1both@31039488 (33554432) 64 x 128x128x64 fp16
//   WT1@64593920 (1024) ZP@64594944 (1024)
//   post-chain overlays: FEATsp@5873664 CORRf@14262272(2097152)
//     CORRh@16359424(524288) R1p@17408000(25x409600) R1h@27648000
//     R2p@27750400(25x73728) R2f@29593600 GEO@29667328 AX@29667904
//     AY@29676096 -> end 29684288
// ---------------------------------------------------------------------------

typedef __attribute__((ext_vector_type(8))) _Float16 f16x8;
typedef __attribute__((ext_vector_type(4))) _Float16 f16x4;
typedef __attribute__((ext_vector_type(4))) float f32x4;

__device__ __forceinline__ unsigned short f2h(float f) {
  return __builtin_bit_cast(unsigned short, (_Float16)f);
}

// direct global->LDS DMA, 16B per lane (lane-linear LDS dest required)
__device__ __forceinline__ void gl16(const unsigned short* g, _Float16* l) {
  auto* gp = (const __attribute__((address_space(1))) unsigned int*)(g);
  auto* lp = (__attribute__((address_space(3))) unsigned int*)(l);
  __builtin_amdgcn_global_load_lds(gp, lp, 16, 0, 0);
}

// ---------------------------------------------------------------- prep (all)
__global__ __launch_bounds__(256) void prep_all(
    const float* __restrict__ W1, const float* __restrict__ W2,
    const float* __restrict__ W3, const float* __restrict__ W4,
    const float* __restrict__ Wr1, const float* __restrict__ Wr2,
    unsigned short* __restrict__ WT1, unsigned short* __restrict__ WT2,
    unsigned short* __restrict__ WT3, unsigned short* __restrict__ WT4,
    unsigned short* __restrict__ WTr1, unsigned short* __restrict__ WTr2,
    float* __restrict__ ZPf) {
  long idx = (long)blockIdx.x * 256 + threadIdx.x;
  if (idx < 1024) { ZPf[idx] = 0.f; return; }
  idx -= 1024;
  if (idx < 2048) {  // WT1: [64 out][32 k], k=(di*3+dj)*3+c, zero-pad 27..31
    const int o = (int)idx >> 5, k = (int)idx & 31;
    WT1[idx] = (k < 27) ? f2h(W1[(size_t)k * 64 + o]) : (unsigned short)0;
    return;
  }
  idx -= 2048;
  if (idx < 73728) {  // WT2: K=576, C=128
    const int k = (int)idx / 128, o = (int)idx % 128;
    WT2[(size_t)o * 576 + k] = f2h(W2[idx]);
    return;
  }
  idx -= 73728;
  if (idx < 294912) {  // WT3: K=1152, C=256
    const int k = (int)idx / 256, o = (int)idx % 256;
    WT3[(size_t)o * 1152 + k] = f2h(W3[idx]);
    return;
  }
  idx -= 294912;
  if (idx < 1179648) {  // WT4: K=2304, C=512
    const int k = (int)idx / 512, o = (int)idx % 512;
    WT4[(size_t)o * 2304 + k] = f2h(W4[idx]);
    return;
  }
  idx -= 1179648;
  if (idx < 1605632) {  // WTr1: K=12544, C=128
    const int k = (int)idx / 128, o = (int)idx % 128;
    WTr1[(size_t)o * 12544 + k] = f2h(Wr1[idx]);
    return;
  }
  idx -= 1605632;
  if (idx < 204800) {  // WTr2: K=3200, C=64
    const int k = (int)idx / 64, o = (int)idx % 64;
    WTr2[(size_t)o * 3200 + k] = f2h(Wr2[idx]);
  }
}

// ---------------------------------------------------------------- conv1 MFMA
// Both images per launch (b 0..63). One block per (out row i, batch b).
// float4 vector staging; LDS-bounce epilogue with 16B coalesced stores.
__global__ __launch_bounds__(256) void conv1_mfma(const float* __restrict__ inA,
                                                  const float* __restrict__ inB,
                                                  const unsigned short* __restrict__ wt1,
                                                  unsigned short* __restrict__ out) {
  const int i = blockIdx.x;   // output row 0..127
  const int b = blockIdx.y;   // virtual batch 0..63
  const int tid = threadIdx.x;
  const int lane = tid & 63, wid = tid >> 6;
  const int lrow = lane & 15, quad = lane >> 4;

  __shared__ _Float16 Rows[3][776];   // 8B-aligned rows; [768..770] = pad
  __shared__ _Float16 OutB[8192];     // 128 j x 64 ch bounce

  const float* __restrict__ img = (b < 32) ? inA : inB;
  const float* __restrict__ inb = img + (size_t)(b & 31) * 196608;
  const f16x4 z4 = {0, 0, 0, 0};
#pragma unroll
  for (int di = 0; di < 3; ++di) {
    const int y = 2 * i + di;
    if (tid < 192) {
      f16x4 h4 = z4;
      if (y < 256) {
        const float4 v4 = *(const float4*)(inb + (size_t)y * 768 + tid * 4);
        h4[0] = (_Float16)v4.x; h4[1] = (_Float16)v4.y;
        h4[2] = (_Float16)v4.z; h4[3] = (_Float16)v4.w;
      }
      *(f16x4*)&Rows[di][tid * 4] = h4;
    }
    if (tid < 3) Rows[di][768 + tid] = (_Float16)0.f;
  }
  __syncthreads();

  // B fragments: all 64 cols, straight from WT1[64][32]
  f16x8 bf[4];
#pragma unroll
  for (int ni = 0; ni < 4; ++ni)
    bf[ni] = *(const f16x8*)(wt1 + (ni * 16 + lrow) * 32 + quad * 8);

  // A fragments: im2col gather. k=(di*3+dj)*3+c -> di=k/9, dj=(k/3)%3, c=k%3
  f16x8 af[2];
#pragma unroll
  for (int mi = 0; mi < 2; ++mi) {
    const int j = wid * 32 + mi * 16 + lrow;
#pragma unroll
    for (int s = 0; s < 8; ++s) {
      const int k = quad * 8 + s;
      if (k < 27) {
        const int di = k / 9, dj = (k / 3) % 3, c = k % 3;
        af[mi][s] = Rows[di][(2 * j + dj) * 3 + c];
      } else {
        af[mi][s] = (_Float16)0.f;
      }
    }
  }

  f32x4 acc[2][4];
#pragma unroll
  for (int mi = 0; mi < 2; ++mi)
#pragma unroll
    for (int ni = 0; ni < 4; ++ni) {
      const f32x4 z = {0.f, 0.f, 0.f, 0.f};
      acc[mi][ni] = __builtin_amdgcn_mfma_f32_16x16x32_f16(af[mi], bf[ni], z, 0, 0, 0);
    }

  // bounce: j = wid*32+mi*16+quad*4+r, ch = ni*16+lrow; swizzle ch bits 4-5
#pragma unroll
  for (int mi = 0; mi < 2; ++mi)
#pragma unroll
    for (int ni = 0; ni < 4; ++ni)
#pragma unroll
      for (int r = 0; r < 4; ++r) {
        const int j = wid * 32 + mi * 16 + quad * 4 + r;
        const int ch = ni * 16 + lrow;
        OutB[j * 64 + (ch ^ (((j >> 2) & 3) << 4))] =
            (_Float16)fmaxf(acc[mi][ni][r], 0.f);
      }
  __syncthreads();

  unsigned short* __restrict__ ob = out + (((size_t)b * 128 + i) * 128) * 64;
#pragma unroll
  for (int q2 = 0; q2 < 4; ++q2) {
    const int v = tid + 256 * q2;
    const int j = v >> 3, c0 = (v & 7) * 8;
    const f16x8 pack = *(const f16x8*)&OutB[j * 64 + (c0 ^ (((j >> 2) & 3) << 4))];
    *(f16x8*)&ob[(size_t)j * 64 + c0] = pack;
  }
}

// ---------------------------------------------------------------- tile conv
// LDS-tiled implicit-GEMM, gl16 staging + XOR swizzle + 2-deep counted
// pipeline (R12). Non-SK epilogues bounce fp16 output through As
// (dead after final s_barrier) -> 16B coalesced stores.
template <int BM, int BN, int CIN, int COUT, int KH, int KW, int STRIDE,
          int SAMEPAD, int SPLIT, int SK, int BATB, int OUTF32, int RELU>
__global__ __launch_bounds__(256) void tile_conv(
    const unsigned short* __restrict__ in, const unsigned short* __restrict__ wt,
    unsigned short* __restrict__ outh, float* __restrict__ outf,
    const unsigned short* __restrict__ zp,
    int Hin, int Win, int Hout, int Wout, int aLo, int bLo) {
  constexpr int CPT = CIN / 64;
  constexpr int LA = BM / 32;
  constexpr int LB = BN / 32;
  constexpr int KTOT = KH * KW * CIN;
  constexpr int MT = BM / 32;
  constexpr int NT = BN / 32;
  constexpr int PL = 1 + SPLIT;
  constexpr int LPS = PL * (LA + LB);  // gl16 issues per thread per stage
  // s_waitcnt imm: vmcnt[3:0]|exp[6:4]|lgkm[11:8]|vmcnt_hi[15:14]
  constexpr unsigned WCN =
      (unsigned)((LPS & 0xF) | (0x7 << 4) | (0xF << 8) | ((LPS >> 4) << 14));
  constexpr unsigned WC0 = (unsigned)((0x7 << 4) | (0xF << 8));
  __shared__ _Float16 As[2][PL * BM * 64];
  __shared__ _Float16 Bs[2][PL * BN * 64];
  static_assert(SK > 1 || (size_t)BM * BN <= sizeof(As) / sizeof(_Float16),
                "bounce must fit in As");

  const int t = threadIdx.x;
  const int lane = t & 63, wid = t >> 6;
  const int lrow = lane & 15, quad = lane >> 4;
  const int m0 = blockIdx.x * BM;
  const int n0 = blockIdx.y * BN;

  // staging: thread t covers row r=(t>>3)+32i, slot sl=t&7 (16B units).
  // source uses swizzled slot q = sl ^ (r&7); (r&7) is i-invariant.
  const int q8 = ((t & 7) ^ ((t >> 3) & 7)) * 8;

  int pixB[LA], iS[LA], jS[LA];
#pragma unroll
  for (int i = 0; i < LA; ++i) {
    const int r = (t >> 3) + 32 * i;
    const int m = m0 + r;
    const int j = m % Wout;
    const int t2 = m / Wout;
    const int ii = t2 % Hout;
    const int b = t2 / Hout;
    iS[i] = ii * STRIDE;
    jS[i] = j * STRIDE;
    pixB[i] = ((b * Hin + iS[i]) * Win + jS[i]) * CIN + q8;
  }
  const unsigned short* wb = wt;
  if (BATB) wb += (size_t)(m0 / (Hout * Wout)) * COUT * KTOT;
  int bofB[LB];
#pragma unroll
  for (int i = 0; i < LB; ++i) {
    const int r = (t >> 3) + 32 * i;
    bofB[i] = (n0 + r) * KTOT + q8;
  }

  f32x4 acc[MT][NT];
#pragma unroll
  for (int mi = 0; mi < MT; ++mi)
#pragma unroll
    for (int ni = 0; ni < NT; ++ni) acc[mi][ni] = {0.f, 0.f, 0.f, 0.f};

  const int mB = (wid >> 1) * (BM / 2);
  const int nB = (wid & 1) * (BN / 2);

  int tap_lo = 0, tap_hi = KH * KW;
  if (SK > 1) {
    tap_lo = (int)blockIdx.z * KH * KW / SK;
    tap_hi = ((int)blockIdx.z + 1) * KH * KW / SK;
  }
  const int ch_lo = tap_lo * CPT, ch_hi = tap_hi * CPT;

  auto stage = [&](int buf, int ch) {
    const int tap = ch / CPT;
    const int c0 = (ch % CPT) * 64;
    const int di = tap / KW, dj = tap % KW;
    const int toff = (di * Win + dj) * CIN + c0;
    const int woff = tap * CIN + c0;
#pragma unroll
    for (int i = 0; i < LA; ++i) {
      const bool ok = !SAMEPAD || ((iS[i] + di < Hin) && (jS[i] + dj < Win));
      const unsigned short* s0 = ok ? in + pixB[i] + toff : zp + q8;
      gl16(s0, &As[buf][t * 8 + 2048 * i]);
      if (SPLIT) {
        const unsigned short* s1 = ok ? in + pixB[i] + toff + aLo : zp + q8;
        gl16(s1, &As[buf][BM * 64 + t * 8 + 2048 * i]);
      }
    }
#pragma unroll
    for (int i = 0; i < LB; ++i) {
      gl16(wb + bofB[i] + woff, &Bs[buf][t * 8 + 2048 * i]);
      if (SPLIT)
        gl16(wb + bofB[i] + woff + bLo, &Bs[buf][BN * 64 + t * 8 + 2048 * i]);
    }
  };

  stage(0, ch_lo);
  if (ch_lo + 1 < ch_hi) stage(1, ch_lo + 1);
  int cur = 0;
  for (int ch = ch_lo; ch < ch_hi; ++ch) {
    // oldest stage (chunk ch) landed; newest (ch+1) stays in flight
    if (ch + 1 < ch_hi) __builtin_amdgcn_s_waitcnt(WCN);
    else __builtin_amdgcn_s_waitcnt(WC0);
    __builtin_amdgcn_sched_barrier(0);
    __builtin_amdgcn_s_barrier();       // all waves' chunk-ch data visible
    __builtin_amdgcn_sched_barrier(0);
#pragma unroll
    for (int ks = 0; ks < 2; ++ks) {
      f16x8 af[MT], bf[NT], al[MT], bl[NT];
#pragma unroll
      for (int mi = 0; mi < MT; ++mi) {
        const int row = mB + mi * 16 + lrow;
        const int off = row * 64 + (((ks * 4 + quad) ^ (row & 7)) * 8);
        af[mi] = *(const f16x8*)&As[cur][off];
        if (SPLIT) al[mi] = *(const f16x8*)&As[cur][BM * 64 + off];
      }
#pragma unroll
      for (int ni = 0; ni < NT; ++ni) {
        const int row = nB + ni * 16 + lrow;
        const int off = row * 64 + (((ks * 4 + quad) ^ (row & 7)) * 8);
        bf[ni] = *(const f16x8*)&Bs[cur][off];
        if (SPLIT) bl[ni] = *(const f16x8*)&Bs[cur][BN * 64 + off];
      }
#pragma unroll
      for (int mi = 0; mi < MT; ++mi)
#pragma unroll
        for (int ni = 0; ni < NT; ++ni) {
          if (SPLIT) {
            acc[mi][ni] = __builtin_amdgcn_mfma_f32_16x16x32_f16(af[mi], bl[ni],
                                                                 acc[mi][ni], 0, 0, 0);
            acc[mi][ni] = __builtin_amdgcn_mfma_f32_16x16x32_f16(al[mi], bf[ni],
                                                                 acc[mi][ni], 0, 0, 0);
          }
          acc[mi][ni] = __builtin_amdgcn_mfma_f32_16x16x32_f16(af[mi], bf[ni],
                                                               acc[mi][ni], 0, 0, 0);
        }
    }
    __builtin_amdgcn_sched_barrier(0);
    __builtin_amdgcn_s_barrier();       // all waves done reading buf[cur]
    __builtin_amdgcn_sched_barrier(0);
    if (ch + 2 < ch_hi) stage(cur, ch + 2);  // overwrite just-freed buffer
    cur ^= 1;
  }

  if (SK > 1) {
    const size_t slice = (size_t)blockIdx.z * ((size_t)gridDim.x * BM * COUT);
#pragma unroll
    for (int mi = 0; mi < MT; ++mi)
#pragma unroll
      for (int ni = 0; ni < NT; ++ni)
#pragma unroll
        for (int r = 0; r < 4; ++r) {
          const int row = m0 + mB + mi * 16 + quad * 4 + r;
          const int col = n0 + nB + ni * 16 + lrow;
          outf[slice + (size_t)row * COUT + col] = acc[mi][ni][r];
        }
  } else {
    // LDS bounce (As is dead: final s_barrier above). Swizzle col bits 4-5.
    _Float16* bounce = &As[0][0];
#pragma unroll
    for (int mi = 0; mi < MT; ++mi)
#pragma unroll
      for (int ni = 0; ni < NT; ++ni)
#pragma unroll
        for (int r = 0; r < 4; ++r) {
          const int row = mB + mi * 16 + quad * 4 + r;
          const int col = nB + ni * 16 + lrow;
          float v = acc[mi][ni][r];
          if (OUTF32) {
            outf[(size_t)(m0 + row) * COUT + n0 + col] = v;
          } else if (RELU) {
            v = fmaxf(v, 0.f);
          }
          bounce[row * BN + (col ^ (((row >> 2) & 3) << 4))] = (_Float16)v;
        }
    __syncthreads();
    constexpr int VPT = (BM * BN / 8) / 256;
#pragma unroll
    for (int q2 = 0; q2 < VPT; ++q2) {
      const int v = t + 256 * q2;
      const int rowL = v / (BN / 8);
      const int c0 = (v % (BN / 8)) * 8;
      const f16x8 pack =
          *(const f16x8*)&bounce[rowL * BN + (c0 ^ (((rowL >> 2) & 3) << 4))];
      *(f16x8*)&outh[(size_t)(m0 + rowL) * COUT + n0 + c0] = pack;
    }
  }
}

// ---------------------------------------------------------------- direct MFMA
// kept for conv_r2 (tiny), single plane.
template <int MT, int NT, int CIN, int COUT, int KH, int KW, int SK>
__global__ __launch_bounds__(256) void gemm_conv(
    const unsigned short* __restrict__ in, const unsigned short* __restrict__ wt,
    float* __restrict__ outf, int Hin, int Win, int Hout, int Wout) {
  const int KTOT = KH * KW * CIN;
  const int lane = threadIdx.x & 63;
  const int wid = threadIdx.x >> 6;
  const int lrow = lane & 15;
  const int quad = lane >> 4;
  const int m0 = (blockIdx.x * 4 + wid) * (16 * MT);
  const int n0 = blockIdx.y * (16 * NT);

  int pix[MT];
#pragma unroll
  for (int mi = 0; mi < MT; ++mi) {
    const int m = m0 + mi * 16 + lrow;
    const int j = m % Wout;
    const int t = m / Wout;
    const int i = t % Hout;
    const int b = t / Hout;
    pix[mi] = (b * Hin + i) * Win + j;
  }
  const unsigned short* brow[NT];
#pragma unroll
  for (int ni = 0; ni < NT; ++ni)
    brow[ni] = wt + (size_t)(n0 + ni * 16 + lrow) * KTOT + quad * 8;

  f32x4 acc[MT][NT];
#pragma unroll
  for (int mi = 0; mi < MT; ++mi)
#pragma unroll
    for (int ni = 0; ni < NT; ++ni) acc[mi][ni] = {0.f, 0.f, 0.f, 0.f};

  const int tap_lo = (int)blockIdx.z * KH * KW / SK;
  const int tap_hi = ((int)blockIdx.z + 1) * KH * KW / SK;
  for (int tap = tap_lo; tap < tap_hi; ++tap) {
    const int di = tap / KW, dj = tap % KW;
    const unsigned short* ap[MT];
#pragma unroll
    for (int mi = 0; mi < MT; ++mi)
      ap[mi] = in + ((size_t)pix[mi] + di * Win + dj) * CIN + quad * 8;
    const int ko = tap * CIN;
#pragma unroll
    for (int c0 = 0; c0 < CIN; c0 += 32) {
      f16x8 ah[MT], bh[NT];
#pragma unroll
      for (int mi = 0; mi < MT; ++mi) ah[mi] = *(const f16x8*)(ap[mi] + c0);
#pragma unroll
      for (int ni = 0; ni < NT; ++ni) bh[ni] = *(const f16x8*)(brow[ni] + ko + c0);
#pragma unroll
      for (int mi = 0; mi < MT; ++mi)
#pragma unroll
        for (int ni = 0; ni < NT; ++ni)
          acc[mi][ni] = __builtin_amdgcn_mfma_f32_16x16x32_f16(ah[mi], bh[ni],
                                                               acc[mi][ni], 0, 0, 0);
    }
  }
  const size_t slice = (size_t)blockIdx.z * ((size_t)gridDim.x * 64 * MT * COUT);
#pragma unroll
  for (int mi = 0; mi < MT; ++mi)
#pragma unroll
    for (int ni = 0; ni < NT; ++ni)
#pragma unroll
      for (int r = 0; r < 4; ++r) {
        const int row = m0 + mi * 16 + quad * 4 + r;
        const int col = n0 + ni * 16 + lrow;
        outf[slice + (size_t)row * COUT + col] = acc[mi][ni][r];
      }
}

// ---------------------------------------------------------------- split-K epi
__global__ __launch_bounds__(256) void sum_relu_s(const float* __restrict__ p,
                                                  unsigned short* __restrict__ o,
                                                  int n, int parts) {
  const int idx = blockIdx.x * 256 + threadIdx.x;
  if (idx < n) {
    float v = 0.f;
    for (int s = 0; s < parts; ++s) v += p[(size_t)s * n + idx];
    o[idx] = f2h(fmaxf(v, 0.f));
  }
}
__global__ __launch_bounds__(256) void sum_relu_f(const float* __restrict__ p,
                                                  float* __restrict__ o,
                                                  int n, int parts) {
  const int idx = blockIdx.x * 256 + threadIdx.x;
  if (idx < n) {
    float v = 0.f;
    for (int s = 0; s < parts; ++s) v += p[(size_t)s * n + idx];
    o[idx] = fmaxf(v, 0.f);
  }
}

// ---------------------------------------------------------------- l2 normalize
// in: single fp16; out: split pair (hi @y, lo @y+loOff).
__global__ __launch_bounds__(64) void l2norm_k(const unsigned short* __restrict__ x,
                                               unsigned short* __restrict__ y,
                                               int loOff) {
  const int lane = threadIdx.x;
  const f16x8 v = *(const f16x8*)(x + (size_t)blockIdx.x * 512 + lane * 8);
  float f[8];
  float s = 0.f;
#pragma unroll
  for (int k = 0; k < 8; ++k) {
    f[k] = (float)v[k];
    s += f[k] * f[k];
  }
#pragma unroll
  for (int off = 32; off; off >>= 1) s += __shfl_xor(s, off, 64);
  const float inv = 1.f / (sqrtf(s) + 1e-6f);
  f16x8 vh, vl;
#pragma unroll
  for (int k = 0; k < 8; ++k) {
    const float nv = f[k] * inv;
    const _Float16 hi = (_Float16)nv;
    vh[k] = hi;
    vl[k] = (_Float16)(nv - (float)hi);
  }
  unsigned short* ph = y + (size_t)blockIdx.x * 512 + lane * 8;
  *(f16x8*)ph = vh;
  *(f16x8*)(ph + (size_t)loOff) = vl;
}

// ---------------------------------------------------------------- dense
__global__ __launch_bounds__(64) void dense_k(const float* __restrict__ r2,
                                              const float* __restrict__ wd,
                                              const float* __restrict__ bd,
                                              float* __restrict__ geo) {
  const int o = blockIdx.x;
  const int b = blockIdx.y;
  const int lane = threadIdx.x;
  const float* __restrict__ rb = r2 + (size_t)b * 2304;
  float s = 0.f;
  for (int k = lane; k < 2304; k += 64) s += rb[k] * wd[(size_t)k * 18 + o];
#pragma unroll
  for (int off = 32; off; off >>= 1) s += __shfl_xor(s, off, 64);
  if (lane == 0) geo[b * 18 + o] = s + bd[o];
}

// ---------------------------------------------------------------- TPS
// LDS-parallel version (R8). One block (1 wave) per batch.
__device__ __forceinline__ float tps_u(float r) { return r * r * logf(r + 1e-6f); }

__global__ __launch_bounds__(64) void tps_k(const float* __restrict__ geo,
                                            float* __restrict__ axb,
                                            float* __restrict__ ayb) {
  const int b = blockIdx.x;
  const int tid = threadIdx.x;
  __shared__ float M[12][14];
  __shared__ float fel[12];
  __shared__ float dxs[9], dys[9];
  __shared__ float th[2][12];   // [0]=x theta, [1]=y theta
  __shared__ float sW[2][9];
  __shared__ float sA[2][3];
  __shared__ int sPiv;

  const float srcx[9] = {0.f, 0.5f, 1.f, 0.f, 0.5f, 1.f, 0.f, 5.f, 1.f};
  const float srcy[9] = {0.f, 0.f, 0.f, 0.5f, 0.5f, 0.5f, 1.f, 1.f, 1.f};

  // dst points + RHS columns (12,13)
  if (tid < 9) {
    const float mx = geo[b * 18 + 2 * tid], my = geo[b * 18 + 2 * tid + 1];
    dxs[tid] = srcx[tid] + mx;
    dys[tid] = srcy[tid] + my;
    M[tid][12] = -mx;
    M[tid][13] = -my;
  } else if (tid < 12) {
    M[tid][12] = 0.f;
    M[tid][13] = 0.f;
  }
  __syncthreads();
  // K block: 81 tps_u entries in parallel
  for (int e = tid; e < 81; e += 64) {
    const int p = e / 9, q = e % 9;
    const float ddx = dxs[p] - dxs[q], ddy = dys[p] - dys[q];
    const float r = sqrtf(ddx * ddx + ddy * ddy + 1e-12f);
    M[p][q] = tps_u(r);
  }
  // P blocks + zero bottom-right 3x3
  if (tid < 9) {
    M[tid][9] = 1.f;  M[tid][10] = dxs[tid]; M[tid][11] = dys[tid];
    M[9][tid] = 1.f;  M[10][tid] = dxs[tid]; M[11][tid] = dys[tid];
  } else if (tid < 12) {
    M[tid][9] = 0.f; M[tid][10] = 0.f; M[tid][11] = 0.f;
  }
  __syncthreads();

  // Gaussian elimination with partial pivoting (same arithmetic/order as R7)
  for (int k = 0; k < 12; ++k) {
    if (tid == 0) {
      int piv = k;
      float best = fabsf(M[k][k]);
      for (int r = k + 1; r < 12; ++r) {
        const float v = fabsf(M[r][k]);
        if (v > best) { best = v; piv = r; }
      }
      sPiv = piv;
    }
    __syncthreads();
    const int piv = sPiv;
    if (piv != k && tid < 14) {
      const float tmp = M[k][tid];
      M[k][tid] = M[piv][tid];
      M[piv][tid] = tmp;
    }
    __syncthreads();
    if (tid > k && tid < 12) fel[tid] = M[tid][k] / M[k][k];
    __syncthreads();
    for (int e = tid; e < (11 - k) * 14; e += 64) {
      const int r = k + 1 + e / 14, cc = e % 14;
      if (cc >= k) M[r][cc] -= fel[r] * M[k][cc];
    }
    __syncthreads();
  }

  // Back substitution: lanes 0-15 -> x (RHS col 12), lanes 16-31 -> y (col 13)
  const int grp = tid >> 4;
  const int cc = tid & 15;
  for (int k = 11; k >= 0; --k) {
    float prod = 0.f;
    if (grp < 2 && cc > k && cc < 12) prod = M[k][cc] * th[grp][cc];
#pragma unroll
    for (int off = 8; off; off >>= 1) prod += __shfl_xor(prod, off, 16);
    if (grp < 2 && cc == 0) th[grp][k] = (M[k][12 + grp] - prod) / M[k][k];
    __syncthreads();
  }

  // w/a extraction: w[0] = -sum(theta[1..8]), w[p]=theta[p], a = theta[9..11]
  if (tid < 2) {
    float sw = 0.f;
    for (int p = 1; p < 9; ++p) {
      sW[tid][p] = th[tid][p];
      sw += th[tid][p];
    }
    sW[tid][0] = -sw;
    sA[tid][0] = th[tid][9];
    sA[tid][1] = th[tid][10];
    sA[tid][2] = th[tid][11];
  }
  __syncthreads();

  // evaluate warp field on the 16x16 grid (4 points per lane)
  for (int p = tid; p < 256; p += 64) {
    const int pi = p >> 4, pj = p & 15;
    const float x = pj * (1.f / 15.f), y = pi * (1.f / 15.f);
    float zx = sA[0][0] + x * sA[0][1] + y * sA[0][2];
    float zy = sA[1][0] + x * sA[1][1] + y * sA[1][2];
#pragma unroll
    for (int c = 0; c < 9; ++c) {
      const float ddx = x - dxs[c], ddy = y - dys[c];
      const float r = sqrtf(ddx * ddx + ddy * ddy + 1e-12f);
      const float u = tps_u(r);
      zx += u * sW[0][c];
      zy += u * sW[1][c];
    }
    axb[b * 256 + p] = (x + zx) * 15.f;
    ayb[b * 256 + p] = (y + zy) * 15.f;
  }
}

// ---------------------------------------------------------------- masked sum
__global__ __launch_bounds__(256) void masksum_k(const float* __restrict__ corr,
                                                 const float* __restrict__ axb,
                                                 const float* __restrict__ ayb,
                                                 float* __restrict__ out) {
  const int b = blockIdx.x;
  const int pB = threadIdx.x;
  const float ax = axb[b * 256 + pB];
  const float ay = ayb[b * 256 + pB];
  const float* __restrict__ cb = corr + (size_t)b * 65536;
  float s = 0.f;
  for (int i = 0; i < 16; ++i) {
    if (fabsf((float)i - ay) <= 1.0f) {
      const float* __restrict__ ci = cb + (size_t)i * 16 * 256 + pB;
      for (int j = 0; j < 16; ++j) {
        if (fabsf((float)j - ax) <= 1.0f) s += ci[(size_t)j * 256];
      }
    }
  }
  __shared__ float sm[256];
  sm[pB] = s;
  __syncthreads();
  for (int off = 128; off; off >>= 1) {
    if (pB < off) sm[pB] += sm[pB + off];
    __syncthreads();
  }
  if (pB == 0) out[b] = sm[0];
}

// ---------------------------------------------------------------- launch
extern "C" void kernel_launch(void* const* d_in, const int* in_sizes, int n_in,
                              void* d_out, int out_size, void* d_ws, size_t ws_size,
                              hipStream_t stream) {
  const float* imgA = (const float*)d_in[0];
  const float* imgB = (const float*)d_in[1];
  const float* W1 = (const float*)d_in[2];
  const float* W2 = (const float*)d_in[3];
  const float* W3 = (const float*)d_in[4];
  const float* W4 = (const float*)d_in[5];
  const float* Wr1 = (const float*)d_in[6];
  const float* Wr2 = (const float*)d_in[7];
  const float* Wd = (const float*)d_in[8];
  const float* bd = (const float*)d_in[9];

  float* ws = (float*)d_ws;
  unsigned short* WT2 = (unsigned short*)(ws + 0);
  unsigned short* WT3 = (unsigned short*)(ws + 36864);
  unsigned short* WT4 = (unsigned short*)(ws + 184320);
  unsigned short* WTr1 = (unsigned short*)(ws + 774144);
  unsigned short* WTr2 = (unsigned short*)(ws + 1576960);
  unsigned short* FEATs = (unsigned short*)(ws + 1679360);
  unsigned short* S3both = (unsigned short*)(ws + 5873664);
  unsigned short* S2both = (unsigned short*)(ws + 14262272);
  unsigned short* S1both = (unsigned short*)(ws + 31039488);
  unsigned short* FEATsp = (unsigned short*)(ws + 5873664);  // overlays S3both
  float* CORRf = ws + 14262272;                              // overlays S2both
  unsigned short* CORRh = (unsigned short*)(ws + 16359424);
  float* R1p = ws + 17408000;                                // 25 x 409600
  unsigned short* R1h = (unsigned short*)(ws + 27648000);
  float* R2p = ws + 27750400;                                // 25 x 73728
  float* R2f = ws + 29593600;
  float* GEOb = ws + 29667328;
  float* AXb = ws + 29667904;
  float* AYb = ws + 29676096;
  unsigned short* WT1 = (unsigned short*)(ws + 64593920);    // after S1both
  float* ZPf = ws + 64594944;                                // zero page (4KB)
  const unsigned short* ZP = (const unsigned short*)ZPf;

  // single prep kernel: zero page + all weight transposes (ws poisoned/iter)
  prep_all<<<13132, 256, 0, stream>>>(W1, W2, W3, W4, Wr1, Wr2,
                                      WT1, WT2, WT3, WT4, WTr1, WTr2, ZPf);

  // feature chain, both images per launch
  conv1_mfma<<<dim3(128, 64), 256, 0, stream>>>(imgA, imgB, WT1, S1both);
  // conv2: M = 64*4096 = 262144 -> 2048 blocks of 128x128
  tile_conv<128, 128, 64, 128, 3, 3, 2, 1, 0, 1, 0, 0, 1>
      <<<dim3(2048, 1), 256, 0, stream>>>(S1both, WT2, S2both, nullptr, ZP,
                                          128, 128, 64, 64, 0, 0);
  // conv3: M = 64*1024 = 65536 -> 512x2 of 128x128
  tile_conv<128, 128, 128, 256, 3, 3, 2, 1, 0, 1, 0, 0, 1>
      <<<dim3(512, 2), 256, 0, stream>>>(S2both, WT3, S3both, nullptr, ZP,
                                         64, 64, 32, 32, 0, 0);
  // conv4: M = 16384 -> 128x4 of 128x128 (R17: fat tiles, 0.5 reads/MFMA)
  tile_conv<128, 128, 256, 512, 3, 3, 2, 1, 0, 1, 0, 0, 1>
      <<<dim3(128, 4), 256, 0, stream>>>(S3both, WT4, FEATs, nullptr, ZP,
                                         32, 32, 16, 16, 0, 0);

  // l2norm: FEATs (single) -> FEATsp (split pair, lo at +8388608 el)
  l2norm_k<<<16384, 64, 0, stream>>>(FEATs, FEATsp, 8388608);
  // corr: tiled split GEMM (batched B), fp32 out + single fp16 hi out
  tile_conv<64, 64, 512, 256, 1, 1, 1, 0, 1, 1, 1, 1, 0>
      <<<dim3(128, 4), 256, 0, stream>>>(FEATsp, FEATsp + 4194304, CORRh, CORRf,
                                         ZP, 16, 16, 16, 16, 8388608, 8388608);
  // conv_r1: 128x128 tiles, split-K 25 (R17) -> fp32 partials (25 x 409600)
  tile_conv<128, 128, 256, 128, 7, 7, 1, 0, 0, 25, 0, 0, 0>
      <<<dim3(25, 1, 25), 256, 0, stream>>>(CORRh, WTr1, nullptr, R1p, ZP,
                                            16, 16, 10, 10, 0, 0);
  sum_relu_s<<<1600, 256, 0, stream>>>(R1p, R1h, 409600, 25);
  // conv_r2: direct single fp16, split-K 25
  gemm_conv<1, 4, 128, 64, 5, 5, 25>
      <<<dim3(18, 1, 25), 256, 0, stream>>>(R1h, WTr2, R2p, 10, 10, 6, 6);
  sum_relu_f<<<288, 256, 0, stream>>>(R2p, R2f, 73728, 25);
  dense_k<<<dim3(18, 32), 64, 0, stream>>>(R2f, Wd, bd, GEOb);
  tps_k<<<32, 64, 0, stream>>>(GEOb, AXb, AYb);
  masksum_k<<<32, 256, 0, stream>>>(CORRf, AXb, AYb, (float*)d_out);
}

// Round 11
// 417.526 us; speedup vs baseline: 1.1932x; 1.0404x over previous
//
#include <hip/hip_runtime.h>
#include <math.h>

// ---------------------------------------------------------------------------
// Round 18: ring-3 single-barrier pipeline for tile_conv.
//   R17 counters: conv3/4 at ~62us, MfmaUtil 24 / VALU 31 / HBM 10 / Occ 20.
//   Pipe math: MFMA 37k + LDS 55k + VALU 46k cyc/CU vs 149k measured -> ~60%
//   phase-serialization stall (barrier-locked waves, only 2 blocks/CU).
//   Now: BK=32, THREE buffers (48KB -> 3 blocks/CU), ONE barrier per chunk
//   (top barrier proves buf[i-1] reads done -> stage i+2 into it race-free),
//   counted vmcnt(LPS) with 2 chunks in flight, mixed stage+read+MFMA region.
//   Swizzle for 64B rows: store slot s at phys s^((row>>1)&3); conflict-free.
//   Same instruction totals; epilogue adds explicit barrier before bounce.
//
//   R15: vectorized conv1 staging + LDS-bounce coalesced epilogues.
//   R12-17: gl16 staging, counted-vmcnt, batched images, single prep, fat
//   tiles (128x128 for conv2/3/4/conv_r1).
//
// Workspace (float units), end 64595968 fl = 258.4 MB < 268.4 MB (256 MiB):
//   WT2@0(36864) WT3@36864(147456) WT4@184320(589824)
//   WTr1@774144(802816) WTr2@1576960(102400) -> 1679360
//   FEATs @1679360 (4194304)   both img, 16384 x 512 fp16
//   S3both@5873664 (8388608)   64 x 32x32x256 fp16
//   S2both@14262272 (16777216) 64 x 64x64x128 fp16
//   S1both@31039488 (33554432) 64 x 128x128x64 fp16
//   WT1@64593920 (1024) ZP@64594944 (1024)
//   post-chain overlays: FEATsp@5873664 CORRf@14262272(2097152)
//     CORRh@16359424(524288) R1p@17408000(25x409600) R1h@27648000
//     R2p@27750400(25x73728) R2f@29593600 GEO@29667328 AX@29667904
//     AY@29676096 -> end 29684288
// ---------------------------------------------------------------------------

typedef __attribute__((ext_vector_type(8))) _Float16 f16x8;
typedef __attribute__((ext_vector_type(4))) _Float16 f16x4;
typedef __attribute__((ext_vector_type(4))) float f32x4;

__device__ __forceinline__ unsigned short f2h(float f) {
  return __builtin_bit_cast(unsigned short, (_Float16)f);
}

// direct global->LDS DMA, 16B per lane (lane-linear LDS dest required)
__device__ __forceinline__ void gl16(const unsigned short* g, _Float16* l) {
  auto* gp = (const __attribute__((address_space(1))) unsigned int*)(g);
  auto* lp = (__attribute__((address_space(3))) unsigned int*)(l);
  __builtin_amdgcn_global_load_lds(gp, lp, 16, 0, 0);
}

// ---------------------------------------------------------------- prep (all)
__global__ __launch_bounds__(256) void prep_all(
    const float* __restrict__ W1, const float* __restrict__ W2,
    const float* __restrict__ W3, const float* __restrict__ W4,
    const float* __restrict__ Wr1, const float* __restrict__ Wr2,
    unsigned short* __restrict__ WT1, unsigned short* __restrict__ WT2,
    unsigned short* __restrict__ WT3, unsigned short* __restrict__ WT4,
    unsigned short* __restrict__ WTr1, unsigned short* __restrict__ WTr2,
    float* __restrict__ ZPf) {
  long idx = (long)blockIdx.x * 256 + threadIdx.x;
  if (idx < 1024) { ZPf[idx] = 0.f; return; }
  idx -= 1024;
  if (idx < 2048) {  // WT1: [64 out][32 k], k=(di*3+dj)*3+c, zero-pad 27..31
    const int o = (int)idx >> 5, k = (int)idx & 31;
    WT1[idx] = (k < 27) ? f2h(W1[(size_t)k * 64 + o]) : (unsigned short)0;
    return;
  }
  idx -= 2048;
  if (idx < 73728) {  // WT2: K=576, C=128
    const int k = (int)idx / 128, o = (int)idx % 128;
    WT2[(size_t)o * 576 + k] = f2h(W2[idx]);
    return;
  }
  idx -= 73728;
  if (idx < 294912) {  // WT3: K=1152, C=256
    const int k = (int)idx / 256, o = (int)idx % 256;
    WT3[(size_t)o * 1152 + k] = f2h(W3[idx]);
    return;
  }
  idx -= 294912;
  if (idx < 1179648) {  // WT4: K=2304, C=512
    const int k = (int)idx / 512, o = (int)idx % 512;
    WT4[(size_t)o * 2304 + k] = f2h(W4[idx]);
    return;
  }
  idx -= 1179648;
  if (idx < 1605632) {  // WTr1: K=12544, C=128
    const int k = (int)idx / 128, o = (int)idx % 128;
    WTr1[(size_t)o * 12544 + k] = f2h(Wr1[idx]);
    return;
  }
  idx -= 1605632;
  if (idx < 204800) {  // WTr2: K=3200, C=64
    const int k = (int)idx / 64, o = (int)idx % 64;
    WTr2[(size_t)o * 3200 + k] = f2h(Wr2[idx]);
  }
}

// ---------------------------------------------------------------- conv1 MFMA
// Both images per launch (b 0..63). One block per (out row i, batch b).
// float4 vector staging; LDS-bounce epilogue with 16B coalesced stores.
__global__ __launch_bounds__(256) void conv1_mfma(const float* __restrict__ inA,
                                                  const float* __restrict__ inB,
                                                  const unsigned short* __restrict__ wt1,
                                                  unsigned short* __restrict__ out) {
  const int i = blockIdx.x;   // output row 0..127
  const int b = blockIdx.y;   // virtual batch 0..63
  const int tid = threadIdx.x;
  const int lane = tid & 63, wid = tid >> 6;
  const int lrow = lane & 15, quad = lane >> 4;

  __shared__ _Float16 Rows[3][776];   // 8B-aligned rows; [768..770] = pad
  __shared__ _Float16 OutB[8192];     // 128 j x 64 ch bounce

  const float* __restrict__ img = (b < 32) ? inA : inB;
  const float* __restrict__ inb = img + (size_t)(b & 31) * 196608;
  const f16x4 z4 = {0, 0, 0, 0};
#pragma unroll
  for (int di = 0; di < 3; ++di) {
    const int y = 2 * i + di;
    if (tid < 192) {
      f16x4 h4 = z4;
      if (y < 256) {
        const float4 v4 = *(const float4*)(inb + (size_t)y * 768 + tid * 4);
        h4[0] = (_Float16)v4.x; h4[1] = (_Float16)v4.y;
        h4[2] = (_Float16)v4.z; h4[3] = (_Float16)v4.w;
      }
      *(f16x4*)&Rows[di][tid * 4] = h4;
    }
    if (tid < 3) Rows[di][768 + tid] = (_Float16)0.f;
  }
  __syncthreads();

  // B fragments: all 64 cols, straight from WT1[64][32]
  f16x8 bf[4];
#pragma unroll
  for (int ni = 0; ni < 4; ++ni)
    bf[ni] = *(const f16x8*)(wt1 + (ni * 16 + lrow) * 32 + quad * 8);

  // A fragments: im2col gather. k=(di*3+dj)*3+c -> di=k/9, dj=(k/3)%3, c=k%3
  f16x8 af[2];
#pragma unroll
  for (int mi = 0; mi < 2; ++mi) {
    const int j = wid * 32 + mi * 16 + lrow;
#pragma unroll
    for (int s = 0; s < 8; ++s) {
      const int k = quad * 8 + s;
      if (k < 27) {
        const int di = k / 9, dj = (k / 3) % 3, c = k % 3;
        af[mi][s] = Rows[di][(2 * j + dj) * 3 + c];
      } else {
        af[mi][s] = (_Float16)0.f;
      }
    }
  }

  f32x4 acc[2][4];
#pragma unroll
  for (int mi = 0; mi < 2; ++mi)
#pragma unroll
    for (int ni = 0; ni < 4; ++ni) {
      const f32x4 z = {0.f, 0.f, 0.f, 0.f};
      acc[mi][ni] = __builtin_amdgcn_mfma_f32_16x16x32_f16(af[mi], bf[ni], z, 0, 0, 0);
    }

  // bounce: j = wid*32+mi*16+quad*4+r, ch = ni*16+lrow; swizzle ch bits 4-5
#pragma unroll
  for (int mi = 0; mi < 2; ++mi)
#pragma unroll
    for (int ni = 0; ni < 4; ++ni)
#pragma unroll
      for (int r = 0; r < 4; ++r) {
        const int j = wid * 32 + mi * 16 + quad * 4 + r;
        const int ch = ni * 16 + lrow;
        OutB[j * 64 + (ch ^ (((j >> 2) & 3) << 4))] =
            (_Float16)fmaxf(acc[mi][ni][r], 0.f);
      }
  __syncthreads();

  unsigned short* __restrict__ ob = out + (((size_t)b * 128 + i) * 128) * 64;
#pragma unroll
  for (int q2 = 0; q2 < 4; ++q2) {
    const int v = tid + 256 * q2;
    const int j = v >> 3, c0 = (v & 7) * 8;
    const f16x8 pack = *(const f16x8*)&OutB[j * 64 + (c0 ^ (((j >> 2) & 3) << 4))];
    *(f16x8*)&ob[(size_t)j * 64 + c0] = pack;
  }
}

// ---------------------------------------------------------------- tile conv
// LDS-tiled implicit-GEMM (R18): BK=32 chunks, ring-3 buffers, ONE barrier
// per chunk, counted vmcnt (2 chunks in flight), mixed stage/read/MFMA
// region. LDS rows 32 f16 = 64B = 4 slots of 16B; logical slot s stored at
// phys s ^ ((row>>1)&3), source pre-swizzled (q8), reads apply same map.
// SPLIT: A/B hi+lo planes, 3 MFMAs per pair. SK>1: split-K over taps.
// BATB: B batched by A batch. OUTF32: fp32 out + fp16 hi out.
template <int BM, int BN, int CIN, int COUT, int KH, int KW, int STRIDE,
          int SAMEPAD, int SPLIT, int SK, int BATB, int OUTF32, int RELU>
__global__ __launch_bounds__(256) void tile_conv(
    const unsigned short* __restrict__ in, const unsigned short* __restrict__ wt,
    unsigned short* __restrict__ outh, float* __restrict__ outf,
    const unsigned short* __restrict__ zp,
    int Hin, int Win, int Hout, int Wout, int aLo, int bLo) {
  constexpr int CPT = CIN / 32;   // 32-wide K chunks per tap (power of 2)
  constexpr int LA = BM / 64;     // gl16 issues per A plane per chunk
  constexpr int LB = BN / 64;
  constexpr int KTOT = KH * KW * CIN;
  constexpr int MT = BM / 32;
  constexpr int NT = BN / 32;
  constexpr int PL = 1 + SPLIT;
  constexpr int LPS = PL * (LA + LB);      // gl16 issues per thread per stage
  constexpr int ASTR = PL * BM * 32;       // f16 per A buffer
  constexpr int BSTR = PL * BN * 32;
  // s_waitcnt imm: vmcnt[3:0]|exp[6:4]|lgkm[11:8]|vmcnt_hi[15:14]
  constexpr unsigned WCN =
      (unsigned)((LPS & 0xF) | (0x7 << 4) | (0xF << 8) | ((LPS >> 4) << 14));
  constexpr unsigned WC0 = (unsigned)((0x7 << 4) | (0xF << 8));
  __shared__ _Float16 SH[3 * (ASTR + BSTR)];
  static_assert(SK > 1 || (size_t)BM * BN <= (size_t)3 * (ASTR + BSTR),
                "bounce must fit in SH");

  const int t = threadIdx.x;
  const int lane = t & 63, wid = t >> 6;
  const int lrow = lane & 15, quad = lane >> 4;
  const int m0 = blockIdx.x * BM;
  const int n0 = blockIdx.y * BN;

  // staging position p = t + 256*i -> row = (t>>2)+64i, phys slot = t&3;
  // fetch logical slot s = (t&3) ^ ((t>>3)&3)   (i-invariant: 64i keeps bits)
  const int q8 = ((t & 3) ^ ((t >> 3) & 3)) * 8;

  int pixB[LA], iS[LA], jS[LA];
#pragma unroll
  for (int i = 0; i < LA; ++i) {
    const int r = (t >> 2) + 64 * i;
    const int m = m0 + r;
    const int j = m % Wout;
    const int t2 = m / Wout;
    const int ii = t2 % Hout;
    const int b = t2 / Hout;
    iS[i] = ii * STRIDE;
    jS[i] = j * STRIDE;
    pixB[i] = ((b * Hin + iS[i]) * Win + jS[i]) * CIN + q8;
  }
  const unsigned short* wb = wt;
  if (BATB) wb += (size_t)(m0 / (Hout * Wout)) * COUT * KTOT;
  int bofB[LB];
#pragma unroll
  for (int i = 0; i < LB; ++i) {
    const int r = (t >> 2) + 64 * i;
    bofB[i] = (n0 + r) * KTOT + q8;
  }

  f32x4 acc[MT][NT];
#pragma unroll
  for (int mi = 0; mi < MT; ++mi)
#pragma unroll
    for (int ni = 0; ni < NT; ++ni) acc[mi][ni] = {0.f, 0.f, 0.f, 0.f};

  const int mB = (wid >> 1) * (BM / 2);
  const int nB = (wid & 1) * (BN / 2);

  // hoisted swizzled read offsets (loop-invariant)
  int offA[MT], offB[NT];
#pragma unroll
  for (int mi = 0; mi < MT; ++mi) {
    const int row = mB + mi * 16 + lrow;
    offA[mi] = row * 32 + ((quad ^ ((row >> 1) & 3)) * 8);
  }
#pragma unroll
  for (int ni = 0; ni < NT; ++ni) {
    const int row = nB + ni * 16 + lrow;
    offB[ni] = row * 32 + ((quad ^ ((row >> 1) & 3)) * 8);
  }

  int tap_lo = 0, tap_hi = KH * KW;
  if (SK > 1) {
    tap_lo = (int)blockIdx.z * KH * KW / SK;
    tap_hi = ((int)blockIdx.z + 1) * KH * KW / SK;
  }
  const int ch_lo = tap_lo * CPT, ch_hi = tap_hi * CPT;

  auto stage = [&](int buf, int ch) {
    const int tap = ch / CPT;
    const int c0 = (ch & (CPT - 1)) * 32;
    const int di = tap / KW, dj = tap % KW;
    const int toff = (di * Win + dj) * CIN + c0;
    const int woff = tap * CIN + c0;
    _Float16* aB = SH + buf * ASTR;
    _Float16* bB = SH + 3 * ASTR + buf * BSTR;
#pragma unroll
    for (int i = 0; i < LA; ++i) {
      const bool ok = !SAMEPAD || ((iS[i] + di < Hin) && (jS[i] + dj < Win));
      const unsigned short* s0 = ok ? in + pixB[i] + toff : zp + q8;
      gl16(s0, aB + t * 8 + 2048 * i);
      if (SPLIT) {
        const unsigned short* s1 = ok ? in + pixB[i] + toff + aLo : zp + q8;
        gl16(s1, aB + BM * 32 + t * 8 + 2048 * i);
      }
    }
#pragma unroll
    for (int i = 0; i < LB; ++i) {
      gl16(wb + bofB[i] + woff, bB + t * 8 + 2048 * i);
      if (SPLIT)
        gl16(wb + bofB[i] + woff + bLo, bB + BN * 32 + t * 8 + 2048 * i);
    }
  };

  stage(0, ch_lo);
  if (ch_lo + 1 < ch_hi) stage(1, ch_lo + 1);
  int cur = 0;
  for (int ch = ch_lo; ch < ch_hi; ++ch) {
    // oldest in-flight stage (chunk ch) landed; chunk ch+1 stays in flight
    if (ch + 1 < ch_hi) __builtin_amdgcn_s_waitcnt(WCN);
    else __builtin_amdgcn_s_waitcnt(WC0);
    __builtin_amdgcn_sched_barrier(0);
    __builtin_amdgcn_s_barrier();  // chunk-ch ready AND buf[cur-1] reads done
    __builtin_amdgcn_sched_barrier(0);
    // stage chunk ch+2 into buf[cur-1] (free per the barrier above)
    if (ch + 2 < ch_hi) stage(cur == 0 ? 2 : cur - 1, ch + 2);
    {
      const _Float16* aB = SH + cur * ASTR;
      const _Float16* bB = SH + 3 * ASTR + cur * BSTR;
      f16x8 af[MT], bf[NT], al[MT], bl[NT];
#pragma unroll
      for (int mi = 0; mi < MT; ++mi) {
        af[mi] = *(const f16x8*)&aB[offA[mi]];
        if (SPLIT) al[mi] = *(const f16x8*)&aB[BM * 32 + offA[mi]];
      }
#pragma unroll
      for (int ni = 0; ni < NT; ++ni) {
        bf[ni] = *(const f16x8*)&bB[offB[ni]];
        if (SPLIT) bl[ni] = *(const f16x8*)&bB[BN * 32 + offB[ni]];
      }
#pragma unroll
      for (int mi = 0; mi < MT; ++mi)
#pragma unroll
        for (int ni = 0; ni < NT; ++ni) {
          if (SPLIT) {
            acc[mi][ni] = __builtin_amdgcn_mfma_f32_16x16x32_f16(af[mi], bl[ni],
                                                                 acc[mi][ni], 0, 0, 0);
            acc[mi][ni] = __builtin_amdgcn_mfma_f32_16x16x32_f16(al[mi], bf[ni],
                                                                 acc[mi][ni], 0, 0, 0);
          }
          acc[mi][ni] = __builtin_amdgcn_mfma_f32_16x16x32_f16(af[mi], bf[ni],
                                                               acc[mi][ni], 0, 0, 0);
        }
    }
    cur = (cur == 2) ? 0 : cur + 1;
  }

  if (SK > 1) {
    const size_t slice = (size_t)blockIdx.z * ((size_t)gridDim.x * BM * COUT);
#pragma unroll
    for (int mi = 0; mi < MT; ++mi)
#pragma unroll
      for (int ni = 0; ni < NT; ++ni)
#pragma unroll
        for (int r = 0; r < 4; ++r) {
          const int row = m0 + mB + mi * 16 + quad * 4 + r;
          const int col = n0 + nB + ni * 16 + lrow;
          outf[slice + (size_t)row * COUT + col] = acc[mi][ni][r];
        }
  } else {
    __syncthreads();  // all waves done with SH (no trailing loop barrier now)
    // LDS bounce; swizzle col bits 4-5 against row bits 2-3.
    _Float16* bounce = &SH[0];
#pragma unroll
    for (int mi = 0; mi < MT; ++mi)
#pragma unroll
      for (int ni = 0; ni < NT; ++ni)
#pragma unroll
        for (int r = 0; r < 4; ++r) {
          const int row = mB + mi * 16 + quad * 4 + r;
          const int col = nB + ni * 16 + lrow;
          float v = acc[mi][ni][r];
          if (OUTF32) {
            outf[(size_t)(m0 + row) * COUT + n0 + col] = v;
          } else if (RELU) {
            v = fmaxf(v, 0.f);
          }
          bounce[row * BN + (col ^ (((row >> 2) & 3) << 4))] = (_Float16)v;
        }
    __syncthreads();
    constexpr int VPT = (BM * BN / 8) / 256;
#pragma unroll
    for (int q2 = 0; q2 < VPT; ++q2) {
      const int v = t + 256 * q2;
      const int rowL = v / (BN / 8);
      const int c0 = (v % (BN / 8)) * 8;
      const f16x8 pack =
          *(const f16x8*)&bounce[rowL * BN + (c0 ^ (((rowL >> 2) & 3) << 4))];
      *(f16x8*)&outh[(size_t)(m0 + rowL) * COUT + n0 + c0] = pack;
    }
  }
}

// ---------------------------------------------------------------- direct MFMA
// kept for conv_r2 (tiny), single plane.
template <int MT, int NT, int CIN, int COUT, int KH, int KW, int SK>
__global__ __launch_bounds__(256) void gemm_conv(
    const unsigned short* __restrict__ in, const unsigned short* __restrict__ wt,
    float* __restrict__ outf, int Hin, int Win, int Hout, int Wout) {
  const int KTOT = KH * KW * CIN;
  const int lane = threadIdx.x & 63;
  const int wid = threadIdx.x >> 6;
  const int lrow = lane & 15;
  const int quad = lane >> 4;
  const int m0 = (blockIdx.x * 4 + wid) * (16 * MT);
  const int n0 = blockIdx.y * (16 * NT);

  int pix[MT];
#pragma unroll
  for (int mi = 0; mi < MT; ++mi) {
    const int m = m0 + mi * 16 + lrow;
    const int j = m % Wout;
    const int t = m / Wout;
    const int i = t % Hout;
    const int b = t / Hout;
    pix[mi] = (b * Hin + i) * Win + j;
  }
  const unsigned short* brow[NT];
#pragma unroll
  for (int ni = 0; ni < NT; ++ni)
    brow[ni] = wt + (size_t)(n0 + ni * 16 + lrow) * KTOT + quad * 8;

  f32x4 acc[MT][NT];
#pragma unroll
  for (int mi = 0; mi < MT; ++mi)
#pragma unroll
    for (int ni = 0; ni < NT; ++ni) acc[mi][ni] = {0.f, 0.f, 0.f, 0.f};

  const int tap_lo = (int)blockIdx.z * KH * KW / SK;
  const int tap_hi = ((int)blockIdx.z + 1) * KH * KW / SK;
  for (int tap = tap_lo; tap < tap_hi; ++tap) {
    const int di = tap / KW, dj = tap % KW;
    const unsigned short* ap[MT];
#pragma unroll
    for (int mi = 0; mi < MT; ++mi)
      ap[mi] = in + ((size_t)pix[mi] + di * Win + dj) * CIN + quad * 8;
    const int ko = tap * CIN;
#pragma unroll
    for (int c0 = 0; c0 < CIN; c0 += 32) {
      f16x8 ah[MT], bh[NT];
#pragma unroll
      for (int mi = 0; mi < MT; ++mi) ah[mi] = *(const f16x8*)(ap[mi] + c0);
#pragma unroll
      for (int ni = 0; ni < NT; ++ni) bh[ni] = *(const f16x8*)(brow[ni] + ko + c0);
#pragma unroll
      for (int mi = 0; mi < MT; ++mi)
#pragma unroll
        for (int ni = 0; ni < NT; ++ni)
          acc[mi][ni] = __builtin_amdgcn_mfma_f32_16x16x32_f16(ah[mi], bh[ni],
                                                               acc[mi][ni], 0, 0, 0);
    }
  }
  const size_t slice = (size_t)blockIdx.z * ((size_t)gridDim.x * 64 * MT * COUT);
#pragma unroll
  for (int mi = 0; mi < MT; ++mi)
#pragma unroll
    for (int ni = 0; ni < NT; ++ni)
#pragma unroll
      for (int r = 0; r < 4; ++r) {
        const int row = m0 + mi * 16 + quad * 4 + r;
        const int col = n0 + ni * 16 + lrow;
        outf[slice + (size_t)row * COUT + col] = acc[mi][ni][r];
      }
}

// ---------------------------------------------------------------- split-K epi
__global__ __launch_bounds__(256) void sum_relu_s(const float* __restrict__ p,
                                                  unsigned short* __restrict__ o,
                                                  int n, int parts) {
  const int idx = blockIdx.x * 256 + threadIdx.x;
  if (idx < n) {
    float v = 0.f;
    for (int s = 0; s < parts; ++s) v += p[(size_t)s * n + idx];
    o[idx] = f2h(fmaxf(v, 0.f));
  }
}
__global__ __launch_bounds__(256) void sum_relu_f(const float* __restrict__ p,
                                                  float* __restrict__ o,
                                                  int n, int parts) {
  const int idx = blockIdx.x * 256 + threadIdx.x;
  if (idx < n) {
    float v = 0.f;
    for (int s = 0; s < parts; ++s) v += p[(size_t)s * n + idx];
    o[idx] = fmaxf(v, 0.f);
  }
}

// ---------------------------------------------------------------- l2 normalize
// in: single fp16; out: split pair (hi @y, lo @y+loOff).
__global__ __launch_bounds__(64) void l2norm_k(const unsigned short* __restrict__ x,
                                               unsigned short* __restrict__ y,
                                               int loOff) {
  const int lane = threadIdx.x;
  const f16x8 v = *(const f16x8*)(x + (size_t)blockIdx.x * 512 + lane * 8);
  float f[8];
  float s = 0.f;
#pragma unroll
  for (int k = 0; k < 8; ++k) {
    f[k] = (float)v[k];
    s += f[k] * f[k];
  }
#pragma unroll
  for (int off = 32; off; off >>= 1) s += __shfl_xor(s, off, 64);
  const float inv = 1.f / (sqrtf(s) + 1e-6f);
  f16x8 vh, vl;
#pragma unroll
  for (int k = 0; k < 8; ++k) {
    const float nv = f[k] * inv;
    const _Float16 hi = (_Float16)nv;
    vh[k] = hi;
    vl[k] = (_Float16)(nv - (float)hi);
  }
  unsigned short* ph = y + (size_t)blockIdx.x * 512 + lane * 8;
  *(f16x8*)ph = vh;
  *(f16x8*)(ph + (size_t)loOff) = vl;
}

// ---------------------------------------------------------------- dense
__global__ __launch_bounds__(64) void dense_k(const float* __restrict__ r2,
                                              const float* __restrict__ wd,
                                              const float* __restrict__ bd,
                                              float* __restrict__ geo) {
  const int o = blockIdx.x;
  const int b = blockIdx.y;
  const int lane = threadIdx.x;
  const float* __restrict__ rb = r2 + (size_t)b * 2304;
  float s = 0.f;
  for (int k = lane; k < 2304; k += 64) s += rb[k] * wd[(size_t)k * 18 + o];
#pragma unroll
  for (int off = 32; off; off >>= 1) s += __shfl_xor(s, off, 64);
  if (lane == 0) geo[b * 18 + o] = s + bd[o];
}

// ---------------------------------------------------------------- TPS
// LDS-parallel version (R8). One block (1 wave) per batch.
__device__ __forceinline__ float tps_u(float r) { return r * r * logf(r + 1e-6f); }

__global__ __launch_bounds__(64) void tps_k(const float* __restrict__ geo,
                                            float* __restrict__ axb,
                                            float* __restrict__ ayb) {
  const int b = blockIdx.x;
  const int tid = threadIdx.x;
  __shared__ float M[12][14];
  __shared__ float fel[12];
  __shared__ float dxs[9], dys[9];
  __shared__ float th[2][12];   // [0]=x theta, [1]=y theta
  __shared__ float sW[2][9];
  __shared__ float sA[2][3];
  __shared__ int sPiv;

  const float srcx[9] = {0.f, 0.5f, 1.f, 0.f, 0.5f, 1.f, 0.f, 5.f, 1.f};
  const float srcy[9] = {0.f, 0.f, 0.f, 0.5f, 0.5f, 0.5f, 1.f, 1.f, 1.f};

  // dst points + RHS columns (12,13)
  if (tid < 9) {
    const float mx = geo[b * 18 + 2 * tid], my = geo[b * 18 + 2 * tid + 1];
    dxs[tid] = srcx[tid] + mx;
    dys[tid] = srcy[tid] + my;
    M[tid][12] = -mx;
    M[tid][13] = -my;
  } else if (tid < 12) {
    M[tid][12] = 0.f;
    M[tid][13] = 0.f;
  }
  __syncthreads();
  // K block: 81 tps_u entries in parallel
  for (int e = tid; e < 81; e += 64) {
    const int p = e / 9, q = e % 9;
    const float ddx = dxs[p] - dxs[q], ddy = dys[p] - dys[q];
    const float r = sqrtf(ddx * ddx + ddy * ddy + 1e-12f);
    M[p][q] = tps_u(r);
  }
  // P blocks + zero bottom-right 3x3
  if (tid < 9) {
    M[tid][9] = 1.f;  M[tid][10] = dxs[tid]; M[tid][11] = dys[tid];
    M[9][tid] = 1.f;  M[10][tid] = dxs[tid]; M[11][tid] = dys[tid];
  } else if (tid < 12) {
    M[tid][9] = 0.f; M[tid][10] = 0.f; M[tid][11] = 0.f;
  }
  __syncthreads();

  // Gaussian elimination with partial pivoting (same arithmetic/order as R7)
  for (int k = 0; k < 12; ++k) {
    if (tid == 0) {
      int piv = k;
      float best = fabsf(M[k][k]);
      for (int r = k + 1; r < 12; ++r) {
        const float v = fabsf(M[r][k]);
        if (v > best) { best = v; piv = r; }
      }
      sPiv = piv;
    }
    __syncthreads();
    const int piv = sPiv;
    if (piv != k && tid < 14) {
      const float tmp = M[k][tid];
      M[k][tid] = M[piv][tid];
      M[piv][tid] = tmp;
    }
    __syncthreads();
    if (tid > k && tid < 12) fel[tid] = M[tid][k] / M[k][k];
    __syncthreads();
    for (int e = tid; e < (11 - k) * 14; e += 64) {
      const int r = k + 1 + e / 14, cc = e % 14;
      if (cc >= k) M[r][cc] -= fel[r] * M[k][cc];
    }
    __syncthreads();
  }

  // Back substitution: lanes 0-15 -> x (RHS col 12), lanes 16-31 -> y (col 13)
  const int grp = tid >> 4;
  const int cc = tid & 15;
  for (int k = 11; k >= 0; --k) {
    float prod = 0.f;
    if (grp < 2 && cc > k && cc < 12) prod = M[k][cc] * th[grp][cc];
#pragma unroll
    for (int off = 8; off; off >>= 1) prod += __shfl_xor(prod, off, 16);
    if (grp < 2 && cc == 0) th[grp][k] = (M[k][12 + grp] - prod) / M[k][k];
    __syncthreads();
  }

  // w/a extraction: w[0] = -sum(theta[1..8]), w[p]=theta[p], a = theta[9..11]
  if (tid < 2) {
    float sw = 0.f;
    for (int p = 1; p < 9; ++p) {
      sW[tid][p] = th[tid][p];
      sw += th[tid][p];
    }
    sW[tid][0] = -sw;
    sA[tid][0] = th[tid][9];
    sA[tid][1] = th[tid][10];
    sA[tid][2] = th[tid][11];
  }
  __syncthreads();

  // evaluate warp field on the 16x16 grid (4 points per lane)
  for (int p = tid; p < 256; p += 64) {
    const int pi = p >> 4, pj = p & 15;
    const float x = pj * (1.f / 15.f), y = pi * (1.f / 15.f);
    float zx = sA[0][0] + x * sA[0][1] + y * sA[0][2];
    float zy = sA[1][0] + x * sA[1][1] + y * sA[1][2];
#pragma unroll
    for (int c = 0; c < 9; ++c) {
      const float ddx = x - dxs[c], ddy = y - dys[c];
      const float r = sqrtf(ddx * ddx + ddy * ddy + 1e-12f);
      const float u = tps_u(r);
      zx += u * sW[0][c];
      zy += u * sW[1][c];
    }
    axb[b * 256 + p] = (x + zx) * 15.f;
    ayb[b * 256 + p] = (y + zy) * 15.f;
  }
}

// ---------------------------------------------------------------- masked sum
__global__ __launch_bounds__(256) void masksum_k(const float* __restrict__ corr,
                                                 const float* __restrict__ axb,
                                                 const float* __restrict__ ayb,
                                                 float* __restrict__ out) {
  const int b = blockIdx.x;
  const int pB = threadIdx.x;
  const float ax = axb[b * 256 + pB];
  const float ay = ayb[b * 256 + pB];
  const float* __restrict__ cb = corr + (size_t)b * 65536;
  float s = 0.f;
  for (int i = 0; i < 16; ++i) {
    if (fabsf((float)i - ay) <= 1.0f) {
      const float* __restrict__ ci = cb + (size_t)i * 16 * 256 + pB;
      for (int j = 0; j < 16; ++j) {
        if (fabsf((float)j - ax) <= 1.0f) s += ci[(size_t)j * 256];
      }
    }
  }
  __shared__ float sm[256];
  sm[pB] = s;
  __syncthreads();
  for (int off = 128; off; off >>= 1) {
    if (pB < off) sm[pB] += sm[pB + off];
    __syncthreads();
  }
  if (pB == 0) out[b] = sm[0];
}

// ---------------------------------------------------------------- launch
extern "C" void kernel_launch(void* const* d_in, const int* in_sizes, int n_in,
                              void* d_out, int out_size, void* d_ws, size_t ws_size,
                              hipStream_t stream) {
  const float* imgA = (const float*)d_in[0];
  const float* imgB = (const float*)d_in[1];
  const float* W1 = (const float*)d_in[2];
  const float* W2 = (const float*)d_in[3];
  const float* W3 = (const float*)d_in[4];
  const float* W4 = (const float*)d_in[5];
  const float* Wr1 = (const float*)d_in[6];
  const float* Wr2 = (const float*)d_in[7];
  const float* Wd = (const float*)d_in[8];
  const float* bd = (const float*)d_in[9];

  float* ws = (float*)d_ws;
  unsigned short* WT2 = (unsigned short*)(ws + 0);
  unsigned short* WT3 = (unsigned short*)(ws + 36864);
  unsigned short* WT4 = (unsigned short*)(ws + 184320);
  unsigned short* WTr1 = (unsigned short*)(ws + 774144);
  unsigned short* WTr2 = (unsigned short*)(ws + 1576960);
  unsigned short* FEATs = (unsigned short*)(ws + 1679360);
  unsigned short* S3both = (unsigned short*)(ws + 5873664);
  unsigned short* S2both = (unsigned short*)(ws + 14262272);
  unsigned short* S1both = (unsigned short*)(ws + 31039488);
  unsigned short* FEATsp = (unsigned short*)(ws + 5873664);  // overlays S3both
  float* CORRf = ws + 14262272;                              // overlays S2both
  unsigned short* CORRh = (unsigned short*)(ws + 16359424);
  float* R1p = ws + 17408000;                                // 25 x 409600
  unsigned short* R1h = (unsigned short*)(ws + 27648000);
  float* R2p = ws + 27750400;                                // 25 x 73728
  float* R2f = ws + 29593600;
  float* GEOb = ws + 29667328;
  float* AXb = ws + 29667904;
  float* AYb = ws + 29676096;
  unsigned short* WT1 = (unsigned short*)(ws + 64593920);    // after S1both
  float* ZPf = ws + 64594944;                                // zero page (4KB)
  const unsigned short* ZP = (const unsigned short*)ZPf;

  // single prep kernel: zero page + all weight transposes (ws poisoned/iter)
  prep_all<<<13132, 256, 0, stream>>>(W1, W2, W3, W4, Wr1, Wr2,
                                      WT1, WT2, WT3, WT4, WTr1, WTr2, ZPf);

  // feature chain, both images per launch
  conv1_mfma<<<dim3(128, 64), 256, 0, stream>>>(imgA, imgB, WT1, S1both);
  // conv2: M = 64*4096 = 262144 -> 2048 blocks of 128x128
  tile_conv<128, 128, 64, 128, 3, 3, 2, 1, 0, 1, 0, 0, 1>
      <<<dim3(2048, 1), 256, 0, stream>>>(S1both, WT2, S2both, nullptr, ZP,
                                          128, 128, 64, 64, 0, 0);
  // conv3: M = 64*1024 = 65536 -> 512x2 of 128x128
  tile_conv<128, 128, 128, 256, 3, 3, 2, 1, 0, 1, 0, 0, 1>
      <<<dim3(512, 2), 256, 0, stream>>>(S2both, WT3, S3both, nullptr, ZP,
                                         64, 64, 32, 32, 0, 0);
  // conv4: M = 16384 -> 128x4 of 128x128
  tile_conv<128, 128, 256, 512, 3, 3, 2, 1, 0, 1, 0, 0, 1>
      <<<dim3(128, 4), 256, 0, stream>>>(S3both, WT4, FEATs, nullptr, ZP,
                                         32, 32, 16, 16, 0, 0);

  // l2norm: FEATs (single) -> FEATsp (split pair, lo at +8388608 el)
  l2norm_k<<<16384, 64, 0, stream>>>(FEATs, FEATsp, 8388608);
  // corr: tiled split GEMM (batched B), fp32 out + single fp16 hi out
  tile_conv<64, 64, 512, 256, 1, 1, 1, 0, 1, 1, 1, 1, 0>
      <<<dim3(128, 4), 256, 0, stream>>>(FEATsp, FEATsp + 4194304, CORRh, CORRf,
                                         ZP, 16, 16, 16, 16, 8388608, 8388608);
  // conv_r1: 128x128 tiles, split-K 25 -> fp32 partials (25 x 409600)
  tile_conv<128, 128, 256, 128, 7, 7, 1, 0, 0, 25, 0, 0, 0>
      <<<dim3(25, 1, 25), 256, 0, stream>>>(CORRh, WTr1, nullptr, R1p, ZP,
                                            16, 16, 10, 10, 0, 0);
  sum_relu_s<<<1600, 256, 0, stream>>>(R1p, R1h, 409600, 25);
  // conv_r2: direct single fp16, split-K 25
  gemm_conv<1, 4, 128, 64, 5, 5, 25>
      <<<dim3(18, 1, 25), 256, 0, stream>>>(R1h, WTr2, R2p, 10, 10, 6, 6);
  sum_relu_f<<<288, 256, 0, stream>>>(R2p, R2f, 73728, 25);
  dense_k<<<dim3(18, 32), 64, 0, stream>>>(R2f, Wd, bd, GEOb);
  tps_k<<<32, 64, 0, stream>>>(GEOb, AXb, AYb);
  masksum_k<<<32, 256, 0, stream>>>(CORRf, AXb, AYb, (float*)d_out);
}

// Round 12
// 412.095 us; speedup vs baseline: 1.2089x; 1.0132x over previous
//
#include <hip/hip_runtime.h>
#include <math.h>

// ---------------------------------------------------------------------------
// Round 19: regime-split tile_conv — db(BK64) for HBM-streamed, ring3(BK32)
// for cache-resident.
//   R18 counters: conv2/conv3 regressed to ~70us with FETCH 67->104MB /
//   ->123MB (BK=32 rows = 64B global segments -> 2x requests, half-wasted
//   128B granules, BW stuck at 2.45TB/s). conv4/corr/conv_r1 (L2/L3-resident
//   inputs) improved with ring-3's 3 blocks/CU. Regime rule: ring3/BK32 for
//   cache-resident inputs, dbuf/BK64 (128B segments) for HBM streams.
//   Both bodies are verbatim from passing rounds (R17=434us, R18=417us);
//   this round only routes call sites: conv2/conv3 -> tile_conv_db;
//   conv4/corr/conv_r1 -> tile_conv_r3.
//
//   conv1_mfma: R15 (float4 staging + LDS-bounce epilogue).
//   tps_k: LDS-parallel gauss (R8). prep_all: single prep kernel (R14).
//
// Workspace (float units), end 64595968 fl = 258.4 MB < 268.4 MB (256 MiB):
//   WT2@0(36864) WT3@36864(147456) WT4@184320(589824)
//   WTr1@774144(802816) WTr2@1576960(102400) -> 1679360
//   FEATs @1679360 (4194304)   both img, 16384 x 512 fp16
//   S3both@5873664 (8388608)   64 x 32x32x256 fp16
//   S2both@14262272 (16777216) 64 x 64x64x128 fp16
//   S1both@31039488 (33554432) 64 x 128x128x64 fp16
//   WT1@64593920 (1024) ZP@64594944 (1024)
//   post-chain overlays: FEATsp@5873664 CORRf@14262272(2097152)
//     CORRh@16359424(524288) R1p@17408000(25x409600) R1h@27648000
//     R2p@27750400(25x73728) R2f@29593600 GEO@29667328 AX@29667904
//     AY@29676096 -> end 29684288
// ---------------------------------------------------------------------------

typedef __attribute__((ext_vector_type(8))) _Float16 f16x8;
typedef __attribute__((ext_vector_type(4))) _Float16 f16x4;
typedef __attribute__((ext_vector_type(4))) float f32x4;

__device__ __forceinline__ unsigned short f2h(float f) {
  return __builtin_bit_cast(unsigned short, (_Float16)f);
}

// direct global->LDS DMA, 16B per lane (lane-linear LDS dest required)
__device__ __forceinline__ void gl16(const unsigned short* g, _Float16* l) {
  auto* gp = (const __attribute__((address_space(1))) unsigned int*)(g);
  auto* lp = (__attribute__((address_space(3))) unsigned int*)(l);
  __builtin_amdgcn_global_load_lds(gp, lp, 16, 0, 0);
}

// ---------------------------------------------------------------- prep (all)
__global__ __launch_bounds__(256) void prep_all(
    const float* __restrict__ W1, const float* __restrict__ W2,
    const float* __restrict__ W3, const float* __restrict__ W4,
    const float* __restrict__ Wr1, const float* __restrict__ Wr2,
    unsigned short* __restrict__ WT1, unsigned short* __restrict__ WT2,
    unsigned short* __restrict__ WT3, unsigned short* __restrict__ WT4,
    unsigned short* __restrict__ WTr1, unsigned short* __restrict__ WTr2,
    float* __restrict__ ZPf) {
  long idx = (long)blockIdx.x * 256 + threadIdx.x;
  if (idx < 1024) { ZPf[idx] = 0.f; return; }
  idx -= 1024;
  if (idx < 2048) {  // WT1: [64 out][32 k], k=(di*3+dj)*3+c, zero-pad 27..31
    const int o = (int)idx >> 5, k = (int)idx & 31;
    WT1[idx] = (k < 27) ? f2h(W1[(size_t)k * 64 + o]) : (unsigned short)0;
    return;
  }
  idx -= 2048;
  if (idx < 73728) {  // WT2: K=576, C=128
    const int k = (int)idx / 128, o = (int)idx % 128;
    WT2[(size_t)o * 576 + k] = f2h(W2[idx]);
    return;
  }
  idx -= 73728;
  if (idx < 294912) {  // WT3: K=1152, C=256
    const int k = (int)idx / 256, o = (int)idx % 256;
    WT3[(size_t)o * 1152 + k] = f2h(W3[idx]);
    return;
  }
  idx -= 294912;
  if (idx < 1179648) {  // WT4: K=2304, C=512
    const int k = (int)idx / 512, o = (int)idx % 512;
    WT4[(size_t)o * 2304 + k] = f2h(W4[idx]);
    return;
  }
  idx -= 1179648;
  if (idx < 1605632) {  // WTr1: K=12544, C=128
    const int k = (int)idx / 128, o = (int)idx % 128;
    WTr1[(size_t)o * 12544 + k] = f2h(Wr1[idx]);
    return;
  }
  idx -= 1605632;
  if (idx < 204800) {  // WTr2: K=3200, C=64
    const int k = (int)idx / 64, o = (int)idx % 64;
    WTr2[(size_t)o * 3200 + k] = f2h(Wr2[idx]);
  }
}

// ---------------------------------------------------------------- conv1 MFMA
// Both images per launch (b 0..63). One block per (out row i, batch b).
// float4 vector staging; LDS-bounce epilogue with 16B coalesced stores.
__global__ __launch_bounds__(256) void conv1_mfma(const float* __restrict__ inA,
                                                  const float* __restrict__ inB,
                                                  const unsigned short* __restrict__ wt1,
                                                  unsigned short* __restrict__ out) {
  const int i = blockIdx.x;   // output row 0..127
  const int b = blockIdx.y;   // virtual batch 0..63
  const int tid = threadIdx.x;
  const int lane = tid & 63, wid = tid >> 6;
  const int lrow = lane & 15, quad = lane >> 4;

  __shared__ _Float16 Rows[3][776];   // 8B-aligned rows; [768..770] = pad
  __shared__ _Float16 OutB[8192];     // 128 j x 64 ch bounce

  const float* __restrict__ img = (b < 32) ? inA : inB;
  const float* __restrict__ inb = img + (size_t)(b & 31) * 196608;
  const f16x4 z4 = {0, 0, 0, 0};
#pragma unroll
  for (int di = 0; di < 3; ++di) {
    const int y = 2 * i + di;
    if (tid < 192) {
      f16x4 h4 = z4;
      if (y < 256) {
        const float4 v4 = *(const float4*)(inb + (size_t)y * 768 + tid * 4);
        h4[0] = (_Float16)v4.x; h4[1] = (_Float16)v4.y;
        h4[2] = (_Float16)v4.z; h4[3] = (_Float16)v4.w;
      }
      *(f16x4*)&Rows[di][tid * 4] = h4;
    }
    if (tid < 3) Rows[di][768 + tid] = (_Float16)0.f;
  }
  __syncthreads();

  // B fragments: all 64 cols, straight from WT1[64][32]
  f16x8 bf[4];
#pragma unroll
  for (int ni = 0; ni < 4; ++ni)
    bf[ni] = *(const f16x8*)(wt1 + (ni * 16 + lrow) * 32 + quad * 8);

  // A fragments: im2col gather. k=(di*3+dj)*3+c -> di=k/9, dj=(k/3)%3, c=k%3
  f16x8 af[2];
#pragma unroll
  for (int mi = 0; mi < 2; ++mi) {
    const int j = wid * 32 + mi * 16 + lrow;
#pragma unroll
    for (int s = 0; s < 8; ++s) {
      const int k = quad * 8 + s;
      if (k < 27) {
        const int di = k / 9, dj = (k / 3) % 3, c = k % 3;
        af[mi][s] = Rows[di][(2 * j + dj) * 3 + c];
      } else {
        af[mi][s] = (_Float16)0.f;
      }
    }
  }

  f32x4 acc[2][4];
#pragma unroll
  for (int mi = 0; mi < 2; ++mi)
#pragma unroll
    for (int ni = 0; ni < 4; ++ni) {
      const f32x4 z = {0.f, 0.f, 0.f, 0.f};
      acc[mi][ni] = __builtin_amdgcn_mfma_f32_16x16x32_f16(af[mi], bf[ni], z, 0, 0, 0);
    }

  // bounce: j = wid*32+mi*16+quad*4+r, ch = ni*16+lrow; swizzle ch bits 4-5
#pragma unroll
  for (int mi = 0; mi < 2; ++mi)
#pragma unroll
    for (int ni = 0; ni < 4; ++ni)
#pragma unroll
      for (int r = 0; r < 4; ++r) {
        const int j = wid * 32 + mi * 16 + quad * 4 + r;
        const int ch = ni * 16 + lrow;
        OutB[j * 64 + (ch ^ (((j >> 2) & 3) << 4))] =
            (_Float16)fmaxf(acc[mi][ni][r], 0.f);
      }
  __syncthreads();

  unsigned short* __restrict__ ob = out + (((size_t)b * 128 + i) * 128) * 64;
#pragma unroll
  for (int q2 = 0; q2 < 4; ++q2) {
    const int v = tid + 256 * q2;
    const int j = v >> 3, c0 = (v & 7) * 8;
    const f16x8 pack = *(const f16x8*)&OutB[j * 64 + (c0 ^ (((j >> 2) & 3) << 4))];
    *(f16x8*)&ob[(size_t)j * 64 + c0] = pack;
  }
}

// ---------------------------------------------------------------- tile_conv_db
// R17 body: BK=64 chunks, double buffer, 2 barriers/chunk, counted vmcnt
// (2 chunks in flight), 128B global segments. For HBM-streamed inputs.
template <int BM, int BN, int CIN, int COUT, int KH, int KW, int STRIDE,
          int SAMEPAD, int SPLIT, int SK, int BATB, int OUTF32, int RELU>
__global__ __launch_bounds__(256) void tile_conv_db(
    const unsigned short* __restrict__ in, const unsigned short* __restrict__ wt,
    unsigned short* __restrict__ outh, float* __restrict__ outf,
    const unsigned short* __restrict__ zp,
    int Hin, int Win, int Hout, int Wout, int aLo, int bLo) {
  constexpr int CPT = CIN / 64;
  constexpr int LA = BM / 32;
  constexpr int LB = BN / 32;
  constexpr int KTOT = KH * KW * CIN;
  constexpr int MT = BM / 32;
  constexpr int NT = BN / 32;
  constexpr int PL = 1 + SPLIT;
  constexpr int LPS = PL * (LA + LB);
  constexpr unsigned WCN =
      (unsigned)((LPS & 0xF) | (0x7 << 4) | (0xF << 8) | ((LPS >> 4) << 14));
  constexpr unsigned WC0 = (unsigned)((0x7 << 4) | (0xF << 8));
  __shared__ _Float16 As[2][PL * BM * 64];
  __shared__ _Float16 Bs[2][PL * BN * 64];
  static_assert(SK > 1 || (size_t)BM * BN <= sizeof(As) / sizeof(_Float16),
                "bounce must fit in As");

  const int t = threadIdx.x;
  const int lane = t & 63, wid = t >> 6;
  const int lrow = lane & 15, quad = lane >> 4;
  const int m0 = blockIdx.x * BM;
  const int n0 = blockIdx.y * BN;

  const int q8 = ((t & 7) ^ ((t >> 3) & 7)) * 8;

  int pixB[LA], iS[LA], jS[LA];
#pragma unroll
  for (int i = 0; i < LA; ++i) {
    const int r = (t >> 3) + 32 * i;
    const int m = m0 + r;
    const int j = m % Wout;
    const int t2 = m / Wout;
    const int ii = t2 % Hout;
    const int b = t2 / Hout;
    iS[i] = ii * STRIDE;
    jS[i] = j * STRIDE;
    pixB[i] = ((b * Hin + iS[i]) * Win + jS[i]) * CIN + q8;
  }
  const unsigned short* wb = wt;
  if (BATB) wb += (size_t)(m0 / (Hout * Wout)) * COUT * KTOT;
  int bofB[LB];
#pragma unroll
  for (int i = 0; i < LB; ++i) {
    const int r = (t >> 3) + 32 * i;
    bofB[i] = (n0 + r) * KTOT + q8;
  }

  f32x4 acc[MT][NT];
#pragma unroll
  for (int mi = 0; mi < MT; ++mi)
#pragma unroll
    for (int ni = 0; ni < NT; ++ni) acc[mi][ni] = {0.f, 0.f, 0.f, 0.f};

  const int mB = (wid >> 1) * (BM / 2);
  const int nB = (wid & 1) * (BN / 2);

  int tap_lo = 0, tap_hi = KH * KW;
  if (SK > 1) {
    tap_lo = (int)blockIdx.z * KH * KW / SK;
    tap_hi = ((int)blockIdx.z + 1) * KH * KW / SK;
  }
  const int ch_lo = tap_lo * CPT, ch_hi = tap_hi * CPT;

  auto stage = [&](int buf, int ch) {
    const int tap = ch / CPT;
    const int c0 = (ch % CPT) * 64;
    const int di = tap / KW, dj = tap % KW;
    const int toff = (di * Win + dj) * CIN + c0;
    const int woff = tap * CIN + c0;
#pragma unroll
    for (int i = 0; i < LA; ++i) {
      const bool ok = !SAMEPAD || ((iS[i] + di < Hin) && (jS[i] + dj < Win));
      const unsigned short* s0 = ok ? in + pixB[i] + toff : zp + q8;
      gl16(s0, &As[buf][t * 8 + 2048 * i]);
      if (SPLIT) {
        const unsigned short* s1 = ok ? in + pixB[i] + toff + aLo : zp + q8;
        gl16(s1, &As[buf][BM * 64 + t * 8 + 2048 * i]);
      }
    }
#pragma unroll
    for (int i = 0; i < LB; ++i) {
      gl16(wb + bofB[i] + woff, &Bs[buf][t * 8 + 2048 * i]);
      if (SPLIT)
        gl16(wb + bofB[i] + woff + bLo, &Bs[buf][BN * 64 + t * 8 + 2048 * i]);
    }
  };

  stage(0, ch_lo);
  if (ch_lo + 1 < ch_hi) stage(1, ch_lo + 1);
  int cur = 0;
  for (int ch = ch_lo; ch < ch_hi; ++ch) {
    if (ch + 1 < ch_hi) __builtin_amdgcn_s_waitcnt(WCN);
    else __builtin_amdgcn_s_waitcnt(WC0);
    __builtin_amdgcn_sched_barrier(0);
    __builtin_amdgcn_s_barrier();       // chunk-ch data visible
    __builtin_amdgcn_sched_barrier(0);
#pragma unroll
    for (int ks = 0; ks < 2; ++ks) {
      f16x8 af[MT], bf[NT], al[MT], bl[NT];
#pragma unroll
      for (int mi = 0; mi < MT; ++mi) {
        const int row = mB + mi * 16 + lrow;
        const int off = row * 64 + (((ks * 4 + quad) ^ (row & 7)) * 8);
        af[mi] = *(const f16x8*)&As[cur][off];
        if (SPLIT) al[mi] = *(const f16x8*)&As[cur][BM * 64 + off];
      }
#pragma unroll
      for (int ni = 0; ni < NT; ++ni) {
        const int row = nB + ni * 16 + lrow;
        const int off = row * 64 + (((ks * 4 + quad) ^ (row & 7)) * 8);
        bf[ni] = *(const f16x8*)&Bs[cur][off];
        if (SPLIT) bl[ni] = *(const f16x8*)&Bs[cur][BN * 64 + off];
      }
#pragma unroll
      for (int mi = 0; mi < MT; ++mi)
#pragma unroll
        for (int ni = 0; ni < NT; ++ni) {
          if (SPLIT) {
            acc[mi][ni] = __builtin_amdgcn_mfma_f32_16x16x32_f16(af[mi], bl[ni],
                                                                 acc[mi][ni], 0, 0, 0);
            acc[mi][ni] = __builtin_amdgcn_mfma_f32_16x16x32_f16(al[mi], bf[ni],
                                                                 acc[mi][ni], 0, 0, 0);
          }
          acc[mi][ni] = __builtin_amdgcn_mfma_f32_16x16x32_f16(af[mi], bf[ni],
                                                               acc[mi][ni], 0, 0, 0);
        }
    }
    __builtin_amdgcn_sched_barrier(0);
    __builtin_amdgcn_s_barrier();       // all waves done reading buf[cur]
    __builtin_amdgcn_sched_barrier(0);
    if (ch + 2 < ch_hi) stage(cur, ch + 2);
    cur ^= 1;
  }

  if (SK > 1) {
    const size_t slice = (size_t)blockIdx.z * ((size_t)gridDim.x * BM * COUT);
#pragma unroll
    for (int mi = 0; mi < MT; ++mi)
#pragma unroll
      for (int ni = 0; ni < NT; ++ni)
#pragma unroll
        for (int r = 0; r < 4; ++r) {
          const int row = m0 + mB + mi * 16 + quad * 4 + r;
          const int col = n0 + nB + ni * 16 + lrow;
          outf[slice + (size_t)row * COUT + col] = acc[mi][ni][r];
        }
  } else {
    _Float16* bounce = &As[0][0];
#pragma unroll
    for (int mi = 0; mi < MT; ++mi)
#pragma unroll
      for (int ni = 0; ni < NT; ++ni)
#pragma unroll
        for (int r = 0; r < 4; ++r) {
          const int row = mB + mi * 16 + quad * 4 + r;
          const int col = nB + ni * 16 + lrow;
          float v = acc[mi][ni][r];
          if (OUTF32) {
            outf[(size_t)(m0 + row) * COUT + n0 + col] = v;
          } else if (RELU) {
            v = fmaxf(v, 0.f);
          }
          bounce[row * BN + (col ^ (((row >> 2) & 3) << 4))] = (_Float16)v;
        }
    __syncthreads();
    constexpr int VPT = (BM * BN / 8) / 256;
#pragma unroll
    for (int q2 = 0; q2 < VPT; ++q2) {
      const int v = t + 256 * q2;
      const int rowL = v / (BN / 8);
      const int c0 = (v % (BN / 8)) * 8;
      const f16x8 pack =
          *(const f16x8*)&bounce[rowL * BN + (c0 ^ (((rowL >> 2) & 3) << 4))];
      *(f16x8*)&outh[(size_t)(m0 + rowL) * COUT + n0 + c0] = pack;
    }
  }
}

// ---------------------------------------------------------------- tile_conv_r3
// R18 body: BK=32 chunks, ring-3 buffers, ONE barrier/chunk, counted vmcnt.
// For cache-resident inputs (64B segments absorbed by L2/L3); 3 blocks/CU.
template <int BM, int BN, int CIN, int COUT, int KH, int KW, int STRIDE,
          int SAMEPAD, int SPLIT, int SK, int BATB, int OUTF32, int RELU>
__global__ __launch_bounds__(256) void tile_conv_r3(
    const unsigned short* __restrict__ in, const unsigned short* __restrict__ wt,
    unsigned short* __restrict__ outh, float* __restrict__ outf,
    const unsigned short* __restrict__ zp,
    int Hin, int Win, int Hout, int Wout, int aLo, int bLo) {
  constexpr int CPT = CIN / 32;
  constexpr int LA = BM / 64;
  constexpr int LB = BN / 64;
  constexpr int KTOT = KH * KW * CIN;
  constexpr int MT = BM / 32;
  constexpr int NT = BN / 32;
  constexpr int PL = 1 + SPLIT;
  constexpr int LPS = PL * (LA + LB);
  constexpr int ASTR = PL * BM * 32;
  constexpr int BSTR = PL * BN * 32;
  constexpr unsigned WCN =
      (unsigned)((LPS & 0xF) | (0x7 << 4) | (0xF << 8) | ((LPS >> 4) << 14));
  constexpr unsigned WC0 = (unsigned)((0x7 << 4) | (0xF << 8));
  __shared__ _Float16 SH[3 * (ASTR + BSTR)];
  static_assert(SK > 1 || (size_t)BM * BN <= (size_t)3 * (ASTR + BSTR),
                "bounce must fit in SH");

  const int t = threadIdx.x;
  const int lane = t & 63, wid = t >> 6;
  const int lrow = lane & 15, quad = lane >> 4;
  const int m0 = blockIdx.x * BM;
  const int n0 = blockIdx.y * BN;

  const int q8 = ((t & 3) ^ ((t >> 3) & 3)) * 8;

  int pixB[LA], iS[LA], jS[LA];
#pragma unroll
  for (int i = 0; i < LA; ++i) {
    const int r = (t >> 2) + 64 * i;
    const int m = m0 + r;
    const int j = m % Wout;
    const int t2 = m / Wout;
    const int ii = t2 % Hout;
    const int b = t2 / Hout;
    iS[i] = ii * STRIDE;
    jS[i] = j * STRIDE;
    pixB[i] = ((b * Hin + iS[i]) * Win + jS[i]) * CIN + q8;
  }
  const unsigned short* wb = wt;
  if (BATB) wb += (size_t)(m0 / (Hout * Wout)) * COUT * KTOT;
  int bofB[LB];
#pragma unroll
  for (int i = 0; i < LB; ++i) {
    const int r = (t >> 2) + 64 * i;
    bofB[i] = (n0 + r) * KTOT + q8;
  }

  f32x4 acc[MT][NT];
#pragma unroll
  for (int mi = 0; mi < MT; ++mi)
#pragma unroll
    for (int ni = 0; ni < NT; ++ni) acc[mi][ni] = {0.f, 0.f, 0.f, 0.f};

  const int mB = (wid >> 1) * (BM / 2);
  const int nB = (wid & 1) * (BN / 2);

  int offA[MT], offB[NT];
#pragma unroll
  for (int mi = 0; mi < MT; ++mi) {
    const int row = mB + mi * 16 + lrow;
    offA[mi] = row * 32 + ((quad ^ ((row >> 1) & 3)) * 8);
  }
#pragma unroll
  for (int ni = 0; ni < NT; ++ni) {
    const int row = nB + ni * 16 + lrow;
    offB[ni] = row * 32 + ((quad ^ ((row >> 1) & 3)) * 8);
  }

  int tap_lo = 0, tap_hi = KH * KW;
  if (SK > 1) {
    tap_lo = (int)blockIdx.z * KH * KW / SK;
    tap_hi = ((int)blockIdx.z + 1) * KH * KW / SK;
  }
  const int ch_lo = tap_lo * CPT, ch_hi = tap_hi * CPT;

  auto stage = [&](int buf, int ch) {
    const int tap = ch / CPT;
    const int c0 = (ch & (CPT - 1)) * 32;
    const int di = tap / KW, dj = tap % KW;
    const int toff = (di * Win + dj) * CIN + c0;
    const int woff = tap * CIN + c0;
    _Float16* aB = SH + buf * ASTR;
    _Float16* bB = SH + 3 * ASTR + buf * BSTR;
#pragma unroll
    for (int i = 0; i < LA; ++i) {
      const bool ok = !SAMEPAD || ((iS[i] + di < Hin) && (jS[i] + dj < Win));
      const unsigned short* s0 = ok ? in + pixB[i] + toff : zp + q8;
      gl16(s0, aB + t * 8 + 2048 * i);
      if (SPLIT) {
        const unsigned short* s1 = ok ? in + pixB[i] + toff + aLo : zp + q8;
        gl16(s1, aB + BM * 32 + t * 8 + 2048 * i);
      }
    }
#pragma unroll
    for (int i = 0; i < LB; ++i) {
      gl16(wb + bofB[i] + woff, bB + t * 8 + 2048 * i);
      if (SPLIT)
        gl16(wb + bofB[i] + woff + bLo, bB + BN * 32 + t * 8 + 2048 * i);
    }
  };

  stage(0, ch_lo);
  if (ch_lo + 1 < ch_hi) stage(1, ch_lo + 1);
  int cur = 0;
  for (int ch = ch_lo; ch < ch_hi; ++ch) {
    if (ch + 1 < ch_hi) __builtin_amdgcn_s_waitcnt(WCN);
    else __builtin_amdgcn_s_waitcnt(WC0);
    __builtin_amdgcn_sched_barrier(0);
    __builtin_amdgcn_s_barrier();  // chunk-ch ready AND buf[cur-1] reads done
    __builtin_amdgcn_sched_barrier(0);
    if (ch + 2 < ch_hi) stage(cur == 0 ? 2 : cur - 1, ch + 2);
    {
      const _Float16* aB = SH + cur * ASTR;
      const _Float16* bB = SH + 3 * ASTR + cur * BSTR;
      f16x8 af[MT], bf[NT], al[MT], bl[NT];
#pragma unroll
      for (int mi = 0; mi < MT; ++mi) {
        af[mi] = *(const f16x8*)&aB[offA[mi]];
        if (SPLIT) al[mi] = *(const f16x8*)&aB[BM * 32 + offA[mi]];
      }
#pragma unroll
      for (int ni = 0; ni < NT; ++ni) {
        bf[ni] = *(const f16x8*)&bB[offB[ni]];
        if (SPLIT) bl[ni] = *(const f16x8*)&bB[BN * 32 + offB[ni]];
      }
#pragma unroll
      for (int mi = 0; mi < MT; ++mi)
#pragma unroll
        for (int ni = 0; ni < NT; ++ni) {
          if (SPLIT) {
            acc[mi][ni] = __builtin_amdgcn_mfma_f32_16x16x32_f16(af[mi], bl[ni],
                                                                 acc[mi][ni], 0, 0, 0);
            acc[mi][ni] = __builtin_amdgcn_mfma_f32_16x16x32_f16(al[mi], bf[ni],
                                                                 acc[mi][ni], 0, 0, 0);
          }
          acc[mi][ni] = __builtin_amdgcn_mfma_f32_16x16x32_f16(af[mi], bf[ni],
                                                               acc[mi][ni], 0, 0, 0);
        }
    }
    cur = (cur == 2) ? 0 : cur + 1;
  }

  if (SK > 1) {
    const size_t slice = (size_t)blockIdx.z * ((size_t)gridDim.x * BM * COUT);
#pragma unroll
    for (int mi = 0; mi < MT; ++mi)
#pragma unroll
      for (int ni = 0; ni < NT; ++ni)
#pragma unroll
        for (int r = 0; r < 4; ++r) {
          const int row = m0 + mB + mi * 16 + quad * 4 + r;
          const int col = n0 + nB + ni * 16 + lrow;
          outf[slice + (size_t)row * COUT + col] = acc[mi][ni][r];
        }
  } else {
    __syncthreads();  // all waves done with SH
    _Float16* bounce = &SH[0];
#pragma unroll
    for (int mi = 0; mi < MT; ++mi)
#pragma unroll
      for (int ni = 0; ni < NT; ++ni)
#pragma unroll
        for (int r = 0; r < 4; ++r) {
          const int row = mB + mi * 16 + quad * 4 + r;
          const int col = nB + ni * 16 + lrow;
          float v = acc[mi][ni][r];
          if (OUTF32) {
            outf[(size_t)(m0 + row) * COUT + n0 + col] = v;
          } else if (RELU) {
            v = fmaxf(v, 0.f);
          }
          bounce[row * BN + (col ^ (((row >> 2) & 3) << 4))] = (_Float16)v;
        }
    __syncthreads();
    constexpr int VPT = (BM * BN / 8) / 256;
#pragma unroll
    for (int q2 = 0; q2 < VPT; ++q2) {
      const int v = t + 256 * q2;
      const int rowL = v / (BN / 8);
      const int c0 = (v % (BN / 8)) * 8;
      const f16x8 pack =
          *(const f16x8*)&bounce[rowL * BN + (c0 ^ (((rowL >> 2) & 3) << 4))];
      *(f16x8*)&outh[(size_t)(m0 + rowL) * COUT + n0 + c0] = pack;
    }
  }
}

// ---------------------------------------------------------------- direct MFMA
// kept for conv_r2 (tiny), single plane.
template <int MT, int NT, int CIN, int COUT, int KH, int KW, int SK>
__global__ __launch_bounds__(256) void gemm_conv(
    const unsigned short* __restrict__ in, const unsigned short* __restrict__ wt,
    float* __restrict__ outf, int Hin, int Win, int Hout, int Wout) {
  const int KTOT = KH * KW * CIN;
  const int lane = threadIdx.x & 63;
  const int wid = threadIdx.x >> 6;
  const int lrow = lane & 15;
  const int quad = lane >> 4;
  const int m0 = (blockIdx.x * 4 + wid) * (16 * MT);
  const int n0 = blockIdx.y * (16 * NT);

  int pix[MT];
#pragma unroll
  for (int mi = 0; mi < MT; ++mi) {
    const int m = m0 + mi * 16 + lrow;
    const int j = m % Wout;
    const int t = m / Wout;
    const int i = t % Hout;
    const int b = t / Hout;
    pix[mi] = (b * Hin + i) * Win + j;
  }
  const unsigned short* brow[NT];
#pragma unroll
  for (int ni = 0; ni < NT; ++ni)
    brow[ni] = wt + (size_t)(n0 + ni * 16 + lrow) * KTOT + quad * 8;

  f32x4 acc[MT][NT];
#pragma unroll
  for (int mi = 0; mi < MT; ++mi)
#pragma unroll
    for (int ni = 0; ni < NT; ++ni) acc[mi][ni] = {0.f, 0.f, 0.f, 0.f};

  const int tap_lo = (int)blockIdx.z * KH * KW / SK;
  const int tap_hi = ((int)blockIdx.z + 1) * KH * KW / SK;
  for (int tap = tap_lo; tap < tap_hi; ++tap) {
    const int di = tap / KW, dj = tap % KW;
    const unsigned short* ap[MT];
#pragma unroll
    for (int mi = 0; mi < MT; ++mi)
      ap[mi] = in + ((size_t)pix[mi] + di * Win + dj) * CIN + quad * 8;
    const int ko = tap * CIN;
#pragma unroll
    for (int c0 = 0; c0 < CIN; c0 += 32) {
      f16x8 ah[MT], bh[NT];
#pragma unroll
      for (int mi = 0; mi < MT; ++mi) ah[mi] = *(const f16x8*)(ap[mi] + c0);
#pragma unroll
      for (int ni = 0; ni < NT; ++ni) bh[ni] = *(const f16x8*)(brow[ni] + ko + c0);
#pragma unroll
      for (int mi = 0; mi < MT; ++mi)
#pragma unroll
        for (int ni = 0; ni < NT; ++ni)
          acc[mi][ni] = __builtin_amdgcn_mfma_f32_16x16x32_f16(ah[mi], bh[ni],
                                                               acc[mi][ni], 0, 0, 0);
    }
  }
  const size_t slice = (size_t)blockIdx.z * ((size_t)gridDim.x * 64 * MT * COUT);
#pragma unroll
  for (int mi = 0; mi < MT; ++mi)
#pragma unroll
    for (int ni = 0; ni < NT; ++ni)
#pragma unroll
      for (int r = 0; r < 4; ++r) {
        const int row = m0 + mi * 16 + quad * 4 + r;
        const int col = n0 + ni * 16 + lrow;
        outf[slice + (size_t)row * COUT + col] = acc[mi][ni][r];
      }
}

// ---------------------------------------------------------------- split-K epi
__global__ __launch_bounds__(256) void sum_relu_s(const float* __restrict__ p,
                                                  unsigned short* __restrict__ o,
                                                  int n, int parts) {
  const int idx = blockIdx.x * 256 + threadIdx.x;
  if (idx < n) {
    float v = 0.f;
    for (int s = 0; s < parts; ++s) v += p[(size_t)s * n + idx];
    o[idx] = f2h(fmaxf(v, 0.f));
  }
}
__global__ __launch_bounds__(256) void sum_relu_f(const float* __restrict__ p,
                                                  float* __restrict__ o,
                                                  int n, int parts) {
  const int idx = blockIdx.x * 256 + threadIdx.x;
  if (idx < n) {
    float v = 0.f;
    for (int s = 0; s < parts; ++s) v += p[(size_t)s * n + idx];
    o[idx] = fmaxf(v, 0.f);
  }
}

// ---------------------------------------------------------------- l2 normalize
// in: single fp16; out: split pair (hi @y, lo @y+loOff).
__global__ __launch_bounds__(64) void l2norm_k(const unsigned short* __restrict__ x,
                                               unsigned short* __restrict__ y,
                                               int loOff) {
  const int lane = threadIdx.x;
  const f16x8 v = *(const f16x8*)(x + (size_t)blockIdx.x * 512 + lane * 8);
  float f[8];
  float s = 0.f;
#pragma unroll
  for (int k = 0; k < 8; ++k) {
    f[k] = (float)v[k];
    s += f[k] * f[k];
  }
#pragma unroll
  for (int off = 32; off; off >>= 1) s += __shfl_xor(s, off, 64);
  const float inv = 1.f / (sqrtf(s) + 1e-6f);
  f16x8 vh, vl;
#pragma unroll
  for (int k = 0; k < 8; ++k) {
    const float nv = f[k] * inv;
    const _Float16 hi = (_Float16)nv;
    vh[k] = hi;
    vl[k] = (_Float16)(nv - (float)hi);
  }
  unsigned short* ph = y + (size_t)blockIdx.x * 512 + lane * 8;
  *(f16x8*)ph = vh;
  *(f16x8*)(ph + (size_t)loOff) = vl;
}

// ---------------------------------------------------------------- dense
__global__ __launch_bounds__(64) void dense_k(const float* __restrict__ r2,
                                              const float* __restrict__ wd,
                                              const float* __restrict__ bd,
                                              float* __restrict__ geo) {
  const int o = blockIdx.x;
  const int b = blockIdx.y;
  const int lane = threadIdx.x;
  const float* __restrict__ rb = r2 + (size_t)b * 2304;
  float s = 0.f;
  for (int k = lane; k < 2304; k += 64) s += rb[k] * wd[(size_t)k * 18 + o];
#pragma unroll
  for (int off = 32; off; off >>= 1) s += __shfl_xor(s, off, 64);
  if (lane == 0) geo[b * 18 + o] = s + bd[o];
}

// ---------------------------------------------------------------- TPS
// LDS-parallel version (R8). One block (1 wave) per batch.
__device__ __forceinline__ float tps_u(float r) { return r * r * logf(r + 1e-6f); }

__global__ __launch_bounds__(64) void tps_k(const float* __restrict__ geo,
                                            float* __restrict__ axb,
                                            float* __restrict__ ayb) {
  const int b = blockIdx.x;
  const int tid = threadIdx.x;
  __shared__ float M[12][14];
  __shared__ float fel[12];
  __shared__ float dxs[9], dys[9];
  __shared__ float th[2][12];   // [0]=x theta, [1]=y theta
  __shared__ float sW[2][9];
  __shared__ float sA[2][3];
  __shared__ int sPiv;

  const float srcx[9] = {0.f, 0.5f, 1.f, 0.f, 0.5f, 1.f, 0.f, 5.f, 1.f};
  const float srcy[9] = {0.f, 0.f, 0.f, 0.5f, 0.5f, 0.5f, 1.f, 1.f, 1.f};

  // dst points + RHS columns (12,13)
  if (tid < 9) {
    const float mx = geo[b * 18 + 2 * tid], my = geo[b * 18 + 2 * tid + 1];
    dxs[tid] = srcx[tid] + mx;
    dys[tid] = srcy[tid] + my;
    M[tid][12] = -mx;
    M[tid][13] = -my;
  } else if (tid < 12) {
    M[tid][12] = 0.f;
    M[tid][13] = 0.f;
  }
  __syncthreads();
  // K block: 81 tps_u entries in parallel
  for (int e = tid; e < 81; e += 64) {
    const int p = e / 9, q = e % 9;
    const float ddx = dxs[p] - dxs[q], ddy = dys[p] - dys[q];
    const float r = sqrtf(ddx * ddx + ddy * ddy + 1e-12f);
    M[p][q] = tps_u(r);
  }
  // P blocks + zero bottom-right 3x3
  if (tid < 9) {
    M[tid][9] = 1.f;  M[tid][10] = dxs[tid]; M[tid][11] = dys[tid];
    M[9][tid] = 1.f;  M[10][tid] = dxs[tid]; M[11][tid] = dys[tid];
  } else if (tid < 12) {
    M[tid][9] = 0.f; M[tid][10] = 0.f; M[tid][11] = 0.f;
  }
  __syncthreads();

  // Gaussian elimination with partial pivoting (same arithmetic/order as R7)
  for (int k = 0; k < 12; ++k) {
    if (tid == 0) {
      int piv = k;
      float best = fabsf(M[k][k]);
      for (int r = k + 1; r < 12; ++r) {
        const float v = fabsf(M[r][k]);
        if (v > best) { best = v; piv = r; }
      }
      sPiv = piv;
    }
    __syncthreads();
    const int piv = sPiv;
    if (piv != k && tid < 14) {
      const float tmp = M[k][tid];
      M[k][tid] = M[piv][tid];
      M[piv][tid] = tmp;
    }
    __syncthreads();
    if (tid > k && tid < 12) fel[tid] = M[tid][k] / M[k][k];
    __syncthreads();
    for (int e = tid; e < (11 - k) * 14; e += 64) {
      const int r = k + 1 + e / 14, cc = e % 14;
      if (cc >= k) M[r][cc] -= fel[r] * M[k][cc];
    }
    __syncthreads();
  }

  // Back substitution: lanes 0-15 -> x (RHS col 12), lanes 16-31 -> y (col 13)
  const int grp = tid >> 4;
  const int cc = tid & 15;
  for (int k = 11; k >= 0; --k) {
    float prod = 0.f;
    if (grp < 2 && cc > k && cc < 12) prod = M[k][cc] * th[grp][cc];
#pragma unroll
    for (int off = 8; off; off >>= 1) prod += __shfl_xor(prod, off, 16);
    if (grp < 2 && cc == 0) th[grp][k] = (M[k][12 + grp] - prod) / M[k][k];
    __syncthreads();
  }

  // w/a extraction: w[0] = -sum(theta[1..8]), w[p]=theta[p], a = theta[9..11]
  if (tid < 2) {
    float sw = 0.f;
    for (int p = 1; p < 9; ++p) {
      sW[tid][p] = th[tid][p];
      sw += th[tid][p];
    }
    sW[tid][0] = -sw;
    sA[tid][0] = th[tid][9];
    sA[tid][1] = th[tid][10];
    sA[tid][2] = th[tid][11];
  }
  __syncthreads();

  // evaluate warp field on the 16x16 grid (4 points per lane)
  for (int p = tid; p < 256; p += 64) {
    const int pi = p >> 4, pj = p & 15;
    const float x = pj * (1.f / 15.f), y = pi * (1.f / 15.f);
    float zx = sA[0][0] + x * sA[0][1] + y * sA[0][2];
    float zy = sA[1][0] + x * sA[1][1] + y * sA[1][2];
#pragma unroll
    for (int c = 0; c < 9; ++c) {
      const float ddx = x - dxs[c], ddy = y - dys[c];
      const float r = sqrtf(ddx * ddx + ddy * ddy + 1e-12f);
      const float u = tps_u(r);
      zx += u * sW[0][c];
      zy += u * sW[1][c];
    }
    axb[b * 256 + p] = (x + zx) * 15.f;
    ayb[b * 256 + p] = (y + zy) * 15.f;
  }
}

// ---------------------------------------------------------------- masked sum
__global__ __launch_bounds__(256) void masksum_k(const float* __restrict__ corr,
                                                 const float* __restrict__ axb,
                                                 const float* __restrict__ ayb,
                                                 float* __restrict__ out) {
  const int b = blockIdx.x;
  const int pB = threadIdx.x;
  const float ax = axb[b * 256 + pB];
  const float ay = ayb[b * 256 + pB];
  const float* __restrict__ cb = corr + (size_t)b * 65536;
  float s = 0.f;
  for (int i = 0; i < 16; ++i) {
    if (fabsf((float)i - ay) <= 1.0f) {
      const float* __restrict__ ci = cb + (size_t)i * 16 * 256 + pB;
      for (int j = 0; j < 16; ++j) {
        if (fabsf((float)j - ax) <= 1.0f) s += ci[(size_t)j * 256];
      }
    }
  }
  __shared__ float sm[256];
  sm[pB] = s;
  __syncthreads();
  for (int off = 128; off; off >>= 1) {
    if (pB < off) sm[pB] += sm[pB + off];
    __syncthreads();
  }
  if (pB == 0) out[b] = sm[0];
}

// ---------------------------------------------------------------- launch
extern "C" void kernel_launch(void* const* d_in, const int* in_sizes, int n_in,
                              void* d_out, int out_size, void* d_ws, size_t ws_size,
                              hipStream_t stream) {
  const float* imgA = (const float*)d_in[0];
  const float* imgB = (const float*)d_in[1];
  const float* W1 = (const float*)d_in[2];
  const float* W2 = (const float*)d_in[3];
  const float* W3 = (const float*)d_in[4];
  const float* W4 = (const float*)d_in[5];
  const float* Wr1 = (const float*)d_in[6];
  const float* Wr2 = (const float*)d_in[7];
  const float* Wd = (const float*)d_in[8];
  const float* bd = (const float*)d_in[9];

  float* ws = (float*)d_ws;
  unsigned short* WT2 = (unsigned short*)(ws + 0);
  unsigned short* WT3 = (unsigned short*)(ws + 36864);
  unsigned short* WT4 = (unsigned short*)(ws + 184320);
  unsigned short* WTr1 = (unsigned short*)(ws + 774144);
  unsigned short* WTr2 = (unsigned short*)(ws + 1576960);
  unsigned short* FEATs = (unsigned short*)(ws + 1679360);
  unsigned short* S3both = (unsigned short*)(ws + 5873664);
  unsigned short* S2both = (unsigned short*)(ws + 14262272);
  unsigned short* S1both = (unsigned short*)(ws + 31039488);
  unsigned short* FEATsp = (unsigned short*)(ws + 5873664);  // overlays S3both
  float* CORRf = ws + 14262272;                              // overlays S2both
  unsigned short* CORRh = (unsigned short*)(ws + 16359424);
  float* R1p = ws + 17408000;                                // 25 x 409600
  unsigned short* R1h = (unsigned short*)(ws + 27648000);
  float* R2p = ws + 27750400;                                // 25 x 73728
  float* R2f = ws + 29593600;
  float* GEOb = ws + 29667328;
  float* AXb = ws + 29667904;
  float* AYb = ws + 29676096;
  unsigned short* WT1 = (unsigned short*)(ws + 64593920);    // after S1both
  float* ZPf = ws + 64594944;                                // zero page (4KB)
  const unsigned short* ZP = (const unsigned short*)ZPf;

  // single prep kernel: zero page + all weight transposes (ws poisoned/iter)
  prep_all<<<13132, 256, 0, stream>>>(W1, W2, W3, W4, Wr1, Wr2,
                                      WT1, WT2, WT3, WT4, WTr1, WTr2, ZPf);

  // feature chain, both images per launch
  conv1_mfma<<<dim3(128, 64), 256, 0, stream>>>(imgA, imgB, WT1, S1both);
  // conv2 (HBM-streamed 67MB input): db/BK64, M = 262144 -> 2048x 128x128
  tile_conv_db<128, 128, 64, 128, 3, 3, 2, 1, 0, 1, 0, 0, 1>
      <<<dim3(2048, 1), 256, 0, stream>>>(S1both, WT2, S2both, nullptr, ZP,
                                          128, 128, 64, 64, 0, 0);
  // conv3 (HBM-streamed 34MB input): db/BK64, M = 65536 -> 512x2 of 128x128
  tile_conv_db<128, 128, 128, 256, 3, 3, 2, 1, 0, 1, 0, 0, 1>
      <<<dim3(512, 2), 256, 0, stream>>>(S2both, WT3, S3both, nullptr, ZP,
                                         64, 64, 32, 32, 0, 0);
  // conv4 (L2-resident 16.8MB input): ring3/BK32, M = 16384 -> 128x4
  tile_conv_r3<128, 128, 256, 512, 3, 3, 2, 1, 0, 1, 0, 0, 1>
      <<<dim3(128, 4), 256, 0, stream>>>(S3both, WT4, FEATs, nullptr, ZP,
                                         32, 32, 16, 16, 0, 0);

  // l2norm: FEATs (single) -> FEATsp (split pair, lo at +8388608 el)
  l2norm_k<<<16384, 64, 0, stream>>>(FEATs, FEATsp, 8388608);
  // corr (L3-resident): ring3 split GEMM (batched B), fp32 + fp16 hi out
  tile_conv_r3<64, 64, 512, 256, 1, 1, 1, 0, 1, 1, 1, 1, 0>
      <<<dim3(128, 4), 256, 0, stream>>>(FEATsp, FEATsp + 4194304, CORRh, CORRf,
                                         ZP, 16, 16, 16, 16, 8388608, 8388608);
  // conv_r1 (L2-resident 1MB input): ring3, 128x128, split-K 25
  tile_conv_r3<128, 128, 256, 128, 7, 7, 1, 0, 0, 25, 0, 0, 0>
      <<<dim3(25, 1, 25), 256, 0, stream>>>(CORRh, WTr1, nullptr, R1p, ZP,
                                            16, 16, 10, 10, 0, 0);
  sum_relu_s<<<1600, 256, 0, stream>>>(R1p, R1h, 409600, 25);
  // conv_r2: direct single fp16, split-K 25
  gemm_conv<1, 4, 128, 64, 5, 5, 25>
      <<<dim3(18, 1, 25), 256, 0, stream>>>(R1h, WTr2, R2p, 10, 10, 6, 6);
  sum_relu_f<<<288, 256, 0, stream>>>(R2p, R2f, 73728, 25);
  dense_k<<<dim3(18, 32), 64, 0, stream>>>(R2f, Wd, bd, GEOb);
  tps_k<<<32, 64, 0, stream>>>(GEOb, AXb, AYb);
  masksum_k<<<32, 256, 0, stream>>>(CORRf, AXb, AYb, (float*)d_out);
}